// Round 1
// baseline (767.615 us; speedup 1.0000x reference)
//
#include <hip/hip_runtime.h>

// SRGNN — Round 9: kill scratch spills in k_mono.
//  Evidence (r8 rocprof): WRITE_SIZE 622MB vs 8.4MB ideal out, FETCH +260MB
//  over ideal — ~870MB of scratch traffic. Root causes:
//   (a) `for (ct = wave; ct < 16; ct += 4)` has a runtime trip count (compiler
//       can't prove wave<4) -> no unroll -> agg[8] (32 VGPRs) runtime-indexed
//       -> allocated in scratch (rule #20).
//   (b) __launch_bounds__(256,5) caps unified VGPR file at ~96/wave (rocprof:
//       48 arch + ~48 acc) while GRU phase needs ~140 -> spill.
//  Fixes: constant-trip unrolled loops (k<4, ct=wave+4k); GRU r/z accumulators
//  fused across the two GEMMs (i_r+h_r summed in one acc, 12->8 f32x4);
//  __launch_bounds__(256,4) -> 128 VGPR/wave, 4 blocks/CU (LDS 126KB/CU fits).
// ws: [0] u32 flag ; [4KiB] bf16 weight copies (~419KB) ; [1MiB] adj u8 (8MB).

#define NG    8192
#define NODES 32
#define HDIM  128
#define NEDGE 524288
#define NCONV 214272   // total weight elements (inputs 2..13)

typedef __bf16 bf16;
typedef __bf16 bf16x8 __attribute__((ext_vector_type(8)));
typedef float  f32x4  __attribute__((ext_vector_type(4)));
typedef unsigned int u32;
typedef unsigned char u8;

__device__ __forceinline__ f32x4 mfma16(bf16x8 a, bf16x8 b, f32x4 c) {
    // D = A(16x32)*B(32x16)+C ; A[m=lane&15][k=quad*8+j], B[k=quad*8+j][n=lane&15],
    // D[row=quad*4+r][col=lane&15]  (verified: r3 MFMA == r4 scalar bit-exact)
    return __builtin_amdgcn_mfma_f32_16x16x32_bf16(a, b, c, 0, 0, 0);
}

__device__ __forceinline__ float sigmoidf_(float x) { return 1.f / (1.f + __expf(-x)); }

// ---- k_prep: blocks [0,2048) zero adj; blocks [2048,2153) convert weights ----
// Convert blocks self-detect f32-vs-bf16 by scanning the first 4096 words of
// feat (f32 data hits the 0xFF pseudo-exponent pattern w.p. 1-e^-16).
__global__ __launch_bounds__(256) void k_prep(
        const u32* __restrict__ featw, u32* __restrict__ adjw,
        bf16* __restrict__ conv, u32* __restrict__ flagout,
        const void* t0, const void* t1, const void* t2,  const void* t3,
        const void* t4, const void* t5, const void* t6,  const void* t7,
        const void* t8, const void* t9, const void* t10, const void* t11) {
    const int b = blockIdx.x, tid = threadIdx.x;
    if (b < 2048) {                       // zero 8MB of adj
        int i = b * 1024 + tid * 4;
        *(uint4*)(adjw + i) = make_uint4(0u, 0u, 0u, 0u);
        return;
    }
    __shared__ int s_isf32;
    if (tid == 0) s_isf32 = 0;
    __syncthreads();
    {
        u32 hit = 0;
#pragma unroll
        for (int k = 0; k < 16; ++k) {
            u32 x = featw[tid * 16 + k];
            hit |= (((x >> 7) & 0xFFu) == 0xFFu) ? 1u : 0u;
        }
        if (hit) s_isf32 = 1;             // benign race
    }
    __syncthreads();
    const bool isf32 = s_isf32 != 0;
    if (b == 2048 && tid == 0) *flagout = isf32 ? 1u : 0u;

    int e0 = (b - 2048) * 2048 + tid * 8;
    if (e0 >= NCONV) return;
    // tensor boundaries (all sizes multiples of 128, so groups of 8 never straddle)
    const int cnts[12] = {16384, 128, 16384, 128, 98304, 384, 49152, 384,
                          16384, 16384, 128, 128};
    int t = 0, base = 0;
    while (e0 >= base + cnts[t]) { base += cnts[t]; ++t; }
    int off = e0 - base;
    const void* sp;
    switch (t) {
        case 0: sp = t0; break; case 1: sp = t1; break;
        case 2: sp = t2; break; case 3: sp = t3; break;
        case 4: sp = t4; break; case 5: sp = t5; break;
        case 6: sp = t6; break; case 7: sp = t7; break;
        case 8: sp = t8; break; case 9: sp = t9; break;
        case 10: sp = t10; break; default: sp = t11; break;
    }
    if (isf32) {
        const float4* s = (const float4*)sp + (off >> 2);
        float4 a = s[0], bb = s[1];
        bf16x8 v;
        v[0] = (bf16)a.x;  v[1] = (bf16)a.y;  v[2] = (bf16)a.z;  v[3] = (bf16)a.w;
        v[4] = (bf16)bb.x; v[5] = (bf16)bb.y; v[6] = (bf16)bb.z; v[7] = (bf16)bb.w;
        *(bf16x8*)(conv + e0) = v;
    } else {
        *(uint4*)(conv + e0) = ((const uint4*)sp)[off >> 3];
    }
}

__global__ __launch_bounds__(256) void k_adj(const int* __restrict__ src,
                                             const int* __restrict__ dst,
                                             u32* __restrict__ adj) {
    int e = blockIdx.x * 256 + threadIdx.x;
    int s = src[e], d = dst[e];
    int g = s >> 5;                          // edges are intra-graph
    u32 bidx = ((u32)g << 10) | ((u32)(d & 31) << 5) | (u32)(s & 31);
    atomicAdd(&adj[bidx >> 2], 1u << (8 * (bidx & 3)));
}

__global__ __launch_bounds__(256, 4) void k_mono(
        const void* __restrict__ featv, const void* __restrict__ cntv,
        const bf16* __restrict__ W_in, const bf16* __restrict__ b_in,
        const bf16* __restrict__ W_og, const bf16* __restrict__ b_og,
        const bf16* __restrict__ W_ih, const bf16* __restrict__ b_ih,
        const bf16* __restrict__ W_hh, const bf16* __restrict__ b_hh,
        const bf16* __restrict__ W_u,  const bf16* __restrict__ W_v,
        const bf16* __restrict__ b_v,  const bf16* __restrict__ w_e,
        const int* __restrict__ last_nodes, const u8* __restrict__ adj8,
        const u32* __restrict__ flag, float* __restrict__ out) {
    const int g    = blockIdx.x;
    const int tid  = threadIdx.x;
    const int wave = tid >> 6, lane = tid & 63, q = lane >> 4, c = lane & 15;
    const bool isf32 = (*flag) != 0u;

    const int SF = 136;   // bf16 stride, 128-wide tiles (pad 8)
    const int SC = 264;   // bf16 stride, 256-wide tiles (pad 8)
    const int SA = 40;    // bf16 stride, 32-wide adjacency (pad 8; 2-way banks)
    __shared__ __align__(16) bf16 s_feat[32 * 136];   // 8704 B (feat, later hn)
    __shared__ __align__(16) bf16 s_fc  [32 * 264];   // 16896 B (featC, later a)
    __shared__ __align__(16) bf16 s_adjb[32 * 40];    // 2560 B  adj[v][u]
    __shared__ __align__(16) bf16 s_adjT[32 * 40];    // 2560 B  adj[u][v]
    __shared__ u32   s_adjw[256];                     // 1024 B; aliased by s_fv
    __shared__ float s_invin[32], s_invout[32];
    __shared__ float s_e[32], s_alpha[32];
    float* s_fv = (float*)s_adjw;     // s_adjw dead after phase 1; s_fv phase 4+

    // ---------- phase 0: stage feat (dtype branch) + adjacency ----------
    if (isf32) {
        const float4* fp = (const float4*)((const float*)featv + (size_t)g * 4096);
        for (int ch = tid; ch < 1024; ch += 256) {
            float4 v = fp[ch];
            int row = ch >> 5, off = (ch & 31) * 4;
            bf16* dp = s_feat + row * SF + off;
            dp[0] = (bf16)v.x; dp[1] = (bf16)v.y; dp[2] = (bf16)v.z; dp[3] = (bf16)v.w;
        }
    } else {
        const uint4* fp = (const uint4*)((const bf16*)featv + (size_t)g * 4096);
        for (int ch = tid; ch < 512; ch += 256) {
            int row = ch >> 4, off = (ch & 15) * 8;
            *(uint4*)(s_feat + row * SF + off) = fp[ch];
        }
    }
    s_adjw[tid] = ((const u32*)(adj8 + (size_t)g * 1024))[tid];
    if (tid < 32) s_e[tid] = 0.f;
    __syncthreads();   // B0

    // ---------- phase 1: adj->bf16 (+T), degrees, featC GEMM ----------
    {
        u32 w = s_adjw[tid];
        int v = tid >> 3, u0 = (tid & 7) * 4;
#pragma unroll
        for (int j = 0; j < 4; ++j) {
            float cv = (float)((w >> (8 * j)) & 0xFFu);
            s_adjb[v * SA + u0 + j] = (bf16)cv;
            s_adjT[(u0 + j) * SA + v] = (bf16)cv;
        }
    }
    if (tid < 32) {                                  // deg_in[v] = row-sum
        u32 s = 0;
        for (int i = 0; i < 8; ++i) {
            u32 w = s_adjw[tid * 8 + i];
            s += (w & 0xFF) + ((w >> 8) & 0xFF) + ((w >> 16) & 0xFF) + (w >> 24);
        }
        s_invin[tid] = 1.f / fmaxf((float)s, 1.f);
    } else if (tid >= 64 && tid < 96) {              // deg_out[u] = col-sum
        int uu = tid - 64; u32 s = 0;
        for (int v = 0; v < 32; ++v)
            s += (s_adjw[v * 8 + (uu >> 2)] >> (8 * (uu & 3))) & 0xFF;
        s_invout[uu] = 1.f / fmaxf((float)s, 1.f);
    }
    // featC = feat @ [W_in; W_og]^T + bias  (32 x 256 -> s_fc), rt-folded
    // NOTE: constant trip count (k<4) so the compiler fully unrolls.
#pragma unroll
    for (int k = 0; k < 4; ++k) {
        int ct = wave + 4 * k;
        int col = ct * 16 + c;
        const bf16* Wp = (col < 128) ? (W_in + col * HDIM) : (W_og + (col - 128) * HDIM);
        const bf16* A0 = s_feat + c * SF;
        const bf16* A1 = s_feat + (16 + c) * SF;
        f32x4 acc0 = {0, 0, 0, 0}, acc1 = {0, 0, 0, 0};
        for (int t = 0; t < 4; ++t) {
            bf16x8 b  = *(const bf16x8*)(Wp + 32 * t + 8 * q);
            bf16x8 a0 = *(const bf16x8*)(A0 + 32 * t + 8 * q);
            bf16x8 a1 = *(const bf16x8*)(A1 + 32 * t + 8 * q);
            acc0 = mfma16(a0, b, acc0);
            acc1 = mfma16(a1, b, acc1);
        }
        float bias = (float)((col < 128) ? b_in[col] : b_og[col - 128]);
#pragma unroll
        for (int r = 0; r < 4; ++r) {
            s_fc[(q * 4 + r) * SC + col]      = (bf16)(acc0[r] + bias);
            s_fc[(16 + q * 4 + r) * SC + col] = (bf16)(acc1[r] + bias);
        }
    }
    __syncthreads();   // B1

    // ---------- phase 2: aggregation via MFMA ----------
    // a_in[v]  = invin[v]  * sum_u adj[v][u] * fin[u]     (cols   0..127)
    // a_out[u] = invout[u] * sum_v adjT[u][v] * fout[v]   (cols 128..255)
    // agg[] indices are compile-time constants (k<4 unrolled) -> stays in VGPRs.
    f32x4 agg[8];
#pragma unroll
    for (int k = 0; k < 4; ++k) {
        int ct = wave + 4 * k;
        bf16x8 bfrag;
        const bf16* Bp = s_fc + (q * 8) * SC + ct * 16 + c;
#pragma unroll
        for (int j = 0; j < 8; ++j) bfrag[j] = Bp[j * SC];
        const bf16* Ab = (ct < 8) ? s_adjb : s_adjT;
        bf16x8 a0 = *(const bf16x8*)(Ab + c * SA + 8 * q);
        bf16x8 a1 = *(const bf16x8*)(Ab + (16 + c) * SA + 8 * q);
        f32x4 z = {0, 0, 0, 0};
        agg[2 * k]     = mfma16(a0, bfrag, z);
        agg[2 * k + 1] = mfma16(a1, bfrag, z);
    }
    __syncthreads();   // B2a (all s_fc reads done)
#pragma unroll
    for (int k = 0; k < 4; ++k) {
        int ct = wave + 4 * k;
        const float* inv = (ct < 8) ? s_invin : s_invout;
#pragma unroll
        for (int r = 0; r < 4; ++r) {
            int row0 = q * 4 + r, row1 = 16 + q * 4 + r;
            s_fc[row0 * SC + ct * 16 + c] = (bf16)(agg[2 * k][r] * inv[row0]);
            s_fc[row1 * SC + ct * 16 + c] = (bf16)(agg[2 * k + 1][r] * inv[row1]);
        }
    }
    __syncthreads();   // B2b (s_a ready in s_fc region)
    const bf16* s_a = s_fc;

    // ---------- phase 3: GRU -> hn kept in regs, then written into s_feat ----
    // r/z gates: sigmoid(i_r+h_r) is a plain sum, so a@Wr and feat@Vr share ONE
    // accumulator (biases folded as b_ih+b_hh). Only the n gate needs i_n and
    // h_n apart (tanh(i_n + r*h_n)). 12 accs -> 8 (32 VGPRs peak, no spill).
    float hn_lo[2][4], hn_hi[2][4];
#pragma unroll
    for (int ii = 0; ii < 2; ++ii) {
        int hb = wave + 4 * ii, h0 = hb * 16;
        const bf16* Wr = W_ih + (h0 + c) * 256;
        const bf16* Wz = W_ih + (128 + h0 + c) * 256;
        const bf16* Wn = W_ih + (256 + h0 + c) * 256;
        const bf16* Vr = W_hh + (h0 + c) * HDIM;
        const bf16* Vz = W_hh + (128 + h0 + c) * HDIM;
        const bf16* Vn = W_hh + (256 + h0 + c) * HDIM;
        const bf16* A0 = s_a + c * SC;
        const bf16* A1 = s_a + (16 + c) * SC;
        const bf16* F0 = s_feat + c * SF;
        const bf16* F1 = s_feat + (16 + c) * SF;
        f32x4 rr0 = {0,0,0,0}, rr1 = {0,0,0,0};   // i_r + h_r (fused)
        f32x4 zz0 = {0,0,0,0}, zz1 = {0,0,0,0};   // i_z + h_z (fused)
        f32x4 in0 = {0,0,0,0}, in1 = {0,0,0,0};   // i_n
        f32x4 nh0 = {0,0,0,0}, nh1 = {0,0,0,0};   // h_n
        for (int t = 0; t < 8; ++t) {
            bf16x8 a0 = *(const bf16x8*)(A0 + 32 * t + 8 * q);
            bf16x8 a1 = *(const bf16x8*)(A1 + 32 * t + 8 * q);
            bf16x8 br = *(const bf16x8*)(Wr + 32 * t + 8 * q);
            rr0 = mfma16(a0, br, rr0); rr1 = mfma16(a1, br, rr1);
            bf16x8 bz = *(const bf16x8*)(Wz + 32 * t + 8 * q);
            zz0 = mfma16(a0, bz, zz0); zz1 = mfma16(a1, bz, zz1);
            bf16x8 bn = *(const bf16x8*)(Wn + 32 * t + 8 * q);
            in0 = mfma16(a0, bn, in0); in1 = mfma16(a1, bn, in1);
        }
        for (int t = 0; t < 4; ++t) {
            bf16x8 f0 = *(const bf16x8*)(F0 + 32 * t + 8 * q);
            bf16x8 f1 = *(const bf16x8*)(F1 + 32 * t + 8 * q);
            bf16x8 br = *(const bf16x8*)(Vr + 32 * t + 8 * q);
            rr0 = mfma16(f0, br, rr0); rr1 = mfma16(f1, br, rr1);
            bf16x8 bz = *(const bf16x8*)(Vz + 32 * t + 8 * q);
            zz0 = mfma16(f0, bz, zz0); zz1 = mfma16(f1, bz, zz1);
            bf16x8 bn = *(const bf16x8*)(Vn + 32 * t + 8 * q);
            nh0 = mfma16(f0, bn, nh0); nh1 = mfma16(f1, bn, nh1);
        }
        float brz  = (float)b_ih[h0 + c]       + (float)b_hh[h0 + c];
        float bzz  = (float)b_ih[128 + h0 + c] + (float)b_hh[128 + h0 + c];
        float bin_ = (float)b_ih[256 + h0 + c];
        float bhn  = (float)b_hh[256 + h0 + c];
#pragma unroll
        for (int r = 0; r < 4; ++r) {
            int row0 = q * 4 + r, row1 = 16 + q * 4 + r;
            float rg = sigmoidf_(rr0[r] + brz);
            float z_ = sigmoidf_(zz0[r] + bzz);
            float ng = tanhf((in0[r] + bin_) + rg * (nh0[r] + bhn));
            float fv = (float)s_feat[row0 * SF + h0 + c];
            hn_lo[ii][r] = (1.f - z_) * ng + z_ * fv;
            rg = sigmoidf_(rr1[r] + brz);
            z_ = sigmoidf_(zz1[r] + bzz);
            ng = tanhf((in1[r] + bin_) + rg * (nh1[r] + bhn));
            fv = (float)s_feat[row1 * SF + h0 + c];
            hn_hi[ii][r] = (1.f - z_) * ng + z_ * fv;
        }
    }
    int ll = last_nodes[g] & 31;
    __syncthreads();   // B3a (all s_feat reads done)
#pragma unroll
    for (int ii = 0; ii < 2; ++ii) {
        int h0 = (wave + 4 * ii) * 16;
#pragma unroll
        for (int r = 0; r < 4; ++r) {
            s_feat[(q * 4 + r) * SF + h0 + c]      = (bf16)hn_lo[ii][r];
            s_feat[(16 + q * 4 + r) * SF + h0 + c] = (bf16)hn_hi[ii][r];
        }
    }
    __syncthreads();   // B3b (s_feat now holds hn)
    const bf16* s_hn = s_feat;

    // ---------- phase 4: feat_v = hn[ll] @ W_v^T + b_v (broadcast-A MFMA) ----
#pragma unroll
    for (int k = 0; k < 2; ++k) {
        int ct = wave * 2 + k;
        const bf16* Wp = W_v + (ct * 16 + c) * HDIM;
        const bf16* Ap = s_hn + ll * SF;
        f32x4 acc = {0, 0, 0, 0};
        for (int t = 0; t < 4; ++t) {
            bf16x8 a = *(const bf16x8*)(Ap + 32 * t + 8 * q);
            bf16x8 b = *(const bf16x8*)(Wp + 32 * t + 8 * q);
            acc = mfma16(a, b, acc);
        }
        if (q == 0) s_fv[ct * 16 + c] = acc[0] + (float)b_v[ct * 16 + c];
    }
    __syncthreads();   // B4

    // ---------- phase 5: e[n] = sum_col sigmoid((hn@W_u^T)[n,col]+fv[col])*w_e[col]
#pragma unroll
    for (int k = 0; k < 2; ++k) {
        int ct = wave * 2 + k;
        const bf16* Wp = W_u + (ct * 16 + c) * HDIM;
        const bf16* A0 = s_hn + c * SF;
        const bf16* A1 = s_hn + (16 + c) * SF;
        f32x4 e0 = {0, 0, 0, 0}, e1 = {0, 0, 0, 0};
        for (int t = 0; t < 4; ++t) {
            bf16x8 b  = *(const bf16x8*)(Wp + 32 * t + 8 * q);
            bf16x8 a0 = *(const bf16x8*)(A0 + 32 * t + 8 * q);
            bf16x8 a1 = *(const bf16x8*)(A1 + 32 * t + 8 * q);
            e0 = mfma16(a0, b, e0);
            e1 = mfma16(a1, b, e1);
        }
        int col = ct * 16 + c;
        float we = (float)w_e[col], fv = s_fv[col];
#pragma unroll
        for (int r = 0; r < 4; ++r) {
            float v0 = sigmoidf_(e0[r] + fv) * we;
            float v1 = sigmoidf_(e1[r] + fv) * we;
            for (int m = 1; m < 16; m <<= 1) {
                v0 += __shfl_xor(v0, m);
                v1 += __shfl_xor(v1, m);
            }
            if (c == 0) {
                atomicAdd(&s_e[q * 4 + r], v0);
                atomicAdd(&s_e[16 + q * 4 + r], v1);
            }
        }
    }
    __syncthreads();   // B5
    if (tid < 32) {
        float cv = isf32 ? ((const float*)cntv)[(size_t)g * 32 + tid]
                         : (float)((const bf16*)cntv)[(size_t)g * 32 + tid];
        s_alpha[tid] = s_e[tid] * cv;
    }
    __syncthreads();   // B6

    // ---------- output (f32): [ct_g (128) | ct_l (128)] ----------
    if (tid < 128) {
        float s = 0.f;
        for (int n = 0; n < 32; ++n) s += s_alpha[n] * (float)s_hn[n * SF + tid];
        out[(size_t)g * 256 + tid] = s;
    } else {
        int h = tid - 128;
        out[(size_t)g * 256 + 128 + h] = (float)s_hn[ll * SF + h];
    }
}

extern "C" void kernel_launch(void* const* d_in, const int* in_sizes, int n_in,
                              void* d_out, int out_size, void* d_ws, size_t ws_size,
                              hipStream_t stream) {
    const int* src  = (const int*)d_in[14];
    const int* dst  = (const int*)d_in[15];
    const int* last = (const int*)d_in[17];
    float* out = (float*)d_out;

    u32*  flag = (u32*)d_ws;
    bf16* conv = (bf16*)((char*)d_ws + 4096);
    u32*  adjw = (u32*)((char*)d_ws + (1u << 20));
    const u8* adj8 = (const u8*)adjw;

    // bf16 weight copies, contiguous in input order 2..13
    const int cnts[12] = {16384, 128, 16384, 128, 98304, 384, 49152, 384,
                          16384, 16384, 128, 128};
    bf16* cp[12];
    {
        bf16* p = conv;
        for (int i = 0; i < 12; ++i) { cp[i] = p; p += cnts[i]; }
    }

    k_prep<<<2048 + (NCONV + 2047) / 2048, 256, 0, stream>>>(
        (const u32*)d_in[0], adjw, conv, flag,
        d_in[2], d_in[3], d_in[4], d_in[5], d_in[6], d_in[7],
        d_in[8], d_in[9], d_in[10], d_in[11], d_in[12], d_in[13]);
    k_adj<<<NEDGE / 256, 256, 0, stream>>>(src, dst, adjw);
    k_mono<<<NG, 256, 0, stream>>>(d_in[0], d_in[1],
                                   cp[0], cp[1], cp[2], cp[3],
                                   cp[4], cp[5], cp[6], cp[7],
                                   cp[8], cp[9], cp[10], cp[11],
                                   last, adj8, flag, out);
}

// Round 2
// 704.479 us; speedup vs baseline: 1.0896x; 1.0896x over previous
//
#include <hip/hip_runtime.h>

// SRGNN — Round 10: fix the REAL register budget.
//  r9 post-mortem: WRITE_SIZE still 502MB (ideal 8.4MB) — spill persists.
//  Root cause: per-SIMD unified VGPR pool is 512 regs (m69: waves/CU halve at
//  vgpr 64/128/256), so __launch_bounds__(256,N) caps waves at 512/N regs:
//    r8 (256,5) -> 102-reg cap (rocprof 48+48=96)   -> heavy spill
//    r9 (256,4) -> 128-reg cap (rocprof 64+64=128)  -> still spills; GRU peak
//       live set ~140-160 (8 f32x4 accs + 5 bf16x8 frags + 16 hn + addrs).
//  Fix: __launch_bounds__(256,2) -> 256 regs/wave, zero spill. Occupancy drops
//  to 2 blocks/CU (LDS would allow 4) — accepted: spill-free latency beats
//  2x occupancy of scratch-thrashing waves (632us measured vs ~40us work).
// ws: [0] u32 flag ; [4KiB] bf16 weight copies (~419KB) ; [1MiB] adj u8 (8MB).

#define NG    8192
#define NODES 32
#define HDIM  128
#define NEDGE 524288
#define NCONV 214272   // total weight elements (inputs 2..13)

typedef __bf16 bf16;
typedef __bf16 bf16x8 __attribute__((ext_vector_type(8)));
typedef float  f32x4  __attribute__((ext_vector_type(4)));
typedef unsigned int u32;
typedef unsigned char u8;

__device__ __forceinline__ f32x4 mfma16(bf16x8 a, bf16x8 b, f32x4 c) {
    // D = A(16x32)*B(32x16)+C ; A[m=lane&15][k=quad*8+j], B[k=quad*8+j][n=lane&15],
    // D[row=quad*4+r][col=lane&15]  (verified: r3 MFMA == r4 scalar bit-exact)
    return __builtin_amdgcn_mfma_f32_16x16x32_bf16(a, b, c, 0, 0, 0);
}

__device__ __forceinline__ float sigmoidf_(float x) { return 1.f / (1.f + __expf(-x)); }

// ---- k_prep: blocks [0,2048) zero adj; blocks [2048,2153) convert weights ----
// Convert blocks self-detect f32-vs-bf16 by scanning the first 4096 words of
// feat (f32 data hits the 0xFF pseudo-exponent pattern w.p. 1-e^-16).
__global__ __launch_bounds__(256) void k_prep(
        const u32* __restrict__ featw, u32* __restrict__ adjw,
        bf16* __restrict__ conv, u32* __restrict__ flagout,
        const void* t0, const void* t1, const void* t2,  const void* t3,
        const void* t4, const void* t5, const void* t6,  const void* t7,
        const void* t8, const void* t9, const void* t10, const void* t11) {
    const int b = blockIdx.x, tid = threadIdx.x;
    if (b < 2048) {                       // zero 8MB of adj
        int i = b * 1024 + tid * 4;
        *(uint4*)(adjw + i) = make_uint4(0u, 0u, 0u, 0u);
        return;
    }
    __shared__ int s_isf32;
    if (tid == 0) s_isf32 = 0;
    __syncthreads();
    {
        u32 hit = 0;
#pragma unroll
        for (int k = 0; k < 16; ++k) {
            u32 x = featw[tid * 16 + k];
            hit |= (((x >> 7) & 0xFFu) == 0xFFu) ? 1u : 0u;
        }
        if (hit) s_isf32 = 1;             // benign race
    }
    __syncthreads();
    const bool isf32 = s_isf32 != 0;
    if (b == 2048 && tid == 0) *flagout = isf32 ? 1u : 0u;

    int e0 = (b - 2048) * 2048 + tid * 8;
    if (e0 >= NCONV) return;
    // tensor boundaries (all sizes multiples of 128, so groups of 8 never straddle)
    const int cnts[12] = {16384, 128, 16384, 128, 98304, 384, 49152, 384,
                          16384, 16384, 128, 128};
    int t = 0, base = 0;
    while (e0 >= base + cnts[t]) { base += cnts[t]; ++t; }
    int off = e0 - base;
    const void* sp;
    switch (t) {
        case 0: sp = t0; break; case 1: sp = t1; break;
        case 2: sp = t2; break; case 3: sp = t3; break;
        case 4: sp = t4; break; case 5: sp = t5; break;
        case 6: sp = t6; break; case 7: sp = t7; break;
        case 8: sp = t8; break; case 9: sp = t9; break;
        case 10: sp = t10; break; default: sp = t11; break;
    }
    if (isf32) {
        const float4* s = (const float4*)sp + (off >> 2);
        float4 a = s[0], bb = s[1];
        bf16x8 v;
        v[0] = (bf16)a.x;  v[1] = (bf16)a.y;  v[2] = (bf16)a.z;  v[3] = (bf16)a.w;
        v[4] = (bf16)bb.x; v[5] = (bf16)bb.y; v[6] = (bf16)bb.z; v[7] = (bf16)bb.w;
        *(bf16x8*)(conv + e0) = v;
    } else {
        *(uint4*)(conv + e0) = ((const uint4*)sp)[off >> 3];
    }
}

__global__ __launch_bounds__(256) void k_adj(const int* __restrict__ src,
                                             const int* __restrict__ dst,
                                             u32* __restrict__ adj) {
    int e = blockIdx.x * 256 + threadIdx.x;
    int s = src[e], d = dst[e];
    int g = s >> 5;                          // edges are intra-graph
    u32 bidx = ((u32)g << 10) | ((u32)(d & 31) << 5) | (u32)(s & 31);
    atomicAdd(&adj[bidx >> 2], 1u << (8 * (bidx & 3)));
}

__global__ __launch_bounds__(256, 2) void k_mono(
        const void* __restrict__ featv, const void* __restrict__ cntv,
        const bf16* __restrict__ W_in, const bf16* __restrict__ b_in,
        const bf16* __restrict__ W_og, const bf16* __restrict__ b_og,
        const bf16* __restrict__ W_ih, const bf16* __restrict__ b_ih,
        const bf16* __restrict__ W_hh, const bf16* __restrict__ b_hh,
        const bf16* __restrict__ W_u,  const bf16* __restrict__ W_v,
        const bf16* __restrict__ b_v,  const bf16* __restrict__ w_e,
        const int* __restrict__ last_nodes, const u8* __restrict__ adj8,
        const u32* __restrict__ flag, float* __restrict__ out) {
    const int g    = blockIdx.x;
    const int tid  = threadIdx.x;
    const int wave = tid >> 6, lane = tid & 63, q = lane >> 4, c = lane & 15;
    const bool isf32 = (*flag) != 0u;

    const int SF = 136;   // bf16 stride, 128-wide tiles (pad 8)
    const int SC = 264;   // bf16 stride, 256-wide tiles (pad 8)
    const int SA = 40;    // bf16 stride, 32-wide adjacency (pad 8; 2-way banks)
    __shared__ __align__(16) bf16 s_feat[32 * 136];   // 8704 B (feat, later hn)
    __shared__ __align__(16) bf16 s_fc  [32 * 264];   // 16896 B (featC, later a)
    __shared__ __align__(16) bf16 s_adjb[32 * 40];    // 2560 B  adj[v][u]
    __shared__ __align__(16) bf16 s_adjT[32 * 40];    // 2560 B  adj[u][v]
    __shared__ u32   s_adjw[256];                     // 1024 B; aliased by s_fv
    __shared__ float s_invin[32], s_invout[32];
    __shared__ float s_e[32], s_alpha[32];
    float* s_fv = (float*)s_adjw;     // s_adjw dead after phase 1; s_fv phase 4+

    // ---------- phase 0: stage feat (dtype branch) + adjacency ----------
    if (isf32) {
        const float4* fp = (const float4*)((const float*)featv + (size_t)g * 4096);
        for (int ch = tid; ch < 1024; ch += 256) {
            float4 v = fp[ch];
            int row = ch >> 5, off = (ch & 31) * 4;
            bf16* dp = s_feat + row * SF + off;
            dp[0] = (bf16)v.x; dp[1] = (bf16)v.y; dp[2] = (bf16)v.z; dp[3] = (bf16)v.w;
        }
    } else {
        const uint4* fp = (const uint4*)((const bf16*)featv + (size_t)g * 4096);
        for (int ch = tid; ch < 512; ch += 256) {
            int row = ch >> 4, off = (ch & 15) * 8;
            *(uint4*)(s_feat + row * SF + off) = fp[ch];
        }
    }
    s_adjw[tid] = ((const u32*)(adj8 + (size_t)g * 1024))[tid];
    if (tid < 32) s_e[tid] = 0.f;
    __syncthreads();   // B0

    // ---------- phase 1: adj->bf16 (+T), degrees, featC GEMM ----------
    {
        u32 w = s_adjw[tid];
        int v = tid >> 3, u0 = (tid & 7) * 4;
#pragma unroll
        for (int j = 0; j < 4; ++j) {
            float cv = (float)((w >> (8 * j)) & 0xFFu);
            s_adjb[v * SA + u0 + j] = (bf16)cv;
            s_adjT[(u0 + j) * SA + v] = (bf16)cv;
        }
    }
    if (tid < 32) {                                  // deg_in[v] = row-sum
        u32 s = 0;
        for (int i = 0; i < 8; ++i) {
            u32 w = s_adjw[tid * 8 + i];
            s += (w & 0xFF) + ((w >> 8) & 0xFF) + ((w >> 16) & 0xFF) + (w >> 24);
        }
        s_invin[tid] = 1.f / fmaxf((float)s, 1.f);
    } else if (tid >= 64 && tid < 96) {              // deg_out[u] = col-sum
        int uu = tid - 64; u32 s = 0;
        for (int v = 0; v < 32; ++v)
            s += (s_adjw[v * 8 + (uu >> 2)] >> (8 * (uu & 3))) & 0xFF;
        s_invout[uu] = 1.f / fmaxf((float)s, 1.f);
    }
    // featC = feat @ [W_in; W_og]^T + bias  (32 x 256 -> s_fc), rt-folded
    // NOTE: constant trip count (k<4) so the compiler fully unrolls.
#pragma unroll
    for (int k = 0; k < 4; ++k) {
        int ct = wave + 4 * k;
        int col = ct * 16 + c;
        const bf16* Wp = (col < 128) ? (W_in + col * HDIM) : (W_og + (col - 128) * HDIM);
        const bf16* A0 = s_feat + c * SF;
        const bf16* A1 = s_feat + (16 + c) * SF;
        f32x4 acc0 = {0, 0, 0, 0}, acc1 = {0, 0, 0, 0};
        for (int t = 0; t < 4; ++t) {
            bf16x8 b  = *(const bf16x8*)(Wp + 32 * t + 8 * q);
            bf16x8 a0 = *(const bf16x8*)(A0 + 32 * t + 8 * q);
            bf16x8 a1 = *(const bf16x8*)(A1 + 32 * t + 8 * q);
            acc0 = mfma16(a0, b, acc0);
            acc1 = mfma16(a1, b, acc1);
        }
        float bias = (float)((col < 128) ? b_in[col] : b_og[col - 128]);
#pragma unroll
        for (int r = 0; r < 4; ++r) {
            s_fc[(q * 4 + r) * SC + col]      = (bf16)(acc0[r] + bias);
            s_fc[(16 + q * 4 + r) * SC + col] = (bf16)(acc1[r] + bias);
        }
    }
    __syncthreads();   // B1

    // ---------- phase 2: aggregation via MFMA ----------
    // a_in[v]  = invin[v]  * sum_u adj[v][u] * fin[u]     (cols   0..127)
    // a_out[u] = invout[u] * sum_v adjT[u][v] * fout[v]   (cols 128..255)
    // agg[] indices are compile-time constants (k<4 unrolled) -> stays in VGPRs.
    f32x4 agg[8];
#pragma unroll
    for (int k = 0; k < 4; ++k) {
        int ct = wave + 4 * k;
        bf16x8 bfrag;
        const bf16* Bp = s_fc + (q * 8) * SC + ct * 16 + c;
#pragma unroll
        for (int j = 0; j < 8; ++j) bfrag[j] = Bp[j * SC];
        const bf16* Ab = (ct < 8) ? s_adjb : s_adjT;
        bf16x8 a0 = *(const bf16x8*)(Ab + c * SA + 8 * q);
        bf16x8 a1 = *(const bf16x8*)(Ab + (16 + c) * SA + 8 * q);
        f32x4 z = {0, 0, 0, 0};
        agg[2 * k]     = mfma16(a0, bfrag, z);
        agg[2 * k + 1] = mfma16(a1, bfrag, z);
    }
    __syncthreads();   // B2a (all s_fc reads done)
#pragma unroll
    for (int k = 0; k < 4; ++k) {
        int ct = wave + 4 * k;
        const float* inv = (ct < 8) ? s_invin : s_invout;
#pragma unroll
        for (int r = 0; r < 4; ++r) {
            int row0 = q * 4 + r, row1 = 16 + q * 4 + r;
            s_fc[row0 * SC + ct * 16 + c] = (bf16)(agg[2 * k][r] * inv[row0]);
            s_fc[row1 * SC + ct * 16 + c] = (bf16)(agg[2 * k + 1][r] * inv[row1]);
        }
    }
    __syncthreads();   // B2b (s_a ready in s_fc region)
    const bf16* s_a = s_fc;

    // ---------- phase 3: GRU -> hn kept in regs, then written into s_feat ----
    // r/z gates: sigmoid(i_r+h_r) is a plain sum, so a@Wr and feat@Vr share ONE
    // accumulator (biases folded as b_ih+b_hh). Only the n gate needs i_n and
    // h_n apart (tanh(i_n + r*h_n)). 8 f32x4 accs; fits the 256-reg budget.
    float hn_lo[2][4], hn_hi[2][4];
#pragma unroll
    for (int ii = 0; ii < 2; ++ii) {
        int hb = wave + 4 * ii, h0 = hb * 16;
        const bf16* Wr = W_ih + (h0 + c) * 256;
        const bf16* Wz = W_ih + (128 + h0 + c) * 256;
        const bf16* Wn = W_ih + (256 + h0 + c) * 256;
        const bf16* Vr = W_hh + (h0 + c) * HDIM;
        const bf16* Vz = W_hh + (128 + h0 + c) * HDIM;
        const bf16* Vn = W_hh + (256 + h0 + c) * HDIM;
        const bf16* A0 = s_a + c * SC;
        const bf16* A1 = s_a + (16 + c) * SC;
        const bf16* F0 = s_feat + c * SF;
        const bf16* F1 = s_feat + (16 + c) * SF;
        f32x4 rr0 = {0,0,0,0}, rr1 = {0,0,0,0};   // i_r + h_r (fused)
        f32x4 zz0 = {0,0,0,0}, zz1 = {0,0,0,0};   // i_z + h_z (fused)
        f32x4 in0 = {0,0,0,0}, in1 = {0,0,0,0};   // i_n
        f32x4 nh0 = {0,0,0,0}, nh1 = {0,0,0,0};   // h_n
        for (int t = 0; t < 8; ++t) {
            bf16x8 a0 = *(const bf16x8*)(A0 + 32 * t + 8 * q);
            bf16x8 a1 = *(const bf16x8*)(A1 + 32 * t + 8 * q);
            bf16x8 br = *(const bf16x8*)(Wr + 32 * t + 8 * q);
            rr0 = mfma16(a0, br, rr0); rr1 = mfma16(a1, br, rr1);
            bf16x8 bz = *(const bf16x8*)(Wz + 32 * t + 8 * q);
            zz0 = mfma16(a0, bz, zz0); zz1 = mfma16(a1, bz, zz1);
            bf16x8 bn = *(const bf16x8*)(Wn + 32 * t + 8 * q);
            in0 = mfma16(a0, bn, in0); in1 = mfma16(a1, bn, in1);
        }
        for (int t = 0; t < 4; ++t) {
            bf16x8 f0 = *(const bf16x8*)(F0 + 32 * t + 8 * q);
            bf16x8 f1 = *(const bf16x8*)(F1 + 32 * t + 8 * q);
            bf16x8 br = *(const bf16x8*)(Vr + 32 * t + 8 * q);
            rr0 = mfma16(f0, br, rr0); rr1 = mfma16(f1, br, rr1);
            bf16x8 bz = *(const bf16x8*)(Vz + 32 * t + 8 * q);
            zz0 = mfma16(f0, bz, zz0); zz1 = mfma16(f1, bz, zz1);
            bf16x8 bn = *(const bf16x8*)(Vn + 32 * t + 8 * q);
            nh0 = mfma16(f0, bn, nh0); nh1 = mfma16(f1, bn, nh1);
        }
        float brz  = (float)b_ih[h0 + c]       + (float)b_hh[h0 + c];
        float bzz  = (float)b_ih[128 + h0 + c] + (float)b_hh[128 + h0 + c];
        float bin_ = (float)b_ih[256 + h0 + c];
        float bhn  = (float)b_hh[256 + h0 + c];
#pragma unroll
        for (int r = 0; r < 4; ++r) {
            int row0 = q * 4 + r, row1 = 16 + q * 4 + r;
            float rg = sigmoidf_(rr0[r] + brz);
            float z_ = sigmoidf_(zz0[r] + bzz);
            float ng = tanhf((in0[r] + bin_) + rg * (nh0[r] + bhn));
            float fv = (float)s_feat[row0 * SF + h0 + c];
            hn_lo[ii][r] = (1.f - z_) * ng + z_ * fv;
            rg = sigmoidf_(rr1[r] + brz);
            z_ = sigmoidf_(zz1[r] + bzz);
            ng = tanhf((in1[r] + bin_) + rg * (nh1[r] + bhn));
            fv = (float)s_feat[row1 * SF + h0 + c];
            hn_hi[ii][r] = (1.f - z_) * ng + z_ * fv;
        }
    }
    int ll = last_nodes[g] & 31;
    __syncthreads();   // B3a (all s_feat reads done)
#pragma unroll
    for (int ii = 0; ii < 2; ++ii) {
        int h0 = (wave + 4 * ii) * 16;
#pragma unroll
        for (int r = 0; r < 4; ++r) {
            s_feat[(q * 4 + r) * SF + h0 + c]      = (bf16)hn_lo[ii][r];
            s_feat[(16 + q * 4 + r) * SF + h0 + c] = (bf16)hn_hi[ii][r];
        }
    }
    __syncthreads();   // B3b (s_feat now holds hn)
    const bf16* s_hn = s_feat;

    // ---------- phase 4: feat_v = hn[ll] @ W_v^T + b_v (broadcast-A MFMA) ----
#pragma unroll
    for (int k = 0; k < 2; ++k) {
        int ct = wave * 2 + k;
        const bf16* Wp = W_v + (ct * 16 + c) * HDIM;
        const bf16* Ap = s_hn + ll * SF;
        f32x4 acc = {0, 0, 0, 0};
        for (int t = 0; t < 4; ++t) {
            bf16x8 a = *(const bf16x8*)(Ap + 32 * t + 8 * q);
            bf16x8 b = *(const bf16x8*)(Wp + 32 * t + 8 * q);
            acc = mfma16(a, b, acc);
        }
        if (q == 0) s_fv[ct * 16 + c] = acc[0] + (float)b_v[ct * 16 + c];
    }
    __syncthreads();   // B4

    // ---------- phase 5: e[n] = sum_col sigmoid((hn@W_u^T)[n,col]+fv[col])*w_e[col]
#pragma unroll
    for (int k = 0; k < 2; ++k) {
        int ct = wave * 2 + k;
        const bf16* Wp = W_u + (ct * 16 + c) * HDIM;
        const bf16* A0 = s_hn + c * SF;
        const bf16* A1 = s_hn + (16 + c) * SF;
        f32x4 e0 = {0, 0, 0, 0}, e1 = {0, 0, 0, 0};
        for (int t = 0; t < 4; ++t) {
            bf16x8 b  = *(const bf16x8*)(Wp + 32 * t + 8 * q);
            bf16x8 a0 = *(const bf16x8*)(A0 + 32 * t + 8 * q);
            bf16x8 a1 = *(const bf16x8*)(A1 + 32 * t + 8 * q);
            e0 = mfma16(a0, b, e0);
            e1 = mfma16(a1, b, e1);
        }
        int col = ct * 16 + c;
        float we = (float)w_e[col], fv = s_fv[col];
#pragma unroll
        for (int r = 0; r < 4; ++r) {
            float v0 = sigmoidf_(e0[r] + fv) * we;
            float v1 = sigmoidf_(e1[r] + fv) * we;
            for (int m = 1; m < 16; m <<= 1) {
                v0 += __shfl_xor(v0, m);
                v1 += __shfl_xor(v1, m);
            }
            if (c == 0) {
                atomicAdd(&s_e[q * 4 + r], v0);
                atomicAdd(&s_e[16 + q * 4 + r], v1);
            }
        }
    }
    __syncthreads();   // B5
    if (tid < 32) {
        float cv = isf32 ? ((const float*)cntv)[(size_t)g * 32 + tid]
                         : (float)((const bf16*)cntv)[(size_t)g * 32 + tid];
        s_alpha[tid] = s_e[tid] * cv;
    }
    __syncthreads();   // B6

    // ---------- output (f32): [ct_g (128) | ct_l (128)] ----------
    if (tid < 128) {
        float s = 0.f;
        for (int n = 0; n < 32; ++n) s += s_alpha[n] * (float)s_hn[n * SF + tid];
        out[(size_t)g * 256 + tid] = s;
    } else {
        int h = tid - 128;
        out[(size_t)g * 256 + 128 + h] = (float)s_hn[ll * SF + h];
    }
}

extern "C" void kernel_launch(void* const* d_in, const int* in_sizes, int n_in,
                              void* d_out, int out_size, void* d_ws, size_t ws_size,
                              hipStream_t stream) {
    const int* src  = (const int*)d_in[14];
    const int* dst  = (const int*)d_in[15];
    const int* last = (const int*)d_in[17];
    float* out = (float*)d_out;

    u32*  flag = (u32*)d_ws;
    bf16* conv = (bf16*)((char*)d_ws + 4096);
    u32*  adjw = (u32*)((char*)d_ws + (1u << 20));
    const u8* adj8 = (const u8*)adjw;

    // bf16 weight copies, contiguous in input order 2..13
    const int cnts[12] = {16384, 128, 16384, 128, 98304, 384, 49152, 384,
                          16384, 16384, 128, 128};
    bf16* cp[12];
    {
        bf16* p = conv;
        for (int i = 0; i < 12; ++i) { cp[i] = p; p += cnts[i]; }
    }

    k_prep<<<2048 + (NCONV + 2047) / 2048, 256, 0, stream>>>(
        (const u32*)d_in[0], adjw, conv, flag,
        d_in[2], d_in[3], d_in[4], d_in[5], d_in[6], d_in[7],
        d_in[8], d_in[9], d_in[10], d_in[11], d_in[12], d_in[13]);
    k_adj<<<NEDGE / 256, 256, 0, stream>>>(src, dst, adjw);
    k_mono<<<NG, 256, 0, stream>>>(d_in[0], d_in[1],
                                   cp[0], cp[1], cp[2], cp[3],
                                   cp[4], cp[5], cp[6], cp[7],
                                   cp[8], cp[9], cp[10], cp[11],
                                   last, adj8, flag, out);
}

// Round 3
// 684.128 us; speedup vs baseline: 1.1220x; 1.0297x over previous
//
#include <hip/hip_runtime.h>

// SRGNN — Round 11: occupancy 2 -> 4 blocks/CU without re-introducing spills.
//  r10 post-mortem: spill gone (WRITE 8.2MB = output exactly), but occupancy
//  halved to 2 waves/SIMD -> latency-bound (all pipes <25%, dur 543us).
//  gfx950 VGPR granule is 64 (m68/m69 + r8/r9/r10 occupancy data): waves/SIMD
//  = 8/4/2 at alloc 64/128/256 — no 3-wave state. So the only step up is
//  4 waves/SIMD with total regs <= 128, which r9 proved the 8-acc GRU can't do.
//  Fix: hoist the h_n gate GEMM (feat @ W_hh_n + b) into phase 1 (low
//  pressure), stash as bf16 in LDS (s_hnp, stride 132, 8448B). GRU phase then
//  carries 6 accs (r/z fused i+h, i_n) and no Vn stream -> ~100 regs peak.
//  LDS 40704B/block; 4 x 40704 = 162816 <= 163840 -> 4 blocks/CU (16 waves).
//  Tripwire: if WRITE_SIZE >> 8.2MB next profile, the 128-cap spilled again.
// ws: [0] u32 flag ; [4KiB] bf16 weight copies (~419KB) ; [1MiB] adj u8 (8MB).

#define NG    8192
#define NODES 32
#define HDIM  128
#define NEDGE 524288
#define NCONV 214272   // total weight elements (inputs 2..13)

typedef __bf16 bf16;
typedef __bf16 bf16x8 __attribute__((ext_vector_type(8)));
typedef float  f32x4  __attribute__((ext_vector_type(4)));
typedef unsigned int u32;
typedef unsigned char u8;

__device__ __forceinline__ f32x4 mfma16(bf16x8 a, bf16x8 b, f32x4 c) {
    // D = A(16x32)*B(32x16)+C ; A[m=lane&15][k=quad*8+j], B[k=quad*8+j][n=lane&15],
    // D[row=quad*4+r][col=lane&15]  (verified: r3 MFMA == r4 scalar bit-exact)
    return __builtin_amdgcn_mfma_f32_16x16x32_bf16(a, b, c, 0, 0, 0);
}

__device__ __forceinline__ float sigmoidf_(float x) { return 1.f / (1.f + __expf(-x)); }

// ---- k_prep: blocks [0,2048) zero adj; blocks [2048,2153) convert weights ----
// Convert blocks self-detect f32-vs-bf16 by scanning the first 4096 words of
// feat (f32 data hits the 0xFF pseudo-exponent pattern w.p. 1-e^-16).
__global__ __launch_bounds__(256) void k_prep(
        const u32* __restrict__ featw, u32* __restrict__ adjw,
        bf16* __restrict__ conv, u32* __restrict__ flagout,
        const void* t0, const void* t1, const void* t2,  const void* t3,
        const void* t4, const void* t5, const void* t6,  const void* t7,
        const void* t8, const void* t9, const void* t10, const void* t11) {
    const int b = blockIdx.x, tid = threadIdx.x;
    if (b < 2048) {                       // zero 8MB of adj
        int i = b * 1024 + tid * 4;
        *(uint4*)(adjw + i) = make_uint4(0u, 0u, 0u, 0u);
        return;
    }
    __shared__ int s_isf32;
    if (tid == 0) s_isf32 = 0;
    __syncthreads();
    {
        u32 hit = 0;
#pragma unroll
        for (int k = 0; k < 16; ++k) {
            u32 x = featw[tid * 16 + k];
            hit |= (((x >> 7) & 0xFFu) == 0xFFu) ? 1u : 0u;
        }
        if (hit) s_isf32 = 1;             // benign race
    }
    __syncthreads();
    const bool isf32 = s_isf32 != 0;
    if (b == 2048 && tid == 0) *flagout = isf32 ? 1u : 0u;

    int e0 = (b - 2048) * 2048 + tid * 8;
    if (e0 >= NCONV) return;
    // tensor boundaries (all sizes multiples of 128, so groups of 8 never straddle)
    const int cnts[12] = {16384, 128, 16384, 128, 98304, 384, 49152, 384,
                          16384, 16384, 128, 128};
    int t = 0, base = 0;
    while (e0 >= base + cnts[t]) { base += cnts[t]; ++t; }
    int off = e0 - base;
    const void* sp;
    switch (t) {
        case 0: sp = t0; break; case 1: sp = t1; break;
        case 2: sp = t2; break; case 3: sp = t3; break;
        case 4: sp = t4; break; case 5: sp = t5; break;
        case 6: sp = t6; break; case 7: sp = t7; break;
        case 8: sp = t8; break; case 9: sp = t9; break;
        case 10: sp = t10; break; default: sp = t11; break;
    }
    if (isf32) {
        const float4* s = (const float4*)sp + (off >> 2);
        float4 a = s[0], bb = s[1];
        bf16x8 v;
        v[0] = (bf16)a.x;  v[1] = (bf16)a.y;  v[2] = (bf16)a.z;  v[3] = (bf16)a.w;
        v[4] = (bf16)bb.x; v[5] = (bf16)bb.y; v[6] = (bf16)bb.z; v[7] = (bf16)bb.w;
        *(bf16x8*)(conv + e0) = v;
    } else {
        *(uint4*)(conv + e0) = ((const uint4*)sp)[off >> 3];
    }
}

__global__ __launch_bounds__(256) void k_adj(const int* __restrict__ src,
                                             const int* __restrict__ dst,
                                             u32* __restrict__ adj) {
    int e = blockIdx.x * 256 + threadIdx.x;
    int s = src[e], d = dst[e];
    int g = s >> 5;                          // edges are intra-graph
    u32 bidx = ((u32)g << 10) | ((u32)(d & 31) << 5) | (u32)(s & 31);
    atomicAdd(&adj[bidx >> 2], 1u << (8 * (bidx & 3)));
}

__global__ __launch_bounds__(256, 4) void k_mono(
        const void* __restrict__ featv, const void* __restrict__ cntv,
        const bf16* __restrict__ W_in, const bf16* __restrict__ b_in,
        const bf16* __restrict__ W_og, const bf16* __restrict__ b_og,
        const bf16* __restrict__ W_ih, const bf16* __restrict__ b_ih,
        const bf16* __restrict__ W_hh, const bf16* __restrict__ b_hh,
        const bf16* __restrict__ W_u,  const bf16* __restrict__ W_v,
        const bf16* __restrict__ b_v,  const bf16* __restrict__ w_e,
        const int* __restrict__ last_nodes, const u8* __restrict__ adj8,
        const u32* __restrict__ flag, float* __restrict__ out) {
    const int g    = blockIdx.x;
    const int tid  = threadIdx.x;
    const int wave = tid >> 6, lane = tid & 63, q = lane >> 4, c = lane & 15;
    const bool isf32 = (*flag) != 0u;

    const int SF = 136;   // bf16 stride, 128-wide tiles (pad 8)
    const int SC = 264;   // bf16 stride, 256-wide tiles (pad 8)
    const int SA = 40;    // bf16 stride, 32-wide adjacency (pad 8; 2-way banks)
    const int SH = 132;   // bf16 stride, h_n pre-GEMM tile (pad 4 -> quads spread)
    __shared__ __align__(16) bf16 s_feat[32 * 136];   // 8704 B (feat, later hn)
    __shared__ __align__(16) bf16 s_fc  [32 * 264];   // 16896 B (featC, later a)
    __shared__ __align__(16) bf16 s_adjb[32 * 40];    // 2560 B  adj[v][u]
    __shared__ __align__(16) bf16 s_adjT[32 * 40];    // 2560 B  adj[u][v]
    __shared__ __align__(16) bf16 s_hnp [32 * 132];   // 8448 B  h_n = feat@Vn+b
    __shared__ u32   s_adjw[256];                     // 1024 B; aliased by s_fv
    __shared__ float s_invin[32], s_invout[32];
    __shared__ float s_e[32], s_alpha[32];
    float* s_fv = (float*)s_adjw;     // s_adjw dead after phase 1; s_fv phase 4+

    // ---------- phase 0: stage feat (dtype branch) + adjacency ----------
    if (isf32) {
        const float4* fp = (const float4*)((const float*)featv + (size_t)g * 4096);
        for (int ch = tid; ch < 1024; ch += 256) {
            float4 v = fp[ch];
            int row = ch >> 5, off = (ch & 31) * 4;
            bf16* dp = s_feat + row * SF + off;
            dp[0] = (bf16)v.x; dp[1] = (bf16)v.y; dp[2] = (bf16)v.z; dp[3] = (bf16)v.w;
        }
    } else {
        const uint4* fp = (const uint4*)((const bf16*)featv + (size_t)g * 4096);
        for (int ch = tid; ch < 512; ch += 256) {
            int row = ch >> 4, off = (ch & 15) * 8;
            *(uint4*)(s_feat + row * SF + off) = fp[ch];
        }
    }
    s_adjw[tid] = ((const u32*)(adj8 + (size_t)g * 1024))[tid];
    if (tid < 32) s_e[tid] = 0.f;
    __syncthreads();   // B0

    // ---------- phase 1: adj->bf16 (+T), degrees, featC GEMM, h_n GEMM ------
    {
        u32 w = s_adjw[tid];
        int v = tid >> 3, u0 = (tid & 7) * 4;
#pragma unroll
        for (int j = 0; j < 4; ++j) {
            float cv = (float)((w >> (8 * j)) & 0xFFu);
            s_adjb[v * SA + u0 + j] = (bf16)cv;
            s_adjT[(u0 + j) * SA + v] = (bf16)cv;
        }
    }
    if (tid < 32) {                                  // deg_in[v] = row-sum
        u32 s = 0;
        for (int i = 0; i < 8; ++i) {
            u32 w = s_adjw[tid * 8 + i];
            s += (w & 0xFF) + ((w >> 8) & 0xFF) + ((w >> 16) & 0xFF) + (w >> 24);
        }
        s_invin[tid] = 1.f / fmaxf((float)s, 1.f);
    } else if (tid >= 64 && tid < 96) {              // deg_out[u] = col-sum
        int uu = tid - 64; u32 s = 0;
        for (int v = 0; v < 32; ++v)
            s += (s_adjw[v * 8 + (uu >> 2)] >> (8 * (uu & 3))) & 0xFF;
        s_invout[uu] = 1.f / fmaxf((float)s, 1.f);
    }
    // featC = feat @ [W_in; W_og]^T + bias  (32 x 256 -> s_fc), rt-folded
#pragma unroll
    for (int k = 0; k < 4; ++k) {
        int ct = wave + 4 * k;
        int col = ct * 16 + c;
        const bf16* Wp = (col < 128) ? (W_in + col * HDIM) : (W_og + (col - 128) * HDIM);
        const bf16* A0 = s_feat + c * SF;
        const bf16* A1 = s_feat + (16 + c) * SF;
        f32x4 acc0 = {0, 0, 0, 0}, acc1 = {0, 0, 0, 0};
        for (int t = 0; t < 4; ++t) {
            bf16x8 b  = *(const bf16x8*)(Wp + 32 * t + 8 * q);
            bf16x8 a0 = *(const bf16x8*)(A0 + 32 * t + 8 * q);
            bf16x8 a1 = *(const bf16x8*)(A1 + 32 * t + 8 * q);
            acc0 = mfma16(a0, b, acc0);
            acc1 = mfma16(a1, b, acc1);
        }
        float bias = (float)((col < 128) ? b_in[col] : b_og[col - 128]);
#pragma unroll
        for (int r = 0; r < 4; ++r) {
            s_fc[(q * 4 + r) * SC + col]      = (bf16)(acc0[r] + bias);
            s_fc[(16 + q * 4 + r) * SC + col] = (bf16)(acc1[r] + bias);
        }
    }
    // h_n = feat @ W_hh_n^T + b_hh_n  (32 x 128 -> s_hnp); consumed in GRU
    // epilogue. Hoisted here so the GRU phase needs only 6 accumulators
    // (fits the 128-reg alloc needed for 4 waves/SIMD).
#pragma unroll
    for (int k2 = 0; k2 < 2; ++k2) {
        int col = (wave * 2 + k2) * 16 + c;
        const bf16* Vp = W_hh + (256 + col) * HDIM;
        const bf16* A0 = s_feat + c * SF;
        const bf16* A1 = s_feat + (16 + c) * SF;
        f32x4 acc0 = {0, 0, 0, 0}, acc1 = {0, 0, 0, 0};
        for (int t = 0; t < 4; ++t) {
            bf16x8 b  = *(const bf16x8*)(Vp + 32 * t + 8 * q);
            bf16x8 a0 = *(const bf16x8*)(A0 + 32 * t + 8 * q);
            bf16x8 a1 = *(const bf16x8*)(A1 + 32 * t + 8 * q);
            acc0 = mfma16(a0, b, acc0);
            acc1 = mfma16(a1, b, acc1);
        }
        float bh = (float)b_hh[256 + col];
#pragma unroll
        for (int r = 0; r < 4; ++r) {
            s_hnp[(q * 4 + r) * SH + col]      = (bf16)(acc0[r] + bh);
            s_hnp[(16 + q * 4 + r) * SH + col] = (bf16)(acc1[r] + bh);
        }
    }
    __syncthreads();   // B1

    // ---------- phase 2: aggregation via MFMA ----------
    // a_in[v]  = invin[v]  * sum_u adj[v][u] * fin[u]     (cols   0..127)
    // a_out[u] = invout[u] * sum_v adjT[u][v] * fout[v]   (cols 128..255)
    f32x4 agg[8];
#pragma unroll
    for (int k = 0; k < 4; ++k) {
        int ct = wave + 4 * k;
        bf16x8 bfrag;
        const bf16* Bp = s_fc + (q * 8) * SC + ct * 16 + c;
#pragma unroll
        for (int j = 0; j < 8; ++j) bfrag[j] = Bp[j * SC];
        const bf16* Ab = (ct < 8) ? s_adjb : s_adjT;
        bf16x8 a0 = *(const bf16x8*)(Ab + c * SA + 8 * q);
        bf16x8 a1 = *(const bf16x8*)(Ab + (16 + c) * SA + 8 * q);
        f32x4 z = {0, 0, 0, 0};
        agg[2 * k]     = mfma16(a0, bfrag, z);
        agg[2 * k + 1] = mfma16(a1, bfrag, z);
    }
    __syncthreads();   // B2a (all s_fc reads done)
#pragma unroll
    for (int k = 0; k < 4; ++k) {
        int ct = wave + 4 * k;
        const float* inv = (ct < 8) ? s_invin : s_invout;
#pragma unroll
        for (int r = 0; r < 4; ++r) {
            int row0 = q * 4 + r, row1 = 16 + q * 4 + r;
            s_fc[row0 * SC + ct * 16 + c] = (bf16)(agg[2 * k][r] * inv[row0]);
            s_fc[row1 * SC + ct * 16 + c] = (bf16)(agg[2 * k + 1][r] * inv[row1]);
        }
    }
    __syncthreads();   // B2b (s_a ready in s_fc region)
    const bf16* s_a = s_fc;

    // ---------- phase 3: GRU -> hn kept in regs, then written into s_feat ----
    // 6 accumulators: rr = i_r+h_r (fused, bias b_ih+b_hh), zz = i_z+h_z
    // (fused), in = i_n. h_n comes from s_hnp (phase 1). tanh(in + r*h_n).
    float hn_lo[2][4], hn_hi[2][4];
#pragma unroll
    for (int ii = 0; ii < 2; ++ii) {
        int hb = wave + 4 * ii, h0 = hb * 16;
        const bf16* Wr = W_ih + (h0 + c) * 256;
        const bf16* Wz = W_ih + (128 + h0 + c) * 256;
        const bf16* Wn = W_ih + (256 + h0 + c) * 256;
        const bf16* Vr = W_hh + (h0 + c) * HDIM;
        const bf16* Vz = W_hh + (128 + h0 + c) * HDIM;
        const bf16* A0 = s_a + c * SC;
        const bf16* A1 = s_a + (16 + c) * SC;
        const bf16* F0 = s_feat + c * SF;
        const bf16* F1 = s_feat + (16 + c) * SF;
        f32x4 rr0 = {0,0,0,0}, rr1 = {0,0,0,0};   // i_r + h_r (fused)
        f32x4 zz0 = {0,0,0,0}, zz1 = {0,0,0,0};   // i_z + h_z (fused)
        f32x4 in0 = {0,0,0,0}, in1 = {0,0,0,0};   // i_n
        for (int t = 0; t < 8; ++t) {
            bf16x8 a0 = *(const bf16x8*)(A0 + 32 * t + 8 * q);
            bf16x8 a1 = *(const bf16x8*)(A1 + 32 * t + 8 * q);
            bf16x8 br = *(const bf16x8*)(Wr + 32 * t + 8 * q);
            rr0 = mfma16(a0, br, rr0); rr1 = mfma16(a1, br, rr1);
            bf16x8 bz = *(const bf16x8*)(Wz + 32 * t + 8 * q);
            zz0 = mfma16(a0, bz, zz0); zz1 = mfma16(a1, bz, zz1);
            bf16x8 bn = *(const bf16x8*)(Wn + 32 * t + 8 * q);
            in0 = mfma16(a0, bn, in0); in1 = mfma16(a1, bn, in1);
        }
        for (int t = 0; t < 4; ++t) {
            bf16x8 f0 = *(const bf16x8*)(F0 + 32 * t + 8 * q);
            bf16x8 f1 = *(const bf16x8*)(F1 + 32 * t + 8 * q);
            bf16x8 br = *(const bf16x8*)(Vr + 32 * t + 8 * q);
            rr0 = mfma16(f0, br, rr0); rr1 = mfma16(f1, br, rr1);
            bf16x8 bz = *(const bf16x8*)(Vz + 32 * t + 8 * q);
            zz0 = mfma16(f0, bz, zz0); zz1 = mfma16(f1, bz, zz1);
        }
        float brz  = (float)b_ih[h0 + c]       + (float)b_hh[h0 + c];
        float bzz  = (float)b_ih[128 + h0 + c] + (float)b_hh[128 + h0 + c];
        float bin_ = (float)b_ih[256 + h0 + c];
#pragma unroll
        for (int r = 0; r < 4; ++r) {
            int row0 = q * 4 + r, row1 = 16 + q * 4 + r;
            float rg = sigmoidf_(rr0[r] + brz);
            float z_ = sigmoidf_(zz0[r] + bzz);
            float ng = tanhf((in0[r] + bin_) + rg * (float)s_hnp[row0 * SH + h0 + c]);
            float fv = (float)s_feat[row0 * SF + h0 + c];
            hn_lo[ii][r] = (1.f - z_) * ng + z_ * fv;
            rg = sigmoidf_(rr1[r] + brz);
            z_ = sigmoidf_(zz1[r] + bzz);
            ng = tanhf((in1[r] + bin_) + rg * (float)s_hnp[row1 * SH + h0 + c]);
            fv = (float)s_feat[row1 * SF + h0 + c];
            hn_hi[ii][r] = (1.f - z_) * ng + z_ * fv;
        }
    }
    int ll = last_nodes[g] & 31;
    __syncthreads();   // B3a (all s_feat reads done)
#pragma unroll
    for (int ii = 0; ii < 2; ++ii) {
        int h0 = (wave + 4 * ii) * 16;
#pragma unroll
        for (int r = 0; r < 4; ++r) {
            s_feat[(q * 4 + r) * SF + h0 + c]      = (bf16)hn_lo[ii][r];
            s_feat[(16 + q * 4 + r) * SF + h0 + c] = (bf16)hn_hi[ii][r];
        }
    }
    __syncthreads();   // B3b (s_feat now holds hn)
    const bf16* s_hn = s_feat;

    // ---------- phase 4: feat_v = hn[ll] @ W_v^T + b_v (broadcast-A MFMA) ----
#pragma unroll
    for (int k = 0; k < 2; ++k) {
        int ct = wave * 2 + k;
        const bf16* Wp = W_v + (ct * 16 + c) * HDIM;
        const bf16* Ap = s_hn + ll * SF;
        f32x4 acc = {0, 0, 0, 0};
        for (int t = 0; t < 4; ++t) {
            bf16x8 a = *(const bf16x8*)(Ap + 32 * t + 8 * q);
            bf16x8 b = *(const bf16x8*)(Wp + 32 * t + 8 * q);
            acc = mfma16(a, b, acc);
        }
        if (q == 0) s_fv[ct * 16 + c] = acc[0] + (float)b_v[ct * 16 + c];
    }
    __syncthreads();   // B4

    // ---------- phase 5: e[n] = sum_col sigmoid((hn@W_u^T)[n,col]+fv[col])*w_e[col]
#pragma unroll
    for (int k = 0; k < 2; ++k) {
        int ct = wave * 2 + k;
        const bf16* Wp = W_u + (ct * 16 + c) * HDIM;
        const bf16* A0 = s_hn + c * SF;
        const bf16* A1 = s_hn + (16 + c) * SF;
        f32x4 e0 = {0, 0, 0, 0}, e1 = {0, 0, 0, 0};
        for (int t = 0; t < 4; ++t) {
            bf16x8 b  = *(const bf16x8*)(Wp + 32 * t + 8 * q);
            bf16x8 a0 = *(const bf16x8*)(A0 + 32 * t + 8 * q);
            bf16x8 a1 = *(const bf16x8*)(A1 + 32 * t + 8 * q);
            e0 = mfma16(a0, b, e0);
            e1 = mfma16(a1, b, e1);
        }
        int col = ct * 16 + c;
        float we = (float)w_e[col], fv = s_fv[col];
#pragma unroll
        for (int r = 0; r < 4; ++r) {
            float v0 = sigmoidf_(e0[r] + fv) * we;
            float v1 = sigmoidf_(e1[r] + fv) * we;
            for (int m = 1; m < 16; m <<= 1) {
                v0 += __shfl_xor(v0, m);
                v1 += __shfl_xor(v1, m);
            }
            if (c == 0) {
                atomicAdd(&s_e[q * 4 + r], v0);
                atomicAdd(&s_e[16 + q * 4 + r], v1);
            }
        }
    }
    __syncthreads();   // B5
    if (tid < 32) {
        float cv = isf32 ? ((const float*)cntv)[(size_t)g * 32 + tid]
                         : (float)((const bf16*)cntv)[(size_t)g * 32 + tid];
        s_alpha[tid] = s_e[tid] * cv;
    }
    __syncthreads();   // B6

    // ---------- output (f32): [ct_g (128) | ct_l (128)] ----------
    if (tid < 128) {
        float s = 0.f;
        for (int n = 0; n < 32; ++n) s += s_alpha[n] * (float)s_hn[n * SF + tid];
        out[(size_t)g * 256 + tid] = s;
    } else {
        int h = tid - 128;
        out[(size_t)g * 256 + 128 + h] = (float)s_hn[ll * SF + h];
    }
}

extern "C" void kernel_launch(void* const* d_in, const int* in_sizes, int n_in,
                              void* d_out, int out_size, void* d_ws, size_t ws_size,
                              hipStream_t stream) {
    const int* src  = (const int*)d_in[14];
    const int* dst  = (const int*)d_in[15];
    const int* last = (const int*)d_in[17];
    float* out = (float*)d_out;

    u32*  flag = (u32*)d_ws;
    bf16* conv = (bf16*)((char*)d_ws + 4096);
    u32*  adjw = (u32*)((char*)d_ws + (1u << 20));
    const u8* adj8 = (const u8*)adjw;

    // bf16 weight copies, contiguous in input order 2..13
    const int cnts[12] = {16384, 128, 16384, 128, 98304, 384, 49152, 384,
                          16384, 16384, 128, 128};
    bf16* cp[12];
    {
        bf16* p = conv;
        for (int i = 0; i < 12; ++i) { cp[i] = p; p += cnts[i]; }
    }

    k_prep<<<2048 + (NCONV + 2047) / 2048, 256, 0, stream>>>(
        (const u32*)d_in[0], adjw, conv, flag,
        d_in[2], d_in[3], d_in[4], d_in[5], d_in[6], d_in[7],
        d_in[8], d_in[9], d_in[10], d_in[11], d_in[12], d_in[13]);
    k_adj<<<NEDGE / 256, 256, 0, stream>>>(src, dst, adjw);
    k_mono<<<NG, 256, 0, stream>>>(d_in[0], d_in[1],
                                   cp[0], cp[1], cp[2], cp[3],
                                   cp[4], cp[5], cp[6], cp[7],
                                   cp[8], cp[9], cp[10], cp[11],
                                   last, adj8, flag, out);
}

// Round 4
// 638.098 us; speedup vs baseline: 1.2030x; 1.0721x over previous
//
#include <hip/hip_runtime.h>

// SRGNN — Round 12: shrink code size (I-cache theory).
//  r8-r11 pattern: dur ~550-630us INSENSITIVE to HBM traffic (622MB->8MB write:
//  -60us) and occupancy (23%->46%: +5us); all pipes idle (VALU 23%, MFMA 8.5%);
//  per-block latency ~81K cycles, ~20x any data-side model. Only theory that
//  reaches that scale: L1 I-cache (32KB) thrashing — the monolithic unrolled
//  kernel is ~30-50KB of text (~210 MFMA sites + 8 inlined tanhf/thread), so
//  every fetch group misses to L2 (~200cy).
//  Fix: roll inner t-loops (#pragma unroll 1) in GRU/featC/hnp/ph4/ph5 (keep
//  unrolled only where static reg indexing requires: phase-2 agg[], ii=2 GRU
//  outer); tanhf -> 3-op __expf form. Expected text ~4x smaller. Side benefit:
//  rolled loops shrink live ranges -> 6-acc GRU should fit 128 regs for real
//  -> keep __launch_bounds__(256,4).
//  Discriminator: dur <250us => I$ confirmed; dur flat => theory dead.
//  Tripwire: WRITE_SIZE >> 8.2MB => spill again => fall back (256,2)+rolled.
// ws: [0] u32 flag ; [4KiB] bf16 weight copies (~419KB) ; [1MiB] adj u8 (8MB).

#define NG    8192
#define NODES 32
#define HDIM  128
#define NEDGE 524288
#define NCONV 214272   // total weight elements (inputs 2..13)

typedef __bf16 bf16;
typedef __bf16 bf16x8 __attribute__((ext_vector_type(8)));
typedef float  f32x4  __attribute__((ext_vector_type(4)));
typedef unsigned int u32;
typedef unsigned char u8;

__device__ __forceinline__ f32x4 mfma16(bf16x8 a, bf16x8 b, f32x4 c) {
    // D = A(16x32)*B(32x16)+C ; A[m=lane&15][k=quad*8+j], B[k=quad*8+j][n=lane&15],
    // D[row=quad*4+r][col=lane&15]  (verified: r3 MFMA == r4 scalar bit-exact)
    return __builtin_amdgcn_mfma_f32_16x16x32_bf16(a, b, c, 0, 0, 0);
}

__device__ __forceinline__ float sigmoidf_(float x) { return 1.f / (1.f + __expf(-x)); }
// tanh via exp2-based __expf: saturates correctly (x->+inf: 1, x->-inf: -1).
__device__ __forceinline__ float tanhf_(float x) { return 1.f - 2.f / (__expf(2.f * x) + 1.f); }

// ---- k_prep: blocks [0,2048) zero adj; blocks [2048,2153) convert weights ----
// Convert blocks self-detect f32-vs-bf16 by scanning the first 4096 words of
// feat (f32 data hits the 0xFF pseudo-exponent pattern w.p. 1-e^-16).
__global__ __launch_bounds__(256) void k_prep(
        const u32* __restrict__ featw, u32* __restrict__ adjw,
        bf16* __restrict__ conv, u32* __restrict__ flagout,
        const void* t0, const void* t1, const void* t2,  const void* t3,
        const void* t4, const void* t5, const void* t6,  const void* t7,
        const void* t8, const void* t9, const void* t10, const void* t11) {
    const int b = blockIdx.x, tid = threadIdx.x;
    if (b < 2048) {                       // zero 8MB of adj
        int i = b * 1024 + tid * 4;
        *(uint4*)(adjw + i) = make_uint4(0u, 0u, 0u, 0u);
        return;
    }
    __shared__ int s_isf32;
    if (tid == 0) s_isf32 = 0;
    __syncthreads();
    {
        u32 hit = 0;
#pragma unroll
        for (int k = 0; k < 16; ++k) {
            u32 x = featw[tid * 16 + k];
            hit |= (((x >> 7) & 0xFFu) == 0xFFu) ? 1u : 0u;
        }
        if (hit) s_isf32 = 1;             // benign race
    }
    __syncthreads();
    const bool isf32 = s_isf32 != 0;
    if (b == 2048 && tid == 0) *flagout = isf32 ? 1u : 0u;

    int e0 = (b - 2048) * 2048 + tid * 8;
    if (e0 >= NCONV) return;
    // tensor boundaries (all sizes multiples of 128, so groups of 8 never straddle)
    const int cnts[12] = {16384, 128, 16384, 128, 98304, 384, 49152, 384,
                          16384, 16384, 128, 128};
    int t = 0, base = 0;
    while (e0 >= base + cnts[t]) { base += cnts[t]; ++t; }
    int off = e0 - base;
    const void* sp;
    switch (t) {
        case 0: sp = t0; break; case 1: sp = t1; break;
        case 2: sp = t2; break; case 3: sp = t3; break;
        case 4: sp = t4; break; case 5: sp = t5; break;
        case 6: sp = t6; break; case 7: sp = t7; break;
        case 8: sp = t8; break; case 9: sp = t9; break;
        case 10: sp = t10; break; default: sp = t11; break;
    }
    if (isf32) {
        const float4* s = (const float4*)sp + (off >> 2);
        float4 a = s[0], bb = s[1];
        bf16x8 v;
        v[0] = (bf16)a.x;  v[1] = (bf16)a.y;  v[2] = (bf16)a.z;  v[3] = (bf16)a.w;
        v[4] = (bf16)bb.x; v[5] = (bf16)bb.y; v[6] = (bf16)bb.z; v[7] = (bf16)bb.w;
        *(bf16x8*)(conv + e0) = v;
    } else {
        *(uint4*)(conv + e0) = ((const uint4*)sp)[off >> 3];
    }
}

__global__ __launch_bounds__(256) void k_adj(const int* __restrict__ src,
                                             const int* __restrict__ dst,
                                             u32* __restrict__ adj) {
    int e = blockIdx.x * 256 + threadIdx.x;
    int s = src[e], d = dst[e];
    int g = s >> 5;                          // edges are intra-graph
    u32 bidx = ((u32)g << 10) | ((u32)(d & 31) << 5) | (u32)(s & 31);
    atomicAdd(&adj[bidx >> 2], 1u << (8 * (bidx & 3)));
}

__global__ __launch_bounds__(256, 4) void k_mono(
        const void* __restrict__ featv, const void* __restrict__ cntv,
        const bf16* __restrict__ W_in, const bf16* __restrict__ b_in,
        const bf16* __restrict__ W_og, const bf16* __restrict__ b_og,
        const bf16* __restrict__ W_ih, const bf16* __restrict__ b_ih,
        const bf16* __restrict__ W_hh, const bf16* __restrict__ b_hh,
        const bf16* __restrict__ W_u,  const bf16* __restrict__ W_v,
        const bf16* __restrict__ b_v,  const bf16* __restrict__ w_e,
        const int* __restrict__ last_nodes, const u8* __restrict__ adj8,
        const u32* __restrict__ flag, float* __restrict__ out) {
    const int g    = blockIdx.x;
    const int tid  = threadIdx.x;
    const int wave = tid >> 6, lane = tid & 63, q = lane >> 4, c = lane & 15;
    const bool isf32 = (*flag) != 0u;

    const int SF = 136;   // bf16 stride, 128-wide tiles (pad 8)
    const int SC = 264;   // bf16 stride, 256-wide tiles (pad 8)
    const int SA = 40;    // bf16 stride, 32-wide adjacency (pad 8; 2-way banks)
    const int SH = 132;   // bf16 stride, h_n pre-GEMM tile (pad 4 -> quads spread)
    __shared__ __align__(16) bf16 s_feat[32 * 136];   // 8704 B (feat, later hn)
    __shared__ __align__(16) bf16 s_fc  [32 * 264];   // 16896 B (featC, later a)
    __shared__ __align__(16) bf16 s_adjb[32 * 40];    // 2560 B  adj[v][u]
    __shared__ __align__(16) bf16 s_adjT[32 * 40];    // 2560 B  adj[u][v]
    __shared__ __align__(16) bf16 s_hnp [32 * 132];   // 8448 B  h_n = feat@Vn+b
    __shared__ u32   s_adjw[256];                     // 1024 B; aliased by s_fv
    __shared__ float s_invin[32], s_invout[32];
    __shared__ float s_e[32], s_alpha[32];
    float* s_fv = (float*)s_adjw;     // s_adjw dead after phase 1; s_fv phase 4+

    // ---------- phase 0: stage feat (dtype branch) + adjacency ----------
    if (isf32) {
        const float4* fp = (const float4*)((const float*)featv + (size_t)g * 4096);
        for (int ch = tid; ch < 1024; ch += 256) {
            float4 v = fp[ch];
            int row = ch >> 5, off = (ch & 31) * 4;
            bf16* dp = s_feat + row * SF + off;
            dp[0] = (bf16)v.x; dp[1] = (bf16)v.y; dp[2] = (bf16)v.z; dp[3] = (bf16)v.w;
        }
    } else {
        const uint4* fp = (const uint4*)((const bf16*)featv + (size_t)g * 4096);
        for (int ch = tid; ch < 512; ch += 256) {
            int row = ch >> 4, off = (ch & 15) * 8;
            *(uint4*)(s_feat + row * SF + off) = fp[ch];
        }
    }
    s_adjw[tid] = ((const u32*)(adj8 + (size_t)g * 1024))[tid];
    if (tid < 32) s_e[tid] = 0.f;
    __syncthreads();   // B0

    // ---------- phase 1: adj->bf16 (+T), degrees, featC GEMM, h_n GEMM ------
    {
        u32 w = s_adjw[tid];
        int v = tid >> 3, u0 = (tid & 7) * 4;
#pragma unroll
        for (int j = 0; j < 4; ++j) {
            float cv = (float)((w >> (8 * j)) & 0xFFu);
            s_adjb[v * SA + u0 + j] = (bf16)cv;
            s_adjT[(u0 + j) * SA + v] = (bf16)cv;
        }
    }
    if (tid < 32) {                                  // deg_in[v] = row-sum
        u32 s = 0;
        for (int i = 0; i < 8; ++i) {
            u32 w = s_adjw[tid * 8 + i];
            s += (w & 0xFF) + ((w >> 8) & 0xFF) + ((w >> 16) & 0xFF) + (w >> 24);
        }
        s_invin[tid] = 1.f / fmaxf((float)s, 1.f);
    } else if (tid >= 64 && tid < 96) {              // deg_out[u] = col-sum
        int uu = tid - 64; u32 s = 0;
        for (int v = 0; v < 32; ++v)
            s += (s_adjw[v * 8 + (uu >> 2)] >> (8 * (uu & 3))) & 0xFF;
        s_invout[uu] = 1.f / fmaxf((float)s, 1.f);
    }
    // featC = feat @ [W_in; W_og]^T + bias  (32 x 256 -> s_fc), rt-folded
    // Rolled (unroll 1) to keep text small — I$ is the suspected bottleneck.
#pragma unroll 1
    for (int k = 0; k < 4; ++k) {
        int ct = wave + 4 * k;
        int col = ct * 16 + c;
        const bf16* Wp = (col < 128) ? (W_in + col * HDIM) : (W_og + (col - 128) * HDIM);
        const bf16* A0 = s_feat + c * SF;
        const bf16* A1 = s_feat + (16 + c) * SF;
        f32x4 acc0 = {0, 0, 0, 0}, acc1 = {0, 0, 0, 0};
#pragma unroll 1
        for (int t = 0; t < 4; ++t) {
            bf16x8 b  = *(const bf16x8*)(Wp + 32 * t + 8 * q);
            bf16x8 a0 = *(const bf16x8*)(A0 + 32 * t + 8 * q);
            bf16x8 a1 = *(const bf16x8*)(A1 + 32 * t + 8 * q);
            acc0 = mfma16(a0, b, acc0);
            acc1 = mfma16(a1, b, acc1);
        }
        float bias = (float)((col < 128) ? b_in[col] : b_og[col - 128]);
#pragma unroll
        for (int r = 0; r < 4; ++r) {
            s_fc[(q * 4 + r) * SC + col]      = (bf16)(acc0[r] + bias);
            s_fc[(16 + q * 4 + r) * SC + col] = (bf16)(acc1[r] + bias);
        }
    }
    // h_n = feat @ W_hh_n^T + b_hh_n  (32 x 128 -> s_hnp); consumed in GRU
    // epilogue (keeps the GRU phase at 6 accumulators).
#pragma unroll 1
    for (int k2 = 0; k2 < 2; ++k2) {
        int col = (wave * 2 + k2) * 16 + c;
        const bf16* Vp = W_hh + (256 + col) * HDIM;
        const bf16* A0 = s_feat + c * SF;
        const bf16* A1 = s_feat + (16 + c) * SF;
        f32x4 acc0 = {0, 0, 0, 0}, acc1 = {0, 0, 0, 0};
#pragma unroll 1
        for (int t = 0; t < 4; ++t) {
            bf16x8 b  = *(const bf16x8*)(Vp + 32 * t + 8 * q);
            bf16x8 a0 = *(const bf16x8*)(A0 + 32 * t + 8 * q);
            bf16x8 a1 = *(const bf16x8*)(A1 + 32 * t + 8 * q);
            acc0 = mfma16(a0, b, acc0);
            acc1 = mfma16(a1, b, acc1);
        }
        float bh = (float)b_hh[256 + col];
#pragma unroll
        for (int r = 0; r < 4; ++r) {
            s_hnp[(q * 4 + r) * SH + col]      = (bf16)(acc0[r] + bh);
            s_hnp[(16 + q * 4 + r) * SH + col] = (bf16)(acc1[r] + bh);
        }
    }
    __syncthreads();   // B1

    // ---------- phase 2: aggregation via MFMA ----------
    // a_in[v]  = invin[v]  * sum_u adj[v][u] * fin[u]     (cols   0..127)
    // a_out[u] = invout[u] * sum_v adjT[u][v] * fout[v]   (cols 128..255)
    // agg[] must stay fully unrolled (static reg indexing, rule #20).
    f32x4 agg[8];
#pragma unroll
    for (int k = 0; k < 4; ++k) {
        int ct = wave + 4 * k;
        bf16x8 bfrag;
        const bf16* Bp = s_fc + (q * 8) * SC + ct * 16 + c;
#pragma unroll
        for (int j = 0; j < 8; ++j) bfrag[j] = Bp[j * SC];
        const bf16* Ab = (ct < 8) ? s_adjb : s_adjT;
        bf16x8 a0 = *(const bf16x8*)(Ab + c * SA + 8 * q);
        bf16x8 a1 = *(const bf16x8*)(Ab + (16 + c) * SA + 8 * q);
        f32x4 z = {0, 0, 0, 0};
        agg[2 * k]     = mfma16(a0, bfrag, z);
        agg[2 * k + 1] = mfma16(a1, bfrag, z);
    }
    __syncthreads();   // B2a (all s_fc reads done)
#pragma unroll
    for (int k = 0; k < 4; ++k) {
        int ct = wave + 4 * k;
        const float* inv = (ct < 8) ? s_invin : s_invout;
#pragma unroll
        for (int r = 0; r < 4; ++r) {
            int row0 = q * 4 + r, row1 = 16 + q * 4 + r;
            s_fc[row0 * SC + ct * 16 + c] = (bf16)(agg[2 * k][r] * inv[row0]);
            s_fc[row1 * SC + ct * 16 + c] = (bf16)(agg[2 * k + 1][r] * inv[row1]);
        }
    }
    __syncthreads();   // B2b (s_a ready in s_fc region)
    const bf16* s_a = s_fc;

    // ---------- phase 3: GRU -> hn kept in regs, then written into s_feat ----
    // 6 accumulators: rr = i_r+h_r (fused, bias b_ih+b_hh), zz = i_z+h_z
    // (fused), in = i_n. h_n comes from s_hnp (phase 1). tanh(in + r*h_n).
    // Inner t-loops rolled: biggest code block in the kernel (was ~128 MFMA
    // sites unrolled).
    float hn_lo[2][4], hn_hi[2][4];
#pragma unroll
    for (int ii = 0; ii < 2; ++ii) {
        int hb = wave + 4 * ii, h0 = hb * 16;
        const bf16* Wr = W_ih + (h0 + c) * 256;
        const bf16* Wz = W_ih + (128 + h0 + c) * 256;
        const bf16* Wn = W_ih + (256 + h0 + c) * 256;
        const bf16* Vr = W_hh + (h0 + c) * HDIM;
        const bf16* Vz = W_hh + (128 + h0 + c) * HDIM;
        const bf16* A0 = s_a + c * SC;
        const bf16* A1 = s_a + (16 + c) * SC;
        const bf16* F0 = s_feat + c * SF;
        const bf16* F1 = s_feat + (16 + c) * SF;
        f32x4 rr0 = {0,0,0,0}, rr1 = {0,0,0,0};   // i_r + h_r (fused)
        f32x4 zz0 = {0,0,0,0}, zz1 = {0,0,0,0};   // i_z + h_z (fused)
        f32x4 in0 = {0,0,0,0}, in1 = {0,0,0,0};   // i_n
#pragma unroll 1
        for (int t = 0; t < 8; ++t) {
            bf16x8 a0 = *(const bf16x8*)(A0 + 32 * t + 8 * q);
            bf16x8 a1 = *(const bf16x8*)(A1 + 32 * t + 8 * q);
            bf16x8 br = *(const bf16x8*)(Wr + 32 * t + 8 * q);
            rr0 = mfma16(a0, br, rr0); rr1 = mfma16(a1, br, rr1);
            bf16x8 bz = *(const bf16x8*)(Wz + 32 * t + 8 * q);
            zz0 = mfma16(a0, bz, zz0); zz1 = mfma16(a1, bz, zz1);
            bf16x8 bn = *(const bf16x8*)(Wn + 32 * t + 8 * q);
            in0 = mfma16(a0, bn, in0); in1 = mfma16(a1, bn, in1);
        }
#pragma unroll 1
        for (int t = 0; t < 4; ++t) {
            bf16x8 f0 = *(const bf16x8*)(F0 + 32 * t + 8 * q);
            bf16x8 f1 = *(const bf16x8*)(F1 + 32 * t + 8 * q);
            bf16x8 br = *(const bf16x8*)(Vr + 32 * t + 8 * q);
            rr0 = mfma16(f0, br, rr0); rr1 = mfma16(f1, br, rr1);
            bf16x8 bz = *(const bf16x8*)(Vz + 32 * t + 8 * q);
            zz0 = mfma16(f0, bz, zz0); zz1 = mfma16(f1, bz, zz1);
        }
        float brz  = (float)b_ih[h0 + c]       + (float)b_hh[h0 + c];
        float bzz  = (float)b_ih[128 + h0 + c] + (float)b_hh[128 + h0 + c];
        float bin_ = (float)b_ih[256 + h0 + c];
#pragma unroll
        for (int r = 0; r < 4; ++r) {
            int row0 = q * 4 + r, row1 = 16 + q * 4 + r;
            float rg = sigmoidf_(rr0[r] + brz);
            float z_ = sigmoidf_(zz0[r] + bzz);
            float ng = tanhf_((in0[r] + bin_) + rg * (float)s_hnp[row0 * SH + h0 + c]);
            float fv = (float)s_feat[row0 * SF + h0 + c];
            hn_lo[ii][r] = (1.f - z_) * ng + z_ * fv;
            rg = sigmoidf_(rr1[r] + brz);
            z_ = sigmoidf_(zz1[r] + bzz);
            ng = tanhf_((in1[r] + bin_) + rg * (float)s_hnp[row1 * SH + h0 + c]);
            fv = (float)s_feat[row1 * SF + h0 + c];
            hn_hi[ii][r] = (1.f - z_) * ng + z_ * fv;
        }
    }
    int ll = last_nodes[g] & 31;
    __syncthreads();   // B3a (all s_feat reads done)
#pragma unroll
    for (int ii = 0; ii < 2; ++ii) {
        int h0 = (wave + 4 * ii) * 16;
#pragma unroll
        for (int r = 0; r < 4; ++r) {
            s_feat[(q * 4 + r) * SF + h0 + c]      = (bf16)hn_lo[ii][r];
            s_feat[(16 + q * 4 + r) * SF + h0 + c] = (bf16)hn_hi[ii][r];
        }
    }
    __syncthreads();   // B3b (s_feat now holds hn)
    const bf16* s_hn = s_feat;

    // ---------- phase 4: feat_v = hn[ll] @ W_v^T + b_v (broadcast-A MFMA) ----
#pragma unroll 1
    for (int k = 0; k < 2; ++k) {
        int ct = wave * 2 + k;
        const bf16* Wp = W_v + (ct * 16 + c) * HDIM;
        const bf16* Ap = s_hn + ll * SF;
        f32x4 acc = {0, 0, 0, 0};
#pragma unroll 1
        for (int t = 0; t < 4; ++t) {
            bf16x8 a = *(const bf16x8*)(Ap + 32 * t + 8 * q);
            bf16x8 b = *(const bf16x8*)(Wp + 32 * t + 8 * q);
            acc = mfma16(a, b, acc);
        }
        if (q == 0) s_fv[ct * 16 + c] = acc[0] + (float)b_v[ct * 16 + c];
    }
    __syncthreads();   // B4

    // ---------- phase 5: e[n] = sum_col sigmoid((hn@W_u^T)[n,col]+fv[col])*w_e[col]
#pragma unroll 1
    for (int k = 0; k < 2; ++k) {
        int ct = wave * 2 + k;
        const bf16* Wp = W_u + (ct * 16 + c) * HDIM;
        const bf16* A0 = s_hn + c * SF;
        const bf16* A1 = s_hn + (16 + c) * SF;
        f32x4 e0 = {0, 0, 0, 0}, e1 = {0, 0, 0, 0};
#pragma unroll 1
        for (int t = 0; t < 4; ++t) {
            bf16x8 b  = *(const bf16x8*)(Wp + 32 * t + 8 * q);
            bf16x8 a0 = *(const bf16x8*)(A0 + 32 * t + 8 * q);
            bf16x8 a1 = *(const bf16x8*)(A1 + 32 * t + 8 * q);
            e0 = mfma16(a0, b, e0);
            e1 = mfma16(a1, b, e1);
        }
        int col = ct * 16 + c;
        float we = (float)w_e[col], fv = s_fv[col];
#pragma unroll
        for (int r = 0; r < 4; ++r) {
            float v0 = sigmoidf_(e0[r] + fv) * we;
            float v1 = sigmoidf_(e1[r] + fv) * we;
            for (int m = 1; m < 16; m <<= 1) {
                v0 += __shfl_xor(v0, m);
                v1 += __shfl_xor(v1, m);
            }
            if (c == 0) {
                atomicAdd(&s_e[q * 4 + r], v0);
                atomicAdd(&s_e[16 + q * 4 + r], v1);
            }
        }
    }
    __syncthreads();   // B5
    if (tid < 32) {
        float cv = isf32 ? ((const float*)cntv)[(size_t)g * 32 + tid]
                         : (float)((const bf16*)cntv)[(size_t)g * 32 + tid];
        s_alpha[tid] = s_e[tid] * cv;
    }
    __syncthreads();   // B6

    // ---------- output (f32): [ct_g (128) | ct_l (128)] ----------
    if (tid < 128) {
        float s = 0.f;
#pragma unroll 4
        for (int n = 0; n < 32; ++n) s += s_alpha[n] * (float)s_hn[n * SF + tid];
        out[(size_t)g * 256 + tid] = s;
    } else {
        int h = tid - 128;
        out[(size_t)g * 256 + 128 + h] = (float)s_hn[ll * SF + h];
    }
}

extern "C" void kernel_launch(void* const* d_in, const int* in_sizes, int n_in,
                              void* d_out, int out_size, void* d_ws, size_t ws_size,
                              hipStream_t stream) {
    const int* src  = (const int*)d_in[14];
    const int* dst  = (const int*)d_in[15];
    const int* last = (const int*)d_in[17];
    float* out = (float*)d_out;

    u32*  flag = (u32*)d_ws;
    bf16* conv = (bf16*)((char*)d_ws + 4096);
    u32*  adjw = (u32*)((char*)d_ws + (1u << 20));
    const u8* adj8 = (const u8*)adjw;

    // bf16 weight copies, contiguous in input order 2..13
    const int cnts[12] = {16384, 128, 16384, 128, 98304, 384, 49152, 384,
                          16384, 16384, 128, 128};
    bf16* cp[12];
    {
        bf16* p = conv;
        for (int i = 0; i < 12; ++i) { cp[i] = p; p += cnts[i]; }
    }

    k_prep<<<2048 + (NCONV + 2047) / 2048, 256, 0, stream>>>(
        (const u32*)d_in[0], adjw, conv, flag,
        d_in[2], d_in[3], d_in[4], d_in[5], d_in[6], d_in[7],
        d_in[8], d_in[9], d_in[10], d_in[11], d_in[12], d_in[13]);
    k_adj<<<NEDGE / 256, 256, 0, stream>>>(src, dst, adjw);
    k_mono<<<NG, 256, 0, stream>>>(d_in[0], d_in[1],
                                   cp[0], cp[1], cp[2], cp[3],
                                   cp[4], cp[5], cp[6], cp[7],
                                   cp[8], cp[9], cp[10], cp[11],
                                   last, adj8, flag, out);
}

// Round 5
// 627.852 us; speedup vs baseline: 1.2226x; 1.0163x over previous
//
#include <hip/hip_runtime.h>

// SRGNN — Round 13: algebraic fusion — delete the featC GEMM.
//  r12 state: spill dead (WRITE=8.2MB=output), traffic ideal, occupancy at its
//  HARD CAP (128-reg waves -> 4/SIMD; 64-reg -> spill; LDS 40KB -> 4 blk/CU),
//  all pipes <30%. Remaining 480us = per-block serial phase chain.
//  Fix (math, not scheduling): D^-1 is a left diagonal, so
//    a_in @ W_ih_in^T = (D^-1 A feat) W_in^T W_ih_in^T = P_in @ U_in
//  with U = [W_in^T W_ih_in^T ; W_og^T W_ih_out^T] (256x384) PRECOMPUTED once
//  (new k_fuse, 24 blocks). k_mono then: P = [invin*(adj@feat)|invout*(adjT@
//  feat)] (K=32, no weights) feeds the GRU directly. featC GEMM + W_in/W_og
//  streams + one barrier deleted; MFMA/wave 208->176.
//  Bias subtlety: reference folds b_in/b_og into feat BEFORE aggregation ->
//  survives as 1[deg>0]*(b@W_ih^T): precomputed bw_in/bw_og vectors + per-node
//  indicator s_din/s_dout.
//  Tripwire: WRITE_SIZE >> 8.2MB => spill came back.
// ws: [0] flag ; [4K] bf16 conv (~419KB) ; [430K] bw_in/bw_og f32 (384 ea) ;
//     [448K] u_t bf16 384x256 (192KB) ; [1MiB] adj u8 (8MB).

#define NG    8192
#define NODES 32
#define HDIM  128
#define NEDGE 524288
#define NCONV 214272   // total weight elements (inputs 2..13)

typedef __bf16 bf16;
typedef __bf16 bf16x8 __attribute__((ext_vector_type(8)));
typedef float  f32x4  __attribute__((ext_vector_type(4)));
typedef unsigned int u32;
typedef unsigned char u8;

__device__ __forceinline__ f32x4 mfma16(bf16x8 a, bf16x8 b, f32x4 c) {
    // D = A(16x32)*B(32x16)+C ; A[m=lane&15][k=quad*8+j], B[k=quad*8+j][n=lane&15],
    // D[row=quad*4+r][col=lane&15]  (verified: r3 MFMA == r4 scalar bit-exact)
    return __builtin_amdgcn_mfma_f32_16x16x32_bf16(a, b, c, 0, 0, 0);
}

__device__ __forceinline__ float sigmoidf_(float x) { return 1.f / (1.f + __expf(-x)); }
__device__ __forceinline__ float tanhf_(float x) { return 1.f - 2.f / (__expf(2.f * x) + 1.f); }

// ---- k_prep: blocks [0,2048) zero adj; blocks [2048,2153) convert weights ----
__global__ __launch_bounds__(256) void k_prep(
        const u32* __restrict__ featw, u32* __restrict__ adjw,
        bf16* __restrict__ conv, u32* __restrict__ flagout,
        const void* t0, const void* t1, const void* t2,  const void* t3,
        const void* t4, const void* t5, const void* t6,  const void* t7,
        const void* t8, const void* t9, const void* t10, const void* t11) {
    const int b = blockIdx.x, tid = threadIdx.x;
    if (b < 2048) {                       // zero 8MB of adj
        int i = b * 1024 + tid * 4;
        *(uint4*)(adjw + i) = make_uint4(0u, 0u, 0u, 0u);
        return;
    }
    __shared__ int s_isf32;
    if (tid == 0) s_isf32 = 0;
    __syncthreads();
    {
        u32 hit = 0;
#pragma unroll
        for (int k = 0; k < 16; ++k) {
            u32 x = featw[tid * 16 + k];
            hit |= (((x >> 7) & 0xFFu) == 0xFFu) ? 1u : 0u;
        }
        if (hit) s_isf32 = 1;             // benign race
    }
    __syncthreads();
    const bool isf32 = s_isf32 != 0;
    if (b == 2048 && tid == 0) *flagout = isf32 ? 1u : 0u;

    int e0 = (b - 2048) * 2048 + tid * 8;
    if (e0 >= NCONV) return;
    const int cnts[12] = {16384, 128, 16384, 128, 98304, 384, 49152, 384,
                          16384, 16384, 128, 128};
    int t = 0, base = 0;
    while (e0 >= base + cnts[t]) { base += cnts[t]; ++t; }
    int off = e0 - base;
    const void* sp;
    switch (t) {
        case 0: sp = t0; break; case 1: sp = t1; break;
        case 2: sp = t2; break; case 3: sp = t3; break;
        case 4: sp = t4; break; case 5: sp = t5; break;
        case 6: sp = t6; break; case 7: sp = t7; break;
        case 8: sp = t8; break; case 9: sp = t9; break;
        case 10: sp = t10; break; default: sp = t11; break;
    }
    if (isf32) {
        const float4* s = (const float4*)sp + (off >> 2);
        float4 a = s[0], bb = s[1];
        bf16x8 v;
        v[0] = (bf16)a.x;  v[1] = (bf16)a.y;  v[2] = (bf16)a.z;  v[3] = (bf16)a.w;
        v[4] = (bf16)bb.x; v[5] = (bf16)bb.y; v[6] = (bf16)bb.z; v[7] = (bf16)bb.w;
        *(bf16x8*)(conv + e0) = v;
    } else {
        *(uint4*)(conv + e0) = ((const uint4*)sp)[off >> 3];
    }
}

// ---- k_fuse: U = [W_in^T@W_ih_in^T ; W_og^T@W_ih_out^T] stored as u_t[384][256]
// (row j = gi col, col k = P col), + bw_in[j]=sum_m b_in[m]*W_ih[j][m],
// bw_og[j]=sum_m b_og[m]*W_ih[j][128+m]. 24 blocks x 256 thr.
__global__ __launch_bounds__(256) void k_fuse(
        const bf16* __restrict__ W_in, const bf16* __restrict__ b_in,
        const bf16* __restrict__ W_og, const bf16* __restrict__ b_og,
        const bf16* __restrict__ W_ih, const bf16* __restrict__ b_ih,
        bf16* __restrict__ u_t, float* __restrict__ bw_in,
        float* __restrict__ bw_og) {
    const int jt = blockIdx.x;                 // 0..23
    const int tid = threadIdx.x;
    const int wave = tid >> 6, lane = tid & 63, q = lane >> 4, c = lane & 15;
#pragma unroll 1
    for (int k2 = 0; k2 < 4; ++k2) {
        int kt = wave * 4 + k2;                // 0..15 (col tile of 256)
        bool og = kt >= 8;
        const bf16* Wsrc = og ? W_og : W_in;   // [128][128] row-major
        int kcol = (kt & 7) * 16 + c;          // 0..127
        int mo = og ? 128 : 0;
        f32x4 acc = {0, 0, 0, 0};
#pragma unroll 1
        for (int t = 0; t < 4; ++t) {
            bf16x8 a = *(const bf16x8*)(W_ih + (jt * 16 + c) * 256 + mo + 32 * t + 8 * q);
            bf16x8 b;
#pragma unroll
            for (int jj = 0; jj < 8; ++jj)
                b[jj] = Wsrc[(32 * t + 8 * q + jj) * 128 + kcol];
            acc = mfma16(a, b, acc);
        }
#pragma unroll
        for (int r = 0; r < 4; ++r)
            u_t[(size_t)(jt * 16 + q * 4 + r) * 256 + kt * 16 + c] = (bf16)acc[r];
    }
    if (tid < 16) {
        int j = jt * 16 + tid;
        float si = 0.f, so = 0.f;
        for (int m = 0; m < 128; ++m) {
            si += (float)b_in[m] * (float)W_ih[j * 256 + m];
            so += (float)b_og[m] * (float)W_ih[j * 256 + 128 + m];
        }
        bw_in[j] = si;
        bw_og[j] = so;
    }
}

__global__ __launch_bounds__(256) void k_adj(const int* __restrict__ src,
                                             const int* __restrict__ dst,
                                             u32* __restrict__ adj) {
    int e = blockIdx.x * 256 + threadIdx.x;
    int s = src[e], d = dst[e];
    int g = s >> 5;                          // edges are intra-graph
    u32 bidx = ((u32)g << 10) | ((u32)(d & 31) << 5) | (u32)(s & 31);
    atomicAdd(&adj[bidx >> 2], 1u << (8 * (bidx & 3)));
}

__global__ __launch_bounds__(256, 4) void k_mono(
        const void* __restrict__ featv, const void* __restrict__ cntv,
        const bf16* __restrict__ u_t,  const bf16* __restrict__ b_ih,
        const bf16* __restrict__ W_hh, const bf16* __restrict__ b_hh,
        const bf16* __restrict__ W_u,  const bf16* __restrict__ W_v,
        const bf16* __restrict__ b_v,  const bf16* __restrict__ w_e,
        const float* __restrict__ bw_in, const float* __restrict__ bw_og,
        const int* __restrict__ last_nodes, const u8* __restrict__ adj8,
        const u32* __restrict__ flag, float* __restrict__ out) {
    const int g    = blockIdx.x;
    const int tid  = threadIdx.x;
    const int wave = tid >> 6, lane = tid & 63, q = lane >> 4, c = lane & 15;
    const bool isf32 = (*flag) != 0u;

    const int SF = 136;   // bf16 stride, 128-wide tiles (pad 8)
    const int SC = 264;   // bf16 stride, 256-wide tiles (pad 8)
    const int SA = 40;    // bf16 stride, 32-wide adjacency (pad 8)
    const int SH = 132;   // bf16 stride, h_n pre-GEMM tile (pad 4)
    __shared__ __align__(16) bf16 s_feat[32 * 136];   // 8704 B (feat, later hn)
    __shared__ __align__(16) bf16 s_fc  [32 * 264];   // 16896 B (P, the GRU A-tile)
    __shared__ __align__(16) bf16 s_adjb[32 * 40];    // 2560 B  adj[v][u]
    __shared__ __align__(16) bf16 s_adjT[32 * 40];    // 2560 B  adj[u][v]
    __shared__ __align__(16) bf16 s_hnp [32 * 132];   // 8448 B  h_n = feat@Vn+b
    __shared__ u32   s_adjw[256];                     // 1024 B; aliased by s_fv
    __shared__ float s_invin[32], s_invout[32];
    __shared__ float s_din[32], s_dout[32];           // 1[deg>0] indicators
    __shared__ float s_e[32], s_alpha[32];
    float* s_fv = (float*)s_adjw;     // s_adjw dead after phase 1; s_fv phase 4+

    // ---------- phase 0: stage feat (dtype branch) + adjacency ----------
    if (isf32) {
        const float4* fp = (const float4*)((const float*)featv + (size_t)g * 4096);
        for (int ch = tid; ch < 1024; ch += 256) {
            float4 v = fp[ch];
            int row = ch >> 5, off = (ch & 31) * 4;
            bf16* dp = s_feat + row * SF + off;
            dp[0] = (bf16)v.x; dp[1] = (bf16)v.y; dp[2] = (bf16)v.z; dp[3] = (bf16)v.w;
        }
    } else {
        const uint4* fp = (const uint4*)((const bf16*)featv + (size_t)g * 4096);
        for (int ch = tid; ch < 512; ch += 256) {
            int row = ch >> 4, off = (ch & 15) * 8;
            *(uint4*)(s_feat + row * SF + off) = fp[ch];
        }
    }
    s_adjw[tid] = ((const u32*)(adj8 + (size_t)g * 1024))[tid];
    if (tid < 32) s_e[tid] = 0.f;
    __syncthreads();   // B0

    // ---------- phase 1: adj->bf16 (+T), degrees+indicators, hnp GEMM ------
    {
        u32 w = s_adjw[tid];
        int v = tid >> 3, u0 = (tid & 7) * 4;
#pragma unroll
        for (int j = 0; j < 4; ++j) {
            float cv = (float)((w >> (8 * j)) & 0xFFu);
            s_adjb[v * SA + u0 + j] = (bf16)cv;
            s_adjT[(u0 + j) * SA + v] = (bf16)cv;
        }
    }
    if (tid < 32) {                                  // deg_in[v] = row-sum
        u32 s = 0;
        for (int i = 0; i < 8; ++i) {
            u32 w = s_adjw[tid * 8 + i];
            s += (w & 0xFF) + ((w >> 8) & 0xFF) + ((w >> 16) & 0xFF) + (w >> 24);
        }
        s_invin[tid] = 1.f / fmaxf((float)s, 1.f);
        s_din[tid] = (s > 0) ? 1.f : 0.f;
    } else if (tid >= 64 && tid < 96) {              // deg_out[u] = col-sum
        int uu = tid - 64; u32 s = 0;
        for (int v = 0; v < 32; ++v)
            s += (s_adjw[v * 8 + (uu >> 2)] >> (8 * (uu & 3))) & 0xFF;
        s_invout[uu] = 1.f / fmaxf((float)s, 1.f);
        s_dout[uu] = (s > 0) ? 1.f : 0.f;
    }
    // h_n = feat @ W_hh_n^T + b_hh_n  (32 x 128 -> s_hnp)
#pragma unroll 1
    for (int k2 = 0; k2 < 2; ++k2) {
        int col = (wave * 2 + k2) * 16 + c;
        const bf16* Vp = W_hh + (256 + col) * HDIM;
        const bf16* A0 = s_feat + c * SF;
        const bf16* A1 = s_feat + (16 + c) * SF;
        f32x4 acc0 = {0, 0, 0, 0}, acc1 = {0, 0, 0, 0};
#pragma unroll 1
        for (int t = 0; t < 4; ++t) {
            bf16x8 b  = *(const bf16x8*)(Vp + 32 * t + 8 * q);
            bf16x8 a0 = *(const bf16x8*)(A0 + 32 * t + 8 * q);
            bf16x8 a1 = *(const bf16x8*)(A1 + 32 * t + 8 * q);
            acc0 = mfma16(a0, b, acc0);
            acc1 = mfma16(a1, b, acc1);
        }
        float bh = (float)b_hh[256 + col];
#pragma unroll
        for (int r = 0; r < 4; ++r) {
            s_hnp[(q * 4 + r) * SH + col]      = (bf16)(acc0[r] + bh);
            s_hnp[(16 + q * 4 + r) * SH + col] = (bf16)(acc1[r] + bh);
        }
    }
    __syncthreads();   // B1

    // ---------- phase 2: P = [invin*(adjb@feat) | invout*(adjT@feat)] -------
    // K=32 -> one MFMA per 16x16 tile. Reads s_feat/adj, writes s_fc: no
    // intra-phase barrier needed (buffers disjoint).
#pragma unroll 1
    for (int k = 0; k < 4; ++k) {
        int ct = wave + 4 * k;
        int colb = (ct & 7) * 16;
        bf16x8 bfrag;
        const bf16* Bp = s_feat + (q * 8) * SF + colb + c;
#pragma unroll
        for (int jj = 0; jj < 8; ++jj) bfrag[jj] = Bp[jj * SF];
        const bf16* Ab = (ct < 8) ? s_adjb : s_adjT;
        const float* inv = (ct < 8) ? s_invin : s_invout;
        bf16x8 a0 = *(const bf16x8*)(Ab + c * SA + 8 * q);
        bf16x8 a1 = *(const bf16x8*)(Ab + (16 + c) * SA + 8 * q);
        f32x4 z = {0, 0, 0, 0};
        f32x4 p0 = mfma16(a0, bfrag, z);
        f32x4 p1 = mfma16(a1, bfrag, z);
#pragma unroll
        for (int r = 0; r < 4; ++r) {
            int row0 = q * 4 + r, row1 = 16 + q * 4 + r;
            s_fc[row0 * SC + ct * 16 + c] = (bf16)(p0[r] * inv[row0]);
            s_fc[row1 * SC + ct * 16 + c] = (bf16)(p1[r] * inv[row1]);
        }
    }
    __syncthreads();   // B2 (P ready)
    const bf16* s_p = s_fc;

    // ---------- phase 3: GRU. gi = P@U (+indicator biases), gh = feat@V ------
    // 6 accs: rr = i_r+h_r, zz = i_z+h_z, in = i_n. h_n from s_hnp.
    float hn_lo[2][4], hn_hi[2][4];
#pragma unroll
    for (int ii = 0; ii < 2; ++ii) {
        int hb = wave + 4 * ii, h0 = hb * 16;
        const bf16* Ur = u_t + (size_t)(h0 + c) * 256;
        const bf16* Uz = u_t + (size_t)(128 + h0 + c) * 256;
        const bf16* Un = u_t + (size_t)(256 + h0 + c) * 256;
        const bf16* Vr = W_hh + (h0 + c) * HDIM;
        const bf16* Vz = W_hh + (128 + h0 + c) * HDIM;
        const bf16* A0 = s_p + c * SC;
        const bf16* A1 = s_p + (16 + c) * SC;
        const bf16* F0 = s_feat + c * SF;
        const bf16* F1 = s_feat + (16 + c) * SF;
        f32x4 rr0 = {0,0,0,0}, rr1 = {0,0,0,0};   // i_r + h_r (fused)
        f32x4 zz0 = {0,0,0,0}, zz1 = {0,0,0,0};   // i_z + h_z (fused)
        f32x4 in0 = {0,0,0,0}, in1 = {0,0,0,0};   // i_n
#pragma unroll 1
        for (int t = 0; t < 8; ++t) {
            bf16x8 a0 = *(const bf16x8*)(A0 + 32 * t + 8 * q);
            bf16x8 a1 = *(const bf16x8*)(A1 + 32 * t + 8 * q);
            bf16x8 br = *(const bf16x8*)(Ur + 32 * t + 8 * q);
            rr0 = mfma16(a0, br, rr0); rr1 = mfma16(a1, br, rr1);
            bf16x8 bz = *(const bf16x8*)(Uz + 32 * t + 8 * q);
            zz0 = mfma16(a0, bz, zz0); zz1 = mfma16(a1, bz, zz1);
            bf16x8 bn = *(const bf16x8*)(Un + 32 * t + 8 * q);
            in0 = mfma16(a0, bn, in0); in1 = mfma16(a1, bn, in1);
        }
#pragma unroll 1
        for (int t = 0; t < 4; ++t) {
            bf16x8 f0 = *(const bf16x8*)(F0 + 32 * t + 8 * q);
            bf16x8 f1 = *(const bf16x8*)(F1 + 32 * t + 8 * q);
            bf16x8 br = *(const bf16x8*)(Vr + 32 * t + 8 * q);
            rr0 = mfma16(f0, br, rr0); rr1 = mfma16(f1, br, rr1);
            bf16x8 bz = *(const bf16x8*)(Vz + 32 * t + 8 * q);
            zz0 = mfma16(f0, bz, zz0); zz1 = mfma16(f1, bz, zz1);
        }
        // biases: b_ih + b_hh (+ indicator * bw terms per row)
        float brz  = (float)b_ih[h0 + c]       + (float)b_hh[h0 + c];
        float bzz  = (float)b_ih[128 + h0 + c] + (float)b_hh[128 + h0 + c];
        float bin_ = (float)b_ih[256 + h0 + c];
        float bwr_i = bw_in[h0 + c],       bwr_o = bw_og[h0 + c];
        float bwz_i = bw_in[128 + h0 + c], bwz_o = bw_og[128 + h0 + c];
        float bwn_i = bw_in[256 + h0 + c], bwn_o = bw_og[256 + h0 + c];
#pragma unroll
        for (int r = 0; r < 4; ++r) {
            int row0 = q * 4 + r, row1 = 16 + q * 4 + r;
            float di = s_din[row0], dou = s_dout[row0];
            float rg = sigmoidf_(rr0[r] + brz + di * bwr_i + dou * bwr_o);
            float z_ = sigmoidf_(zz0[r] + bzz + di * bwz_i + dou * bwz_o);
            float ng = tanhf_((in0[r] + bin_ + di * bwn_i + dou * bwn_o)
                              + rg * (float)s_hnp[row0 * SH + h0 + c]);
            float fv = (float)s_feat[row0 * SF + h0 + c];
            hn_lo[ii][r] = (1.f - z_) * ng + z_ * fv;
            di = s_din[row1]; dou = s_dout[row1];
            rg = sigmoidf_(rr1[r] + brz + di * bwr_i + dou * bwr_o);
            z_ = sigmoidf_(zz1[r] + bzz + di * bwz_i + dou * bwz_o);
            ng = tanhf_((in1[r] + bin_ + di * bwn_i + dou * bwn_o)
                        + rg * (float)s_hnp[row1 * SH + h0 + c]);
            fv = (float)s_feat[row1 * SF + h0 + c];
            hn_hi[ii][r] = (1.f - z_) * ng + z_ * fv;
        }
    }
    int ll = last_nodes[g] & 31;
    __syncthreads();   // B3a (all s_feat reads done)
#pragma unroll
    for (int ii = 0; ii < 2; ++ii) {
        int h0 = (wave + 4 * ii) * 16;
#pragma unroll
        for (int r = 0; r < 4; ++r) {
            s_feat[(q * 4 + r) * SF + h0 + c]      = (bf16)hn_lo[ii][r];
            s_feat[(16 + q * 4 + r) * SF + h0 + c] = (bf16)hn_hi[ii][r];
        }
    }
    __syncthreads();   // B3b (s_feat now holds hn)
    const bf16* s_hn = s_feat;

    // ---------- phase 4: feat_v = hn[ll] @ W_v^T + b_v (broadcast-A MFMA) ----
#pragma unroll 1
    for (int k = 0; k < 2; ++k) {
        int ct = wave * 2 + k;
        const bf16* Wp = W_v + (ct * 16 + c) * HDIM;
        const bf16* Ap = s_hn + ll * SF;
        f32x4 acc = {0, 0, 0, 0};
#pragma unroll 1
        for (int t = 0; t < 4; ++t) {
            bf16x8 a = *(const bf16x8*)(Ap + 32 * t + 8 * q);
            bf16x8 b = *(const bf16x8*)(Wp + 32 * t + 8 * q);
            acc = mfma16(a, b, acc);
        }
        if (q == 0) s_fv[ct * 16 + c] = acc[0] + (float)b_v[ct * 16 + c];
    }
    __syncthreads();   // B4

    // ---------- phase 5: e[n] = sum_col sigmoid((hn@W_u^T)[n,col]+fv[col])*w_e[col]
#pragma unroll 1
    for (int k = 0; k < 2; ++k) {
        int ct = wave * 2 + k;
        const bf16* Wp = W_u + (ct * 16 + c) * HDIM;
        const bf16* A0 = s_hn + c * SF;
        const bf16* A1 = s_hn + (16 + c) * SF;
        f32x4 e0 = {0, 0, 0, 0}, e1 = {0, 0, 0, 0};
#pragma unroll 1
        for (int t = 0; t < 4; ++t) {
            bf16x8 b  = *(const bf16x8*)(Wp + 32 * t + 8 * q);
            bf16x8 a0 = *(const bf16x8*)(A0 + 32 * t + 8 * q);
            bf16x8 a1 = *(const bf16x8*)(A1 + 32 * t + 8 * q);
            e0 = mfma16(a0, b, e0);
            e1 = mfma16(a1, b, e1);
        }
        int col = ct * 16 + c;
        float we = (float)w_e[col], fv = s_fv[col];
#pragma unroll
        for (int r = 0; r < 4; ++r) {
            float v0 = sigmoidf_(e0[r] + fv) * we;
            float v1 = sigmoidf_(e1[r] + fv) * we;
            for (int m = 1; m < 16; m <<= 1) {
                v0 += __shfl_xor(v0, m);
                v1 += __shfl_xor(v1, m);
            }
            if (c == 0) {
                atomicAdd(&s_e[q * 4 + r], v0);
                atomicAdd(&s_e[16 + q * 4 + r], v1);
            }
        }
    }
    __syncthreads();   // B5
    if (tid < 32) {
        float cv = isf32 ? ((const float*)cntv)[(size_t)g * 32 + tid]
                         : (float)((const bf16*)cntv)[(size_t)g * 32 + tid];
        s_alpha[tid] = s_e[tid] * cv;
    }
    __syncthreads();   // B6

    // ---------- output (f32): [ct_g (128) | ct_l (128)] ----------
    if (tid < 128) {
        float s = 0.f;
#pragma unroll 4
        for (int n = 0; n < 32; ++n) s += s_alpha[n] * (float)s_hn[n * SF + tid];
        out[(size_t)g * 256 + tid] = s;
    } else {
        int h = tid - 128;
        out[(size_t)g * 256 + 128 + h] = (float)s_hn[ll * SF + h];
    }
}

extern "C" void kernel_launch(void* const* d_in, const int* in_sizes, int n_in,
                              void* d_out, int out_size, void* d_ws, size_t ws_size,
                              hipStream_t stream) {
    const int* src  = (const int*)d_in[14];
    const int* dst  = (const int*)d_in[15];
    const int* last = (const int*)d_in[17];
    float* out = (float*)d_out;

    u32*  flag  = (u32*)d_ws;
    bf16* conv  = (bf16*)((char*)d_ws + 4096);
    float* bwin = (float*)((char*)d_ws + 430 * 1024);
    float* bwog = (float*)((char*)d_ws + 434 * 1024);
    bf16* u_t   = (bf16*)((char*)d_ws + 448 * 1024);   // 384x256 bf16 = 192KB
    u32*  adjw  = (u32*)((char*)d_ws + (1u << 20));
    const u8* adj8 = (const u8*)adjw;

    // bf16 weight copies, contiguous in input order 2..13
    const int cnts[12] = {16384, 128, 16384, 128, 98304, 384, 49152, 384,
                          16384, 16384, 128, 128};
    bf16* cp[12];
    {
        bf16* p = conv;
        for (int i = 0; i < 12; ++i) { cp[i] = p; p += cnts[i]; }
    }

    k_prep<<<2048 + (NCONV + 2047) / 2048, 256, 0, stream>>>(
        (const u32*)d_in[0], adjw, conv, flag,
        d_in[2], d_in[3], d_in[4], d_in[5], d_in[6], d_in[7],
        d_in[8], d_in[9], d_in[10], d_in[11], d_in[12], d_in[13]);
    k_fuse<<<24, 256, 0, stream>>>(cp[0], cp[1], cp[2], cp[3], cp[4], cp[5],
                                   u_t, bwin, bwog);
    k_adj<<<NEDGE / 256, 256, 0, stream>>>(src, dst, adjw);
    k_mono<<<NG, 256, 0, stream>>>(d_in[0], d_in[1],
                                   u_t, cp[5], cp[6], cp[7],
                                   cp[8], cp[9], cp[10], cp[11],
                                   bwin, bwog,
                                   last, adj8, flag, out);
}

// Round 6
// 483.306 us; speedup vs baseline: 1.5883x; 1.2991x over previous
//
#include <hip/hip_runtime.h>

// SRGNN — Round 14: 2 graphs/block — halve the weight re-stream.
//  r13 post-mortem: dur tracks per-wave instruction+stream volume (~15-20
//  cy/instr effective), insensitive to occupancy/HBM. Dominant stream: u_t
//  (192KB) + W_hh + W_u/W_v re-read per block from L2 with only 32 rows to
//  amortize (8192 x ~350KB = 2.8GB latency-exposed). Also WRITE=113MB means
//  r13's GRU re-spilled mildly at the 128-reg cap.
//  Fix: 2 graphs/block (64 rows), 512 thr / 8 waves; each wave = ONE 16-col
//  tile x FOUR row-frags -> each weight fragment feeds 4 MFMAs (was 2), block
//  count halves -> weight traffic halves. hnp now lives in 4 f32x4 REGS (its
//  phase-1 tile mapping == GRU tile mapping) -> s_hnp LDS + roundtrip deleted.
//  LDS 63.5KB -> 2 blocks/CU, __launch_bounds__(512,4) (128-reg cap).
//  k_fuse: bias loop parallelized (16 thr/j + shfl reduce) — was tid<16 with
//  128 serial scalar loads (~30-60us).
//  Tripwires: WRITE >> 8.2MB => spill; fail/absmax shift => 2-graph indexing.
// ws: [0] flag ; [4K] bf16 conv (~419KB) ; [430K] bw_in/bw_og f32 ;
//     [448K] u_t bf16 384x256 (192KB) ; [1MiB] adj u8 (8MB).

#define NG    8192
#define NODES 32
#define HDIM  128
#define NEDGE 524288
#define NCONV 214272   // total weight elements (inputs 2..13)

typedef __bf16 bf16;
typedef __bf16 bf16x8 __attribute__((ext_vector_type(8)));
typedef float  f32x4  __attribute__((ext_vector_type(4)));
typedef unsigned int u32;
typedef unsigned char u8;

__device__ __forceinline__ f32x4 mfma16(bf16x8 a, bf16x8 b, f32x4 c) {
    // D = A(16x32)*B(32x16)+C ; A[m=lane&15][k=quad*8+j], B[k=quad*8+j][n=lane&15],
    // D[row=quad*4+r][col=lane&15]
    return __builtin_amdgcn_mfma_f32_16x16x32_bf16(a, b, c, 0, 0, 0);
}

__device__ __forceinline__ float sigmoidf_(float x) { return 1.f / (1.f + __expf(-x)); }
__device__ __forceinline__ float tanhf_(float x) { return 1.f - 2.f / (__expf(2.f * x) + 1.f); }

// ---- k_prep: blocks [0,2048) zero adj; blocks [2048,2153) convert weights ----
__global__ __launch_bounds__(256) void k_prep(
        const u32* __restrict__ featw, u32* __restrict__ adjw,
        bf16* __restrict__ conv, u32* __restrict__ flagout,
        const void* t0, const void* t1, const void* t2,  const void* t3,
        const void* t4, const void* t5, const void* t6,  const void* t7,
        const void* t8, const void* t9, const void* t10, const void* t11) {
    const int b = blockIdx.x, tid = threadIdx.x;
    if (b < 2048) {                       // zero 8MB of adj
        int i = b * 1024 + tid * 4;
        *(uint4*)(adjw + i) = make_uint4(0u, 0u, 0u, 0u);
        return;
    }
    __shared__ int s_isf32;
    if (tid == 0) s_isf32 = 0;
    __syncthreads();
    {
        u32 hit = 0;
#pragma unroll
        for (int k = 0; k < 16; ++k) {
            u32 x = featw[tid * 16 + k];
            hit |= (((x >> 7) & 0xFFu) == 0xFFu) ? 1u : 0u;
        }
        if (hit) s_isf32 = 1;             // benign race
    }
    __syncthreads();
    const bool isf32 = s_isf32 != 0;
    if (b == 2048 && tid == 0) *flagout = isf32 ? 1u : 0u;

    int e0 = (b - 2048) * 2048 + tid * 8;
    if (e0 >= NCONV) return;
    const int cnts[12] = {16384, 128, 16384, 128, 98304, 384, 49152, 384,
                          16384, 16384, 128, 128};
    int t = 0, base = 0;
    while (e0 >= base + cnts[t]) { base += cnts[t]; ++t; }
    int off = e0 - base;
    const void* sp;
    switch (t) {
        case 0: sp = t0; break; case 1: sp = t1; break;
        case 2: sp = t2; break; case 3: sp = t3; break;
        case 4: sp = t4; break; case 5: sp = t5; break;
        case 6: sp = t6; break; case 7: sp = t7; break;
        case 8: sp = t8; break; case 9: sp = t9; break;
        case 10: sp = t10; break; default: sp = t11; break;
    }
    if (isf32) {
        const float4* s = (const float4*)sp + (off >> 2);
        float4 a = s[0], bb = s[1];
        bf16x8 v;
        v[0] = (bf16)a.x;  v[1] = (bf16)a.y;  v[2] = (bf16)a.z;  v[3] = (bf16)a.w;
        v[4] = (bf16)bb.x; v[5] = (bf16)bb.y; v[6] = (bf16)bb.z; v[7] = (bf16)bb.w;
        *(bf16x8*)(conv + e0) = v;
    } else {
        *(uint4*)(conv + e0) = ((const uint4*)sp)[off >> 3];
    }
}

// ---- k_fuse: U = [W_in^T@W_ih_in^T ; W_og^T@W_ih_out^T] as u_t[384][256] ----
// bias: bw_in[j]=sum_m b_in[m]*W_ih[j][m]; bw_og[j]=sum_m b_og[m]*W_ih[j][128+m]
// (parallel: 16 threads per j, shfl-reduce)
__global__ __launch_bounds__(256) void k_fuse(
        const bf16* __restrict__ W_in, const bf16* __restrict__ b_in,
        const bf16* __restrict__ W_og, const bf16* __restrict__ b_og,
        const bf16* __restrict__ W_ih, const bf16* __restrict__ b_ih,
        bf16* __restrict__ u_t, float* __restrict__ bw_in,
        float* __restrict__ bw_og) {
    const int jt = blockIdx.x;                 // 0..23
    const int tid = threadIdx.x;
    const int wave = tid >> 6, lane = tid & 63, q = lane >> 4, c = lane & 15;
#pragma unroll 1
    for (int k2 = 0; k2 < 4; ++k2) {
        int kt = wave * 4 + k2;                // 0..15 (col tile of 256)
        bool og = kt >= 8;
        const bf16* Wsrc = og ? W_og : W_in;   // [128][128] row-major
        int kcol = (kt & 7) * 16 + c;          // 0..127
        int mo = og ? 128 : 0;
        f32x4 acc = {0, 0, 0, 0};
#pragma unroll 1
        for (int t = 0; t < 4; ++t) {
            bf16x8 a = *(const bf16x8*)(W_ih + (jt * 16 + c) * 256 + mo + 32 * t + 8 * q);
            bf16x8 b;
#pragma unroll
            for (int jj = 0; jj < 8; ++jj)
                b[jj] = Wsrc[(32 * t + 8 * q + jj) * 128 + kcol];
            acc = mfma16(a, b, acc);
        }
#pragma unroll
        for (int r = 0; r < 4; ++r)
            u_t[(size_t)(jt * 16 + q * 4 + r) * 256 + kt * 16 + c] = (bf16)acc[r];
    }
    {   // bias, parallel: jj = tid>>4 (16 j's per block), mm = tid&15
        int jj = tid >> 4, mm = tid & 15;
        int j = jt * 16 + jj;
        float si = 0.f, so = 0.f;
#pragma unroll
        for (int i = 0; i < 8; ++i) {
            int m = mm * 8 + i;
            si += (float)b_in[m] * (float)W_ih[j * 256 + m];
            so += (float)b_og[m] * (float)W_ih[j * 256 + 128 + m];
        }
        for (int m = 1; m < 16; m <<= 1) {
            si += __shfl_xor(si, m);
            so += __shfl_xor(so, m);
        }
        if (mm == 0) { bw_in[j] = si; bw_og[j] = so; }
    }
}

__global__ __launch_bounds__(256) void k_adj(const int* __restrict__ src,
                                             const int* __restrict__ dst,
                                             u32* __restrict__ adj) {
    int e = blockIdx.x * 256 + threadIdx.x;
    int s = src[e], d = dst[e];
    int g = s >> 5;                          // edges are intra-graph
    u32 bidx = ((u32)g << 10) | ((u32)(d & 31) << 5) | (u32)(s & 31);
    atomicAdd(&adj[bidx >> 2], 1u << (8 * (bidx & 3)));
}

__global__ __launch_bounds__(512, 4) void k_mono(
        const void* __restrict__ featv, const void* __restrict__ cntv,
        const bf16* __restrict__ u_t,  const bf16* __restrict__ b_ih,
        const bf16* __restrict__ W_hh, const bf16* __restrict__ b_hh,
        const bf16* __restrict__ W_u,  const bf16* __restrict__ W_v,
        const bf16* __restrict__ b_v,  const bf16* __restrict__ w_e,
        const float* __restrict__ bw_in, const float* __restrict__ bw_og,
        const int* __restrict__ last_nodes, const u8* __restrict__ adj8,
        const u32* __restrict__ flag, float* __restrict__ out) {
    const int g2   = blockIdx.x;            // graph pair: graphs 2*g2, 2*g2+1
    const int tid  = threadIdx.x;
    const int wave = tid >> 6, lane = tid & 63, q = lane >> 4, c = lane & 15;
    const bool isf32 = (*flag) != 0u;
    const int col  = wave * 16 + c;         // this wave's output column (0..127)

    const int SF = 136;   // bf16 stride, 128-wide tiles (pad 8)
    const int SC = 264;   // bf16 stride, 256-wide P tile (pad 8)
    const int SA = 40;    // bf16 stride, 32-wide adjacency (pad 8)
    __shared__ __align__(16) bf16 s_feat[64 * 136];   // 17408 B (feat, later hn)
    __shared__ __align__(16) bf16 s_fc  [64 * 264];   // 33792 B (P)
    __shared__ __align__(16) bf16 s_adjb[64 * 40];    // 5120 B  adj[v][u] (2 graphs)
    __shared__ __align__(16) bf16 s_adjT[64 * 40];    // 5120 B  adj[u][v]
    __shared__ u32   s_adjw[512];                     // 2048 B; aliased by s_fv
    __shared__ float s_invin[64], s_invout[64];
    __shared__ float s_din[64], s_dout[64];
    __shared__ float s_e[64], s_alpha[64];
    float* s_fv = (float*)s_adjw;   // 256 floats; s_adjw dead after phase 1

    // ---------- phase 0: stage feat (64 contiguous rows) + adjacency --------
    if (isf32) {
        const float4* fp = (const float4*)((const float*)featv + (size_t)g2 * 8192);
        for (int ch = tid; ch < 2048; ch += 512) {
            float4 v = fp[ch];
            int row = ch >> 5, off = (ch & 31) * 4;
            bf16* dp = s_feat + row * SF + off;
            dp[0] = (bf16)v.x; dp[1] = (bf16)v.y; dp[2] = (bf16)v.z; dp[3] = (bf16)v.w;
        }
    } else {
        const uint4* fp = (const uint4*)((const bf16*)featv + (size_t)g2 * 8192);
        for (int ch = tid; ch < 1024; ch += 512) {
            int row = ch >> 4, off = (ch & 15) * 8;
            *(uint4*)(s_feat + row * SF + off) = fp[ch];
        }
    }
    s_adjw[tid] = ((const u32*)(adj8 + (size_t)g2 * 2048))[tid];
    if (tid < 64) s_e[tid] = 0.f;
    __syncthreads();   // B0

    // ---------- phase 1: adj->bf16 (+T), degrees+indicators, hnp (REGS) -----
    {
        u32 w = s_adjw[tid];
        int vrow = tid >> 3;            // global row 0..63
        int grp  = tid >> 8;            // graph within pair
        int vloc = vrow & 31;
        int u0 = (tid & 7) * 4;
#pragma unroll
        for (int j = 0; j < 4; ++j) {
            float cv = (float)((w >> (8 * j)) & 0xFFu);
            s_adjb[vrow * SA + u0 + j] = (bf16)cv;
            s_adjT[(grp * 32 + u0 + j) * SA + vloc] = (bf16)cv;
        }
    }
    if (tid < 64) {                                  // deg_in[row] = row-sum
        u32 s = 0;
        for (int i = 0; i < 8; ++i) {
            u32 w = s_adjw[tid * 8 + i];
            s += (w & 0xFF) + ((w >> 8) & 0xFF) + ((w >> 16) & 0xFF) + (w >> 24);
        }
        s_invin[tid] = 1.f / fmaxf((float)s, 1.f);
        s_din[tid] = (s > 0) ? 1.f : 0.f;
    } else if (tid < 128) {                          // deg_out = col-sum
        int uu = tid - 64; int grp = uu >> 5; int ul = uu & 31; u32 s = 0;
        for (int v = 0; v < 32; ++v)
            s += (s_adjw[grp * 256 + v * 8 + (ul >> 2)] >> (8 * (ul & 3))) & 0xFF;
        s_invout[uu] = 1.f / fmaxf((float)s, 1.f);
        s_dout[uu] = (s > 0) ? 1.f : 0.f;
    }
    // hnp = (feat @ W_hh_n^T + b)[tile of this wave] -> stays in REGISTERS
    // (tile mapping identical to the GRU output tile: rows fr*16+q*4+r, col).
    f32x4 hnp[4] = {{0,0,0,0},{0,0,0,0},{0,0,0,0},{0,0,0,0}};
    {
        const bf16* Vp = W_hh + (256 + col) * HDIM;
#pragma unroll 1
        for (int t = 0; t < 4; ++t) {
            bf16x8 b = *(const bf16x8*)(Vp + 32 * t + 8 * q);
#pragma unroll
            for (int fr = 0; fr < 4; ++fr) {
                bf16x8 a = *(const bf16x8*)(s_feat + (fr * 16 + c) * SF + 32 * t + 8 * q);
                hnp[fr] = mfma16(a, b, hnp[fr]);
            }
        }
        float bh = (float)b_hh[256 + col];
#pragma unroll
        for (int fr = 0; fr < 4; ++fr)
#pragma unroll
            for (int r = 0; r < 4; ++r) hnp[fr][r] += bh;
    }
    __syncthreads();   // B1

    // ---------- phase 2: P = [invin*(adj@feat) | invout*(adjT@feat)] --------
    // 16 col-tiles over 8 waves (2 each); block-diagonal: frags 0,1 = graph A
    // (adj rows 0-31, feat rows 0-31), frags 2,3 = graph B.
#pragma unroll 1
    for (int kk = 0; kk < 2; ++kk) {
        int ct = wave * 2 + kk;                // 0..15
        int colb = (ct & 7) * 16;
        const bf16* Ab = (ct < 8) ? s_adjb : s_adjT;
        const float* inv = (ct < 8) ? s_invin : s_invout;
        bf16x8 bA, bB;
        const bf16* Bp0 = s_feat + (q * 8) * SF + colb + c;
        const bf16* Bp1 = s_feat + (32 + q * 8) * SF + colb + c;
#pragma unroll
        for (int jj = 0; jj < 8; ++jj) { bA[jj] = Bp0[jj * SF]; bB[jj] = Bp1[jj * SF]; }
        bf16x8 a0 = *(const bf16x8*)(Ab + c * SA + 8 * q);
        bf16x8 a1 = *(const bf16x8*)(Ab + (16 + c) * SA + 8 * q);
        bf16x8 a2 = *(const bf16x8*)(Ab + (32 + c) * SA + 8 * q);
        bf16x8 a3 = *(const bf16x8*)(Ab + (48 + c) * SA + 8 * q);
        f32x4 z = {0, 0, 0, 0};
        f32x4 p0 = mfma16(a0, bA, z);
        f32x4 p1 = mfma16(a1, bA, z);
        f32x4 p2 = mfma16(a2, bB, z);
        f32x4 p3 = mfma16(a3, bB, z);
#pragma unroll
        for (int r = 0; r < 4; ++r) {
            int r0 = q * 4 + r;
            s_fc[(r0)      * SC + ct * 16 + c] = (bf16)(p0[r] * inv[r0]);
            s_fc[(16 + r0) * SC + ct * 16 + c] = (bf16)(p1[r] * inv[16 + r0]);
            s_fc[(32 + r0) * SC + ct * 16 + c] = (bf16)(p2[r] * inv[32 + r0]);
            s_fc[(48 + r0) * SC + ct * 16 + c] = (bf16)(p3[r] * inv[48 + r0]);
        }
    }
    __syncthreads();   // B2

    // ---------- phase 3: GRU. Each wave: 1 col-tile x 4 row-frags. ----------
    // Accs: rr = i_r+h_r, zz = i_z+h_z, in_ = i_n (x4 frags) + hnp held.
    f32x4 rr[4] = {{0,0,0,0},{0,0,0,0},{0,0,0,0},{0,0,0,0}};
    f32x4 zz[4] = {{0,0,0,0},{0,0,0,0},{0,0,0,0},{0,0,0,0}};
    f32x4 in_[4] = {{0,0,0,0},{0,0,0,0},{0,0,0,0},{0,0,0,0}};
    {
        const bf16* Ur = u_t + (size_t)(col) * 256;
        const bf16* Uz = u_t + (size_t)(128 + col) * 256;
        const bf16* Un = u_t + (size_t)(256 + col) * 256;
#pragma unroll 1
        for (int t = 0; t < 8; ++t) {
            bf16x8 br = *(const bf16x8*)(Ur + 32 * t + 8 * q);
            bf16x8 bz = *(const bf16x8*)(Uz + 32 * t + 8 * q);
            bf16x8 bn = *(const bf16x8*)(Un + 32 * t + 8 * q);
#pragma unroll
            for (int fr = 0; fr < 4; ++fr) {
                bf16x8 a = *(const bf16x8*)(s_fc + (fr * 16 + c) * SC + 32 * t + 8 * q);
                rr[fr] = mfma16(a, br, rr[fr]);
                zz[fr] = mfma16(a, bz, zz[fr]);
                in_[fr] = mfma16(a, bn, in_[fr]);
            }
        }
        const bf16* Vr = W_hh + (col) * HDIM;
        const bf16* Vz = W_hh + (128 + col) * HDIM;
#pragma unroll 1
        for (int t = 0; t < 4; ++t) {
            bf16x8 br = *(const bf16x8*)(Vr + 32 * t + 8 * q);
            bf16x8 bz = *(const bf16x8*)(Vz + 32 * t + 8 * q);
#pragma unroll
            for (int fr = 0; fr < 4; ++fr) {
                bf16x8 f = *(const bf16x8*)(s_feat + (fr * 16 + c) * SF + 32 * t + 8 * q);
                rr[fr] = mfma16(f, br, rr[fr]);
                zz[fr] = mfma16(f, bz, zz[fr]);
            }
        }
    }
    // epilogue -> hn into hv[] regs
    f32x4 hv[4];
    {
        float brz  = (float)b_ih[col]       + (float)b_hh[col];
        float bzz  = (float)b_ih[128 + col] + (float)b_hh[128 + col];
        float bin_ = (float)b_ih[256 + col];
        float bwr_i = bw_in[col],       bwr_o = bw_og[col];
        float bwz_i = bw_in[128 + col], bwz_o = bw_og[128 + col];
        float bwn_i = bw_in[256 + col], bwn_o = bw_og[256 + col];
#pragma unroll
        for (int fr = 0; fr < 4; ++fr) {
#pragma unroll
            for (int r = 0; r < 4; ++r) {
                int row = fr * 16 + q * 4 + r;
                float di = s_din[row], dou = s_dout[row];
                float rg = sigmoidf_(rr[fr][r] + brz + di * bwr_i + dou * bwr_o);
                float z_ = sigmoidf_(zz[fr][r] + bzz + di * bwz_i + dou * bwz_o);
                float ng = tanhf_(in_[fr][r] + bin_ + di * bwn_i + dou * bwn_o
                                  + rg * hnp[fr][r]);
                float fv = (float)s_feat[row * SF + col];
                hv[fr][r] = (1.f - z_) * ng + z_ * fv;
            }
        }
    }
    int llA = last_nodes[2 * g2] & 31;
    int llB = 32 + (last_nodes[2 * g2 + 1] & 31);
    __syncthreads();   // B3a (all s_feat reads done)
#pragma unroll
    for (int fr = 0; fr < 4; ++fr)
#pragma unroll
        for (int r = 0; r < 4; ++r)
            s_feat[(fr * 16 + q * 4 + r) * SF + col] = (bf16)hv[fr][r];
    __syncthreads();   // B3b (s_feat now holds hn)
    const bf16* s_hn = s_feat;

    // ---------- phase 4: feat_v = hn[ll] @ W_v^T + b_v, per graph -----------
#pragma unroll 1
    for (int gsel = 0; gsel < 2; ++gsel) {
        int ll = gsel ? llB : llA;
        const bf16* Ap = s_hn + ll * SF;
        const bf16* Wp = W_v + (size_t)col * HDIM;
        f32x4 acc = {0, 0, 0, 0};
#pragma unroll 1
        for (int t = 0; t < 4; ++t) {
            bf16x8 a = *(const bf16x8*)(Ap + 32 * t + 8 * q);
            bf16x8 b = *(const bf16x8*)(Wp + 32 * t + 8 * q);
            acc = mfma16(a, b, acc);
        }
        if (q == 0) s_fv[gsel * 128 + col] = acc[0] + (float)b_v[col];
    }
    __syncthreads();   // B4

    // ---------- phase 5: e[n] = sum_col sigmoid((hn@W_u^T)+fv)*w_e ----------
    {
        const bf16* Wp = W_u + (size_t)col * HDIM;
        f32x4 ee[4] = {{0,0,0,0},{0,0,0,0},{0,0,0,0},{0,0,0,0}};
#pragma unroll 1
        for (int t = 0; t < 4; ++t) {
            bf16x8 b = *(const bf16x8*)(Wp + 32 * t + 8 * q);
#pragma unroll
            for (int fr = 0; fr < 4; ++fr) {
                bf16x8 a = *(const bf16x8*)(s_hn + (fr * 16 + c) * SF + 32 * t + 8 * q);
                ee[fr] = mfma16(a, b, ee[fr]);
            }
        }
        float we = (float)w_e[col];
        float fvA = s_fv[col], fvB = s_fv[128 + col];
#pragma unroll
        for (int fr = 0; fr < 4; ++fr) {
            float fv = (fr < 2) ? fvA : fvB;
#pragma unroll
            for (int r = 0; r < 4; ++r) {
                float v = sigmoidf_(ee[fr][r] + fv) * we;
                for (int m = 1; m < 16; m <<= 1) v += __shfl_xor(v, m);
                if (c == 0) atomicAdd(&s_e[fr * 16 + q * 4 + r], v);
            }
        }
    }
    __syncthreads();   // B5
    if (tid < 64) {
        float cv = isf32 ? ((const float*)cntv)[(size_t)g2 * 64 + tid]
                         : (float)((const bf16*)cntv)[(size_t)g2 * 64 + tid];
        s_alpha[tid] = s_e[tid] * cv;
    }
    __syncthreads();   // B6

    // ---------- output (f32): per graph [ct_g (128) | ct_l (128)] -----------
    {
        int part = tid >> 7;        // 0..3
        int co = tid & 127;
        if (part == 0) {
            float s = 0.f;
#pragma unroll 4
            for (int n = 0; n < 32; ++n) s += s_alpha[n] * (float)s_hn[n * SF + co];
            out[(size_t)(2 * g2) * 256 + co] = s;
        } else if (part == 1) {
            out[(size_t)(2 * g2) * 256 + 128 + co] = (float)s_hn[llA * SF + co];
        } else if (part == 2) {
            float s = 0.f;
#pragma unroll 4
            for (int n = 32; n < 64; ++n) s += s_alpha[n] * (float)s_hn[n * SF + co];
            out[(size_t)(2 * g2 + 1) * 256 + co] = s;
        } else {
            out[(size_t)(2 * g2 + 1) * 256 + 128 + co] = (float)s_hn[llB * SF + co];
        }
    }
}

extern "C" void kernel_launch(void* const* d_in, const int* in_sizes, int n_in,
                              void* d_out, int out_size, void* d_ws, size_t ws_size,
                              hipStream_t stream) {
    const int* src  = (const int*)d_in[14];
    const int* dst  = (const int*)d_in[15];
    const int* last = (const int*)d_in[17];
    float* out = (float*)d_out;

    u32*  flag  = (u32*)d_ws;
    bf16* conv  = (bf16*)((char*)d_ws + 4096);
    float* bwin = (float*)((char*)d_ws + 430 * 1024);
    float* bwog = (float*)((char*)d_ws + 434 * 1024);
    bf16* u_t   = (bf16*)((char*)d_ws + 448 * 1024);   // 384x256 bf16 = 192KB
    u32*  adjw  = (u32*)((char*)d_ws + (1u << 20));
    const u8* adj8 = (const u8*)adjw;

    // bf16 weight copies, contiguous in input order 2..13
    const int cnts[12] = {16384, 128, 16384, 128, 98304, 384, 49152, 384,
                          16384, 16384, 128, 128};
    bf16* cp[12];
    {
        bf16* p = conv;
        for (int i = 0; i < 12; ++i) { cp[i] = p; p += cnts[i]; }
    }

    k_prep<<<2048 + (NCONV + 2047) / 2048, 256, 0, stream>>>(
        (const u32*)d_in[0], adjw, conv, flag,
        d_in[2], d_in[3], d_in[4], d_in[5], d_in[6], d_in[7],
        d_in[8], d_in[9], d_in[10], d_in[11], d_in[12], d_in[13]);
    k_fuse<<<24, 256, 0, stream>>>(cp[0], cp[1], cp[2], cp[3], cp[4], cp[5],
                                   u_t, bwin, bwog);
    k_adj<<<NEDGE / 256, 256, 0, stream>>>(src, dst, adjw);
    k_mono<<<NG / 2, 512, 0, stream>>>(d_in[0], d_in[1],
                                       u_t, cp[5], cp[6], cp[7],
                                       cp[8], cp[9], cp[10], cp[11],
                                       bwin, bwog,
                                       last, adj8, flag, out);
}

// Round 7
// 481.591 us; speedup vs baseline: 1.5939x; 1.0036x over previous
//
#include <hip/hip_runtime.h>

// SRGNN — Round 15: exposed-latency pass (occupancy is hard-pinned).
//  r14 post-mortem: VGPR_Count=60 is ARCH only; +64 AGPR -> ~124 unified ->
//  128-reg class -> 4 waves/SIMD cap. 2 blocks x 8 waves = 16 waves/CU is
//  already AT that cap; occupancy can't rise (GRU needs >=48 acc regs).
//  Levers left: (1) per-wave exposed latency in the 12 rolled dependence-
//  serialized GRU t-iterations; (2) the 149us non-k_mono gap (31% of total;
//  work-model says ~35us -> something is slow; instrument by elimination).
//  k_mono: merge U+V loops (8 iters, t<4 issues V too) + #pragma unroll 2;
//  hnp moves regs->LDS (frees 16 acc regs for the pipelined frags; LDS
//  63.5->80.4KB, still 2 blocks/CU; wave-private cols, no barrier).
//  k_prep: 2048 zero-blocks -> hipMemsetAsync. k_fuse: 24 -> 96 blocks.
//  k_adj untouched: if the gap survives, k_adj's 512K atomics are the monster.
//  Tripwires: WRITE >> 8.2MB => unroll-2 spilled => revert; absmax shift =>
//  hnp-LDS or memset bug.
// ws: [0] flag ; [4K] bf16 conv (~419KB) ; [430K] bw_in/bw_og f32 ;
//     [448K] u_t bf16 384x256 (192KB) ; [1MiB] adj u8 (8MB).

#define NG    8192
#define NODES 32
#define HDIM  128
#define NEDGE 524288
#define NCONV 214272   // total weight elements (inputs 2..13)

typedef __bf16 bf16;
typedef __bf16 bf16x8 __attribute__((ext_vector_type(8)));
typedef float  f32x4  __attribute__((ext_vector_type(4)));
typedef unsigned int u32;
typedef unsigned char u8;

__device__ __forceinline__ f32x4 mfma16(bf16x8 a, bf16x8 b, f32x4 c) {
    // D = A(16x32)*B(32x16)+C ; A[m=lane&15][k=quad*8+j], B[k=quad*8+j][n=lane&15],
    // D[row=quad*4+r][col=lane&15]
    return __builtin_amdgcn_mfma_f32_16x16x32_bf16(a, b, c, 0, 0, 0);
}

__device__ __forceinline__ float sigmoidf_(float x) { return 1.f / (1.f + __expf(-x)); }
__device__ __forceinline__ float tanhf_(float x) { return 1.f - 2.f / (__expf(2.f * x) + 1.f); }

// ---- k_prep: 105 convert blocks (zeroing moved to hipMemsetAsync) ----------
__global__ __launch_bounds__(256) void k_prep(
        const u32* __restrict__ featw,
        bf16* __restrict__ conv, u32* __restrict__ flagout,
        const void* t0, const void* t1, const void* t2,  const void* t3,
        const void* t4, const void* t5, const void* t6,  const void* t7,
        const void* t8, const void* t9, const void* t10, const void* t11) {
    const int b = blockIdx.x, tid = threadIdx.x;
    __shared__ int s_isf32;
    if (tid == 0) s_isf32 = 0;
    __syncthreads();
    {
        u32 hit = 0;
#pragma unroll
        for (int k = 0; k < 16; ++k) {
            u32 x = featw[tid * 16 + k];
            hit |= (((x >> 7) & 0xFFu) == 0xFFu) ? 1u : 0u;
        }
        if (hit) s_isf32 = 1;             // benign race
    }
    __syncthreads();
    const bool isf32 = s_isf32 != 0;
    if (b == 0 && tid == 0) *flagout = isf32 ? 1u : 0u;

    int e0 = b * 2048 + tid * 8;
    if (e0 >= NCONV) return;
    const int cnts[12] = {16384, 128, 16384, 128, 98304, 384, 49152, 384,
                          16384, 16384, 128, 128};
    int t = 0, base = 0;
    while (e0 >= base + cnts[t]) { base += cnts[t]; ++t; }
    int off = e0 - base;
    const void* sp;
    switch (t) {
        case 0: sp = t0; break; case 1: sp = t1; break;
        case 2: sp = t2; break; case 3: sp = t3; break;
        case 4: sp = t4; break; case 5: sp = t5; break;
        case 6: sp = t6; break; case 7: sp = t7; break;
        case 8: sp = t8; break; case 9: sp = t9; break;
        case 10: sp = t10; break; default: sp = t11; break;
    }
    if (isf32) {
        const float4* s = (const float4*)sp + (off >> 2);
        float4 a = s[0], bb = s[1];
        bf16x8 v;
        v[0] = (bf16)a.x;  v[1] = (bf16)a.y;  v[2] = (bf16)a.z;  v[3] = (bf16)a.w;
        v[4] = (bf16)bb.x; v[5] = (bf16)bb.y; v[6] = (bf16)bb.z; v[7] = (bf16)bb.w;
        *(bf16x8*)(conv + e0) = v;
    } else {
        *(uint4*)(conv + e0) = ((const uint4*)sp)[off >> 3];
    }
}

// ---- k_fuse: 96 blocks (jt = b>>2, ksel = b&3): each wave one kt tile ------
__global__ __launch_bounds__(256) void k_fuse(
        const bf16* __restrict__ W_in, const bf16* __restrict__ b_in,
        const bf16* __restrict__ W_og, const bf16* __restrict__ b_og,
        const bf16* __restrict__ W_ih, const bf16* __restrict__ b_ih,
        bf16* __restrict__ u_t, float* __restrict__ bw_in,
        float* __restrict__ bw_og) {
    const int jt = blockIdx.x >> 2;            // 0..23
    const int ksel = blockIdx.x & 3;
    const int tid = threadIdx.x;
    const int wave = tid >> 6, lane = tid & 63, q = lane >> 4, c = lane & 15;
    {
        int kt = wave * 4 + ksel;              // 0..15 (col tile of 256)
        bool og = kt >= 8;
        const bf16* Wsrc = og ? W_og : W_in;   // [128][128] row-major
        int kcol = (kt & 7) * 16 + c;          // 0..127
        int mo = og ? 128 : 0;
        f32x4 acc = {0, 0, 0, 0};
#pragma unroll 1
        for (int t = 0; t < 4; ++t) {
            bf16x8 a = *(const bf16x8*)(W_ih + (jt * 16 + c) * 256 + mo + 32 * t + 8 * q);
            bf16x8 b;
#pragma unroll
            for (int jj = 0; jj < 8; ++jj)
                b[jj] = Wsrc[(32 * t + 8 * q + jj) * 128 + kcol];
            acc = mfma16(a, b, acc);
        }
#pragma unroll
        for (int r = 0; r < 4; ++r)
            u_t[(size_t)(jt * 16 + q * 4 + r) * 256 + kt * 16 + c] = (bf16)acc[r];
    }
    if (ksel == 0) {   // bias: jj = tid>>4 (16 j's), mm = tid&15, shfl reduce
        int jj = tid >> 4, mm = tid & 15;
        int j = jt * 16 + jj;
        float si = 0.f, so = 0.f;
#pragma unroll
        for (int i = 0; i < 8; ++i) {
            int m = mm * 8 + i;
            si += (float)b_in[m] * (float)W_ih[j * 256 + m];
            so += (float)b_og[m] * (float)W_ih[j * 256 + 128 + m];
        }
        for (int m = 1; m < 16; m <<= 1) {
            si += __shfl_xor(si, m);
            so += __shfl_xor(so, m);
        }
        if (mm == 0) { bw_in[j] = si; bw_og[j] = so; }
    }
}

__global__ __launch_bounds__(256) void k_adj(const int* __restrict__ src,
                                             const int* __restrict__ dst,
                                             u32* __restrict__ adj) {
    int e = blockIdx.x * 256 + threadIdx.x;
    int s = src[e], d = dst[e];
    int g = s >> 5;                          // edges are intra-graph
    u32 bidx = ((u32)g << 10) | ((u32)(d & 31) << 5) | (u32)(s & 31);
    atomicAdd(&adj[bidx >> 2], 1u << (8 * (bidx & 3)));
}

__global__ __launch_bounds__(512, 4) void k_mono(
        const void* __restrict__ featv, const void* __restrict__ cntv,
        const bf16* __restrict__ u_t,  const bf16* __restrict__ b_ih,
        const bf16* __restrict__ W_hh, const bf16* __restrict__ b_hh,
        const bf16* __restrict__ W_u,  const bf16* __restrict__ W_v,
        const bf16* __restrict__ b_v,  const bf16* __restrict__ w_e,
        const float* __restrict__ bw_in, const float* __restrict__ bw_og,
        const int* __restrict__ last_nodes, const u8* __restrict__ adj8,
        const u32* __restrict__ flag, float* __restrict__ out) {
    const int g2   = blockIdx.x;            // graph pair: graphs 2*g2, 2*g2+1
    const int tid  = threadIdx.x;
    const int wave = tid >> 6, lane = tid & 63, q = lane >> 4, c = lane & 15;
    const bool isf32 = (*flag) != 0u;
    const int col  = wave * 16 + c;         // this wave's output column (0..127)

    const int SF = 136;   // bf16 stride, 128-wide tiles (pad 8)
    const int SC = 264;   // bf16 stride, 256-wide P tile (pad 8)
    const int SA = 40;    // bf16 stride, 32-wide adjacency (pad 8)
    const int SH = 132;   // bf16 stride, hnp tile (pad 4)
    __shared__ __align__(16) bf16 s_feat[64 * 136];   // 17408 B (feat, later hn)
    __shared__ __align__(16) bf16 s_fc  [64 * 264];   // 33792 B (P)
    __shared__ __align__(16) bf16 s_adjb[64 * 40];    // 5120 B  adj[v][u] (2 graphs)
    __shared__ __align__(16) bf16 s_adjT[64 * 40];    // 5120 B  adj[u][v]
    __shared__ __align__(16) bf16 s_hnp [64 * 132];   // 16896 B h_n = feat@Vn+b
    __shared__ u32   s_adjw[512];                     // 2048 B; aliased by s_fv
    __shared__ float s_invin[64], s_invout[64];
    __shared__ float s_din[64], s_dout[64];
    __shared__ float s_e[64], s_alpha[64];
    float* s_fv = (float*)s_adjw;   // 256 floats; s_adjw dead after phase 1

    // ---------- phase 0: stage feat (64 contiguous rows) + adjacency --------
    if (isf32) {
        const float4* fp = (const float4*)((const float*)featv + (size_t)g2 * 8192);
        for (int ch = tid; ch < 2048; ch += 512) {
            float4 v = fp[ch];
            int row = ch >> 5, off = (ch & 31) * 4;
            bf16* dp = s_feat + row * SF + off;
            dp[0] = (bf16)v.x; dp[1] = (bf16)v.y; dp[2] = (bf16)v.z; dp[3] = (bf16)v.w;
        }
    } else {
        const uint4* fp = (const uint4*)((const bf16*)featv + (size_t)g2 * 8192);
        for (int ch = tid; ch < 1024; ch += 512) {
            int row = ch >> 4, off = (ch & 15) * 8;
            *(uint4*)(s_feat + row * SF + off) = fp[ch];
        }
    }
    s_adjw[tid] = ((const u32*)(adj8 + (size_t)g2 * 2048))[tid];
    if (tid < 64) s_e[tid] = 0.f;
    __syncthreads();   // B0

    // ---------- phase 1: adj->bf16 (+T), degrees+indicators, hnp -> LDS -----
    {
        u32 w = s_adjw[tid];
        int vrow = tid >> 3;            // global row 0..63
        int grp  = tid >> 8;            // graph within pair
        int vloc = vrow & 31;
        int u0 = (tid & 7) * 4;
#pragma unroll
        for (int j = 0; j < 4; ++j) {
            float cv = (float)((w >> (8 * j)) & 0xFFu);
            s_adjb[vrow * SA + u0 + j] = (bf16)cv;
            s_adjT[(grp * 32 + u0 + j) * SA + vloc] = (bf16)cv;
        }
    }
    if (tid < 64) {                                  // deg_in[row] = row-sum
        u32 s = 0;
        for (int i = 0; i < 8; ++i) {
            u32 w = s_adjw[tid * 8 + i];
            s += (w & 0xFF) + ((w >> 8) & 0xFF) + ((w >> 16) & 0xFF) + (w >> 24);
        }
        s_invin[tid] = 1.f / fmaxf((float)s, 1.f);
        s_din[tid] = (s > 0) ? 1.f : 0.f;
    } else if (tid < 128) {                          // deg_out = col-sum
        int uu = tid - 64; int grp = uu >> 5; int ul = uu & 31; u32 s = 0;
        for (int v = 0; v < 32; ++v)
            s += (s_adjw[grp * 256 + v * 8 + (ul >> 2)] >> (8 * (ul & 3))) & 0xFF;
        s_invout[uu] = 1.f / fmaxf((float)s, 1.f);
        s_dout[uu] = (s > 0) ? 1.f : 0.f;
    }
    // hnp = feat @ W_hh_n^T + b -> s_hnp (wave-private cols; frees 16 acc regs)
    {
        f32x4 hp[4] = {{0,0,0,0},{0,0,0,0},{0,0,0,0},{0,0,0,0}};
        const bf16* Vp = W_hh + (256 + col) * HDIM;
#pragma unroll 1
        for (int t = 0; t < 4; ++t) {
            bf16x8 b = *(const bf16x8*)(Vp + 32 * t + 8 * q);
#pragma unroll
            for (int fr = 0; fr < 4; ++fr) {
                bf16x8 a = *(const bf16x8*)(s_feat + (fr * 16 + c) * SF + 32 * t + 8 * q);
                hp[fr] = mfma16(a, b, hp[fr]);
            }
        }
        float bh = (float)b_hh[256 + col];
#pragma unroll
        for (int fr = 0; fr < 4; ++fr)
#pragma unroll
            for (int r = 0; r < 4; ++r)
                s_hnp[(fr * 16 + q * 4 + r) * SH + col] = (bf16)(hp[fr][r] + bh);
    }
    __syncthreads();   // B1

    // ---------- phase 2: P = [invin*(adj@feat) | invout*(adjT@feat)] --------
#pragma unroll 1
    for (int kk = 0; kk < 2; ++kk) {
        int ct = wave * 2 + kk;                // 0..15
        int colb = (ct & 7) * 16;
        const bf16* Ab = (ct < 8) ? s_adjb : s_adjT;
        const float* inv = (ct < 8) ? s_invin : s_invout;
        bf16x8 bA, bB;
        const bf16* Bp0 = s_feat + (q * 8) * SF + colb + c;
        const bf16* Bp1 = s_feat + (32 + q * 8) * SF + colb + c;
#pragma unroll
        for (int jj = 0; jj < 8; ++jj) { bA[jj] = Bp0[jj * SF]; bB[jj] = Bp1[jj * SF]; }
        bf16x8 a0 = *(const bf16x8*)(Ab + c * SA + 8 * q);
        bf16x8 a1 = *(const bf16x8*)(Ab + (16 + c) * SA + 8 * q);
        bf16x8 a2 = *(const bf16x8*)(Ab + (32 + c) * SA + 8 * q);
        bf16x8 a3 = *(const bf16x8*)(Ab + (48 + c) * SA + 8 * q);
        f32x4 z = {0, 0, 0, 0};
        f32x4 p0 = mfma16(a0, bA, z);
        f32x4 p1 = mfma16(a1, bA, z);
        f32x4 p2 = mfma16(a2, bB, z);
        f32x4 p3 = mfma16(a3, bB, z);
#pragma unroll
        for (int r = 0; r < 4; ++r) {
            int r0 = q * 4 + r;
            s_fc[(r0)      * SC + ct * 16 + c] = (bf16)(p0[r] * inv[r0]);
            s_fc[(16 + r0) * SC + ct * 16 + c] = (bf16)(p1[r] * inv[16 + r0]);
            s_fc[(32 + r0) * SC + ct * 16 + c] = (bf16)(p2[r] * inv[32 + r0]);
            s_fc[(48 + r0) * SC + ct * 16 + c] = (bf16)(p3[r] * inv[48 + r0]);
        }
    }
    __syncthreads();   // B2

    // ---------- phase 3: GRU — merged U+V loop, unroll 2 for MLP ------------
    f32x4 rr[4] = {{0,0,0,0},{0,0,0,0},{0,0,0,0},{0,0,0,0}};
    f32x4 zz[4] = {{0,0,0,0},{0,0,0,0},{0,0,0,0},{0,0,0,0}};
    f32x4 in_[4] = {{0,0,0,0},{0,0,0,0},{0,0,0,0},{0,0,0,0}};
    {
        const bf16* Ur = u_t + (size_t)(col) * 256;
        const bf16* Uz = u_t + (size_t)(128 + col) * 256;
        const bf16* Un = u_t + (size_t)(256 + col) * 256;
        const bf16* Vr = W_hh + (col) * HDIM;
        const bf16* Vz = W_hh + (128 + col) * HDIM;
#pragma unroll 2
        for (int t = 0; t < 8; ++t) {
            bf16x8 br = *(const bf16x8*)(Ur + 32 * t + 8 * q);
            bf16x8 bz = *(const bf16x8*)(Uz + 32 * t + 8 * q);
            bf16x8 bn = *(const bf16x8*)(Un + 32 * t + 8 * q);
#pragma unroll
            for (int fr = 0; fr < 4; ++fr) {
                bf16x8 a = *(const bf16x8*)(s_fc + (fr * 16 + c) * SC + 32 * t + 8 * q);
                rr[fr] = mfma16(a, br, rr[fr]);
                zz[fr] = mfma16(a, bz, zz[fr]);
                in_[fr] = mfma16(a, bn, in_[fr]);
            }
            if (t < 4) {
                bf16x8 vr = *(const bf16x8*)(Vr + 32 * t + 8 * q);
                bf16x8 vz = *(const bf16x8*)(Vz + 32 * t + 8 * q);
#pragma unroll
                for (int fr = 0; fr < 4; ++fr) {
                    bf16x8 f = *(const bf16x8*)(s_feat + (fr * 16 + c) * SF + 32 * t + 8 * q);
                    rr[fr] = mfma16(f, vr, rr[fr]);
                    zz[fr] = mfma16(f, vz, zz[fr]);
                }
            }
        }
    }
    // epilogue -> hn into hv[] regs (hnp read from LDS, wave-private cols)
    f32x4 hv[4];
    {
        float brz  = (float)b_ih[col]       + (float)b_hh[col];
        float bzz  = (float)b_ih[128 + col] + (float)b_hh[128 + col];
        float bin_ = (float)b_ih[256 + col];
        float bwr_i = bw_in[col],       bwr_o = bw_og[col];
        float bwz_i = bw_in[128 + col], bwz_o = bw_og[128 + col];
        float bwn_i = bw_in[256 + col], bwn_o = bw_og[256 + col];
#pragma unroll
        for (int fr = 0; fr < 4; ++fr) {
#pragma unroll
            for (int r = 0; r < 4; ++r) {
                int row = fr * 16 + q * 4 + r;
                float di = s_din[row], dou = s_dout[row];
                float rg = sigmoidf_(rr[fr][r] + brz + di * bwr_i + dou * bwr_o);
                float z_ = sigmoidf_(zz[fr][r] + bzz + di * bwz_i + dou * bwz_o);
                float ng = tanhf_(in_[fr][r] + bin_ + di * bwn_i + dou * bwn_o
                                  + rg * (float)s_hnp[row * SH + col]);
                float fv = (float)s_feat[row * SF + col];
                hv[fr][r] = (1.f - z_) * ng + z_ * fv;
            }
        }
    }
    int llA = last_nodes[2 * g2] & 31;
    int llB = 32 + (last_nodes[2 * g2 + 1] & 31);
    __syncthreads();   // B3a (all s_feat reads done)
#pragma unroll
    for (int fr = 0; fr < 4; ++fr)
#pragma unroll
        for (int r = 0; r < 4; ++r)
            s_feat[(fr * 16 + q * 4 + r) * SF + col] = (bf16)hv[fr][r];
    __syncthreads();   // B3b (s_feat now holds hn)
    const bf16* s_hn = s_feat;

    // ---------- phase 4: feat_v = hn[ll] @ W_v^T + b_v, per graph -----------
#pragma unroll 1
    for (int gsel = 0; gsel < 2; ++gsel) {
        int ll = gsel ? llB : llA;
        const bf16* Ap = s_hn + ll * SF;
        const bf16* Wp = W_v + (size_t)col * HDIM;
        f32x4 acc = {0, 0, 0, 0};
#pragma unroll 1
        for (int t = 0; t < 4; ++t) {
            bf16x8 a = *(const bf16x8*)(Ap + 32 * t + 8 * q);
            bf16x8 b = *(const bf16x8*)(Wp + 32 * t + 8 * q);
            acc = mfma16(a, b, acc);
        }
        if (q == 0) s_fv[gsel * 128 + col] = acc[0] + (float)b_v[col];
    }
    __syncthreads();   // B4

    // ---------- phase 5: e[n] = sum_col sigmoid((hn@W_u^T)+fv)*w_e ----------
    {
        const bf16* Wp = W_u + (size_t)col * HDIM;
        f32x4 ee[4] = {{0,0,0,0},{0,0,0,0},{0,0,0,0},{0,0,0,0}};
#pragma unroll 1
        for (int t = 0; t < 4; ++t) {
            bf16x8 b = *(const bf16x8*)(Wp + 32 * t + 8 * q);
#pragma unroll
            for (int fr = 0; fr < 4; ++fr) {
                bf16x8 a = *(const bf16x8*)(s_hn + (fr * 16 + c) * SF + 32 * t + 8 * q);
                ee[fr] = mfma16(a, b, ee[fr]);
            }
        }
        float we = (float)w_e[col];
        float fvA = s_fv[col], fvB = s_fv[128 + col];
#pragma unroll
        for (int fr = 0; fr < 4; ++fr) {
            float fv = (fr < 2) ? fvA : fvB;
#pragma unroll
            for (int r = 0; r < 4; ++r) {
                float v = sigmoidf_(ee[fr][r] + fv) * we;
                for (int m = 1; m < 16; m <<= 1) v += __shfl_xor(v, m);
                if (c == 0) atomicAdd(&s_e[fr * 16 + q * 4 + r], v);
            }
        }
    }
    __syncthreads();   // B5
    if (tid < 64) {
        float cv = isf32 ? ((const float*)cntv)[(size_t)g2 * 64 + tid]
                         : (float)((const bf16*)cntv)[(size_t)g2 * 64 + tid];
        s_alpha[tid] = s_e[tid] * cv;
    }
    __syncthreads();   // B6

    // ---------- output (f32): per graph [ct_g (128) | ct_l (128)] -----------
    {
        int part = tid >> 7;        // 0..3
        int co = tid & 127;
        if (part == 0) {
            float s = 0.f;
#pragma unroll 4
            for (int n = 0; n < 32; ++n) s += s_alpha[n] * (float)s_hn[n * SF + co];
            out[(size_t)(2 * g2) * 256 + co] = s;
        } else if (part == 1) {
            out[(size_t)(2 * g2) * 256 + 128 + co] = (float)s_hn[llA * SF + co];
        } else if (part == 2) {
            float s = 0.f;
#pragma unroll 4
            for (int n = 32; n < 64; ++n) s += s_alpha[n] * (float)s_hn[n * SF + co];
            out[(size_t)(2 * g2 + 1) * 256 + co] = s;
        } else {
            out[(size_t)(2 * g2 + 1) * 256 + 128 + co] = (float)s_hn[llB * SF + co];
        }
    }
}

extern "C" void kernel_launch(void* const* d_in, const int* in_sizes, int n_in,
                              void* d_out, int out_size, void* d_ws, size_t ws_size,
                              hipStream_t stream) {
    const int* src  = (const int*)d_in[14];
    const int* dst  = (const int*)d_in[15];
    const int* last = (const int*)d_in[17];
    float* out = (float*)d_out;

    u32*  flag  = (u32*)d_ws;
    bf16* conv  = (bf16*)((char*)d_ws + 4096);
    float* bwin = (float*)((char*)d_ws + 430 * 1024);
    float* bwog = (float*)((char*)d_ws + 434 * 1024);
    bf16* u_t   = (bf16*)((char*)d_ws + 448 * 1024);   // 384x256 bf16 = 192KB
    u32*  adjw  = (u32*)((char*)d_ws + (1u << 20));
    const u8* adj8 = (const u8*)adjw;

    // bf16 weight copies, contiguous in input order 2..13
    const int cnts[12] = {16384, 128, 16384, 128, 98304, 384, 49152, 384,
                          16384, 16384, 128, 128};
    bf16* cp[12];
    {
        bf16* p = conv;
        for (int i = 0; i < 12; ++i) { cp[i] = p; p += cnts[i]; }
    }

    hipMemsetAsync(adjw, 0, 8u << 20, stream);          // zero adj (was 2048 blocks)
    k_prep<<<(NCONV + 2047) / 2048, 256, 0, stream>>>(
        (const u32*)d_in[0], conv, flag,
        d_in[2], d_in[3], d_in[4], d_in[5], d_in[6], d_in[7],
        d_in[8], d_in[9], d_in[10], d_in[11], d_in[12], d_in[13]);
    k_fuse<<<96, 256, 0, stream>>>(cp[0], cp[1], cp[2], cp[3], cp[4], cp[5],
                                   u_t, bwin, bwog);
    k_adj<<<NEDGE / 256, 256, 0, stream>>>(src, dst, adjw);
    k_mono<<<NG / 2, 512, 0, stream>>>(d_in[0], d_in[1],
                                       u_t, cp[5], cp[6], cp[7],
                                       cp[8], cp[9], cp[10], cp[11],
                                       bwin, bwog,
                                       last, adj8, flag, out);
}

// Round 8
// 473.005 us; speedup vs baseline: 1.6228x; 1.0182x over previous
//
#include <hip/hip_runtime.h>

// SRGNN — Round 16: cut the serial phase chain — barriers 8 -> 5, phases -2.
//  r15 post-mortem: k_mono 334->306us (no spill, VGPR 52), total flat (~481):
//  bench gap ~150-175us is mostly harness/launch overhead; k_mono (64%) is
//  the lever. k_mono is exposed-latency bound (MFMA 13%, VALU 40%), 8 barriers
//  each drain all in-flight mem with only 2 blocks/CU to cover.
//  Changes (structure, no new math):
//   1. hn -> s_hnp region (wave-private cols on BOTH read & write) => B3a gone;
//      s_feat never overwritten. SH=136 for 16B-aligned reads.
//   2. feat_v: broadcast-A MFMA => every lane's acc[0] == fv[its col]; phase 5
//      uses register fvA/fvB => B4 + phase gone.
//   3. cnt staged in phase 0 (s_cnt); output uses s_e*s_cnt directly => B6 +
//      alpha phase gone.
//   4. s_adjw aliased into s_fc (dead before P written); adjb/adjT conversion
//      moved pre-B0 (register word). LDS 80.4KB -> still 2 blocks/CU.
//   5. kk-loop / colsum unrolled (independent iters; text budget OK post-r12).
//  Barriers now: B0 (stage) B1 (deg+hnp) B2 (P) B3 (hn) B5 (s_e atomics).
//  Tripwires: WRITE >> 8.2MB => spill; absmax shift => aliasing/fv bug.
// ws: [0] flag ; [4K] bf16 conv (~419KB) ; [430K] bw_in/bw_og f32 ;
//     [448K] u_t bf16 384x256 (192KB) ; [1MiB] adj u8 (8MB).

#define NG    8192
#define NODES 32
#define HDIM  128
#define NEDGE 524288
#define NCONV 214272   // total weight elements (inputs 2..13)

typedef __bf16 bf16;
typedef __bf16 bf16x8 __attribute__((ext_vector_type(8)));
typedef float  f32x4  __attribute__((ext_vector_type(4)));
typedef unsigned int u32;
typedef unsigned char u8;

__device__ __forceinline__ f32x4 mfma16(bf16x8 a, bf16x8 b, f32x4 c) {
    // D = A(16x32)*B(32x16)+C ; A[m=lane&15][k=quad*8+j], B[k=quad*8+j][n=lane&15],
    // D[row=quad*4+r][col=lane&15]
    return __builtin_amdgcn_mfma_f32_16x16x32_bf16(a, b, c, 0, 0, 0);
}

__device__ __forceinline__ float sigmoidf_(float x) { return 1.f / (1.f + __expf(-x)); }
__device__ __forceinline__ float tanhf_(float x) { return 1.f - 2.f / (__expf(2.f * x) + 1.f); }

// ---- k_prep: 105 convert blocks (zeroing via hipMemsetAsync) ---------------
__global__ __launch_bounds__(256) void k_prep(
        const u32* __restrict__ featw,
        bf16* __restrict__ conv, u32* __restrict__ flagout,
        const void* t0, const void* t1, const void* t2,  const void* t3,
        const void* t4, const void* t5, const void* t6,  const void* t7,
        const void* t8, const void* t9, const void* t10, const void* t11) {
    const int b = blockIdx.x, tid = threadIdx.x;
    __shared__ int s_isf32;
    if (tid == 0) s_isf32 = 0;
    __syncthreads();
    {
        u32 hit = 0;
#pragma unroll
        for (int k = 0; k < 16; ++k) {
            u32 x = featw[tid * 16 + k];
            hit |= (((x >> 7) & 0xFFu) == 0xFFu) ? 1u : 0u;
        }
        if (hit) s_isf32 = 1;             // benign race
    }
    __syncthreads();
    const bool isf32 = s_isf32 != 0;
    if (b == 0 && tid == 0) *flagout = isf32 ? 1u : 0u;

    int e0 = b * 2048 + tid * 8;
    if (e0 >= NCONV) return;
    const int cnts[12] = {16384, 128, 16384, 128, 98304, 384, 49152, 384,
                          16384, 16384, 128, 128};
    int t = 0, base = 0;
    while (e0 >= base + cnts[t]) { base += cnts[t]; ++t; }
    int off = e0 - base;
    const void* sp;
    switch (t) {
        case 0: sp = t0; break; case 1: sp = t1; break;
        case 2: sp = t2; break; case 3: sp = t3; break;
        case 4: sp = t4; break; case 5: sp = t5; break;
        case 6: sp = t6; break; case 7: sp = t7; break;
        case 8: sp = t8; break; case 9: sp = t9; break;
        case 10: sp = t10; break; default: sp = t11; break;
    }
    if (isf32) {
        const float4* s = (const float4*)sp + (off >> 2);
        float4 a = s[0], bb = s[1];
        bf16x8 v;
        v[0] = (bf16)a.x;  v[1] = (bf16)a.y;  v[2] = (bf16)a.z;  v[3] = (bf16)a.w;
        v[4] = (bf16)bb.x; v[5] = (bf16)bb.y; v[6] = (bf16)bb.z; v[7] = (bf16)bb.w;
        *(bf16x8*)(conv + e0) = v;
    } else {
        *(uint4*)(conv + e0) = ((const uint4*)sp)[off >> 3];
    }
}

// ---- k_fuse: 96 blocks (jt = b>>2, ksel = b&3) -----------------------------
__global__ __launch_bounds__(256) void k_fuse(
        const bf16* __restrict__ W_in, const bf16* __restrict__ b_in,
        const bf16* __restrict__ W_og, const bf16* __restrict__ b_og,
        const bf16* __restrict__ W_ih, const bf16* __restrict__ b_ih,
        bf16* __restrict__ u_t, float* __restrict__ bw_in,
        float* __restrict__ bw_og) {
    const int jt = blockIdx.x >> 2;            // 0..23
    const int ksel = blockIdx.x & 3;
    const int tid = threadIdx.x;
    const int wave = tid >> 6, lane = tid & 63, q = lane >> 4, c = lane & 15;
    {
        int kt = wave * 4 + ksel;              // 0..15 (col tile of 256)
        bool og = kt >= 8;
        const bf16* Wsrc = og ? W_og : W_in;   // [128][128] row-major
        int kcol = (kt & 7) * 16 + c;          // 0..127
        int mo = og ? 128 : 0;
        f32x4 acc = {0, 0, 0, 0};
#pragma unroll 1
        for (int t = 0; t < 4; ++t) {
            bf16x8 a = *(const bf16x8*)(W_ih + (jt * 16 + c) * 256 + mo + 32 * t + 8 * q);
            bf16x8 b;
#pragma unroll
            for (int jj = 0; jj < 8; ++jj)
                b[jj] = Wsrc[(32 * t + 8 * q + jj) * 128 + kcol];
            acc = mfma16(a, b, acc);
        }
#pragma unroll
        for (int r = 0; r < 4; ++r)
            u_t[(size_t)(jt * 16 + q * 4 + r) * 256 + kt * 16 + c] = (bf16)acc[r];
    }
    if (ksel == 0) {   // bias: jj = tid>>4 (16 j's), mm = tid&15, shfl reduce
        int jj = tid >> 4, mm = tid & 15;
        int j = jt * 16 + jj;
        float si = 0.f, so = 0.f;
#pragma unroll
        for (int i = 0; i < 8; ++i) {
            int m = mm * 8 + i;
            si += (float)b_in[m] * (float)W_ih[j * 256 + m];
            so += (float)b_og[m] * (float)W_ih[j * 256 + 128 + m];
        }
        for (int m = 1; m < 16; m <<= 1) {
            si += __shfl_xor(si, m);
            so += __shfl_xor(so, m);
        }
        if (mm == 0) { bw_in[j] = si; bw_og[j] = so; }
    }
}

__global__ __launch_bounds__(256) void k_adj(const int* __restrict__ src,
                                             const int* __restrict__ dst,
                                             u32* __restrict__ adj) {
    int e = blockIdx.x * 256 + threadIdx.x;
    int s = src[e], d = dst[e];
    int g = s >> 5;                          // edges are intra-graph
    u32 bidx = ((u32)g << 10) | ((u32)(d & 31) << 5) | (u32)(s & 31);
    atomicAdd(&adj[bidx >> 2], 1u << (8 * (bidx & 3)));
}

__global__ __launch_bounds__(512, 4) void k_mono(
        const void* __restrict__ featv, const void* __restrict__ cntv,
        const bf16* __restrict__ u_t,  const bf16* __restrict__ b_ih,
        const bf16* __restrict__ W_hh, const bf16* __restrict__ b_hh,
        const bf16* __restrict__ W_u,  const bf16* __restrict__ W_v,
        const bf16* __restrict__ b_v,  const bf16* __restrict__ w_e,
        const float* __restrict__ bw_in, const float* __restrict__ bw_og,
        const int* __restrict__ last_nodes, const u8* __restrict__ adj8,
        const u32* __restrict__ flag, float* __restrict__ out) {
    const int g2   = blockIdx.x;            // graph pair: graphs 2*g2, 2*g2+1
    const int tid  = threadIdx.x;
    const int wave = tid >> 6, lane = tid & 63, q = lane >> 4, c = lane & 15;
    const bool isf32 = (*flag) != 0u;
    const int col  = wave * 16 + c;         // this wave's output column (0..127)

    const int SF = 136;   // bf16 stride, feat tile (pad 8)
    const int SC = 264;   // bf16 stride, P tile (pad 8)
    const int SA = 40;    // bf16 stride, adjacency (pad 8)
    const int SH = 136;   // bf16 stride, hnp/hn tile (16B-aligned rows)
    __shared__ __align__(16) bf16 s_feat[64 * 136];   // 17408 B (feat, stays feat)
    __shared__ __align__(16) bf16 s_fc  [64 * 264];   // 33792 B (P; adjw aliased)
    __shared__ __align__(16) bf16 s_adjb[64 * 40];    // 5120 B  adj[v][u]
    __shared__ __align__(16) bf16 s_adjT[64 * 40];    // 5120 B  adj[u][v]
    __shared__ __align__(16) bf16 s_hnp [64 * 136];   // 17408 B hnp, then hn
    __shared__ float s_invin[64], s_invout[64];
    __shared__ float s_din[64], s_dout[64];
    __shared__ float s_e[64], s_cnt[64];
    u32* s_adjw = (u32*)s_fc;   // alias: read pre-B1 only; s_fc written post-B1

    // ---------- phase 0: stage feat + adj word + adjb/adjT + cnt + e=0 ------
    if (isf32) {
        const float4* fp = (const float4*)((const float*)featv + (size_t)g2 * 8192);
        for (int ch = tid; ch < 2048; ch += 512) {
            float4 v = fp[ch];
            int row = ch >> 5, off = (ch & 31) * 4;
            bf16* dp = s_feat + row * SF + off;
            dp[0] = (bf16)v.x; dp[1] = (bf16)v.y; dp[2] = (bf16)v.z; dp[3] = (bf16)v.w;
        }
    } else {
        const uint4* fp = (const uint4*)((const bf16*)featv + (size_t)g2 * 8192);
        for (int ch = tid; ch < 1024; ch += 512) {
            int row = ch >> 4, off = (ch & 15) * 8;
            *(uint4*)(s_feat + row * SF + off) = fp[ch];
        }
    }
    {
        u32 w = ((const u32*)(adj8 + (size_t)g2 * 2048))[tid];
        s_adjw[tid] = w;
        int vrow = tid >> 3;            // global row 0..63
        int grp  = tid >> 8;            // graph within pair
        int vloc = vrow & 31;
        int u0 = (tid & 7) * 4;
#pragma unroll
        for (int j = 0; j < 4; ++j) {
            float cv = (float)((w >> (8 * j)) & 0xFFu);
            s_adjb[vrow * SA + u0 + j] = (bf16)cv;
            s_adjT[(grp * 32 + u0 + j) * SA + vloc] = (bf16)cv;
        }
    }
    if (tid < 64) {
        s_e[tid] = 0.f;
        s_cnt[tid] = isf32 ? ((const float*)cntv)[(size_t)g2 * 64 + tid]
                           : (float)((const bf16*)cntv)[(size_t)g2 * 64 + tid];
    }
    __syncthreads();   // B0

    // ---------- phase 1: degrees (from s_adjw alias) + hnp GEMM -------------
    if (tid < 64) {                                  // deg_in[row] = row-sum
        u32 s = 0;
#pragma unroll
        for (int i = 0; i < 8; ++i) {
            u32 w = s_adjw[tid * 8 + i];
            s += (w & 0xFF) + ((w >> 8) & 0xFF) + ((w >> 16) & 0xFF) + (w >> 24);
        }
        s_invin[tid] = 1.f / fmaxf((float)s, 1.f);
        s_din[tid] = (s > 0) ? 1.f : 0.f;
    } else if (tid < 128) {                          // deg_out = col-sum
        int uu = tid - 64; int grp = uu >> 5; int ul = uu & 31; u32 s = 0;
#pragma unroll 8
        for (int v = 0; v < 32; ++v)
            s += (s_adjw[grp * 256 + v * 8 + (ul >> 2)] >> (8 * (ul & 3))) & 0xFF;
        s_invout[uu] = 1.f / fmaxf((float)s, 1.f);
        s_dout[uu] = (s > 0) ? 1.f : 0.f;
    }
    // hnp = feat @ W_hh_n^T + b -> s_hnp (wave-private cols)
    {
        f32x4 hp[4] = {{0,0,0,0},{0,0,0,0},{0,0,0,0},{0,0,0,0}};
        const bf16* Vp = W_hh + (256 + col) * HDIM;
#pragma unroll 1
        for (int t = 0; t < 4; ++t) {
            bf16x8 b = *(const bf16x8*)(Vp + 32 * t + 8 * q);
#pragma unroll
            for (int fr = 0; fr < 4; ++fr) {
                bf16x8 a = *(const bf16x8*)(s_feat + (fr * 16 + c) * SF + 32 * t + 8 * q);
                hp[fr] = mfma16(a, b, hp[fr]);
            }
        }
        float bh = (float)b_hh[256 + col];
#pragma unroll
        for (int fr = 0; fr < 4; ++fr)
#pragma unroll
            for (int r = 0; r < 4; ++r)
                s_hnp[(fr * 16 + q * 4 + r) * SH + col] = (bf16)(hp[fr][r] + bh);
    }
    __syncthreads();   // B1 (degrees + hnp ready; s_adjw alias now dead)

    // ---------- phase 2: P = [invin*(adj@feat) | invout*(adjT@feat)] --------
#pragma unroll
    for (int kk = 0; kk < 2; ++kk) {
        int ct = wave * 2 + kk;                // 0..15
        int colb = (ct & 7) * 16;
        const bf16* Ab = (ct < 8) ? s_adjb : s_adjT;
        const float* inv = (ct < 8) ? s_invin : s_invout;
        bf16x8 bA, bB;
        const bf16* Bp0 = s_feat + (q * 8) * SF + colb + c;
        const bf16* Bp1 = s_feat + (32 + q * 8) * SF + colb + c;
#pragma unroll
        for (int jj = 0; jj < 8; ++jj) { bA[jj] = Bp0[jj * SF]; bB[jj] = Bp1[jj * SF]; }
        bf16x8 a0 = *(const bf16x8*)(Ab + c * SA + 8 * q);
        bf16x8 a1 = *(const bf16x8*)(Ab + (16 + c) * SA + 8 * q);
        bf16x8 a2 = *(const bf16x8*)(Ab + (32 + c) * SA + 8 * q);
        bf16x8 a3 = *(const bf16x8*)(Ab + (48 + c) * SA + 8 * q);
        f32x4 z = {0, 0, 0, 0};
        f32x4 p0 = mfma16(a0, bA, z);
        f32x4 p1 = mfma16(a1, bA, z);
        f32x4 p2 = mfma16(a2, bB, z);
        f32x4 p3 = mfma16(a3, bB, z);
#pragma unroll
        for (int r = 0; r < 4; ++r) {
            int r0 = q * 4 + r;
            s_fc[(r0)      * SC + ct * 16 + c] = (bf16)(p0[r] * inv[r0]);
            s_fc[(16 + r0) * SC + ct * 16 + c] = (bf16)(p1[r] * inv[16 + r0]);
            s_fc[(32 + r0) * SC + ct * 16 + c] = (bf16)(p2[r] * inv[32 + r0]);
            s_fc[(48 + r0) * SC + ct * 16 + c] = (bf16)(p3[r] * inv[48 + r0]);
        }
    }
    __syncthreads();   // B2

    // ---------- phase 3: GRU (merged U+V, unroll 2); hn -> s_hnp own cols ---
    f32x4 rr[4] = {{0,0,0,0},{0,0,0,0},{0,0,0,0},{0,0,0,0}};
    f32x4 zz[4] = {{0,0,0,0},{0,0,0,0},{0,0,0,0},{0,0,0,0}};
    f32x4 in_[4] = {{0,0,0,0},{0,0,0,0},{0,0,0,0},{0,0,0,0}};
    {
        const bf16* Ur = u_t + (size_t)(col) * 256;
        const bf16* Uz = u_t + (size_t)(128 + col) * 256;
        const bf16* Un = u_t + (size_t)(256 + col) * 256;
        const bf16* Vr = W_hh + (col) * HDIM;
        const bf16* Vz = W_hh + (128 + col) * HDIM;
#pragma unroll 2
        for (int t = 0; t < 8; ++t) {
            bf16x8 br = *(const bf16x8*)(Ur + 32 * t + 8 * q);
            bf16x8 bz = *(const bf16x8*)(Uz + 32 * t + 8 * q);
            bf16x8 bn = *(const bf16x8*)(Un + 32 * t + 8 * q);
#pragma unroll
            for (int fr = 0; fr < 4; ++fr) {
                bf16x8 a = *(const bf16x8*)(s_fc + (fr * 16 + c) * SC + 32 * t + 8 * q);
                rr[fr] = mfma16(a, br, rr[fr]);
                zz[fr] = mfma16(a, bz, zz[fr]);
                in_[fr] = mfma16(a, bn, in_[fr]);
            }
            if (t < 4) {
                bf16x8 vr = *(const bf16x8*)(Vr + 32 * t + 8 * q);
                bf16x8 vz = *(const bf16x8*)(Vz + 32 * t + 8 * q);
#pragma unroll
                for (int fr = 0; fr < 4; ++fr) {
                    bf16x8 f = *(const bf16x8*)(s_feat + (fr * 16 + c) * SF + 32 * t + 8 * q);
                    rr[fr] = mfma16(f, vr, rr[fr]);
                    zz[fr] = mfma16(f, vz, zz[fr]);
                }
            }
        }
    }
    // epilogue: read hnp (own cols) -> hv; then overwrite s_hnp with hn (own cols)
    f32x4 hv[4];
    {
        float brz  = (float)b_ih[col]       + (float)b_hh[col];
        float bzz  = (float)b_ih[128 + col] + (float)b_hh[128 + col];
        float bin_ = (float)b_ih[256 + col];
        float bwr_i = bw_in[col],       bwr_o = bw_og[col];
        float bwz_i = bw_in[128 + col], bwz_o = bw_og[128 + col];
        float bwn_i = bw_in[256 + col], bwn_o = bw_og[256 + col];
#pragma unroll
        for (int fr = 0; fr < 4; ++fr) {
#pragma unroll
            for (int r = 0; r < 4; ++r) {
                int row = fr * 16 + q * 4 + r;
                float di = s_din[row], dou = s_dout[row];
                float rg = sigmoidf_(rr[fr][r] + brz + di * bwr_i + dou * bwr_o);
                float z_ = sigmoidf_(zz[fr][r] + bzz + di * bwz_i + dou * bwz_o);
                float ng = tanhf_(in_[fr][r] + bin_ + di * bwn_i + dou * bwn_o
                                  + rg * (float)s_hnp[row * SH + col]);
                float fv = (float)s_feat[row * SF + col];
                hv[fr][r] = (1.f - z_) * ng + z_ * fv;
            }
        }
    }
    int llA = last_nodes[2 * g2] & 31;
    int llB = 32 + (last_nodes[2 * g2 + 1] & 31);
#pragma unroll
    for (int fr = 0; fr < 4; ++fr)
#pragma unroll
        for (int r = 0; r < 4; ++r)
            s_hnp[(fr * 16 + q * 4 + r) * SH + col] = (bf16)hv[fr][r];
    __syncthreads();   // B3 (hn visible everywhere)
    const bf16* s_hn = s_hnp;

    // ---------- phase 4+5: fv in regs, then e via MFMA + shfl + s_e atomics -
    float fvA, fvB;
    {
        const bf16* Wp = W_v + (size_t)col * HDIM;
        f32x4 accA = {0, 0, 0, 0}, accB = {0, 0, 0, 0};
#pragma unroll 2
        for (int t = 0; t < 4; ++t) {
            bf16x8 b  = *(const bf16x8*)(Wp + 32 * t + 8 * q);
            bf16x8 aA = *(const bf16x8*)(s_hn + llA * SH + 32 * t + 8 * q);
            bf16x8 aB = *(const bf16x8*)(s_hn + llB * SH + 32 * t + 8 * q);
            accA = mfma16(aA, b, accA);
            accB = mfma16(aB, b, accB);
        }
        // broadcast-A: every lane's acc[0] == fv[col] (A rows identical)
        fvA = accA[0] + (float)b_v[col];
        fvB = accB[0] + (float)b_v[col];
    }
    {
        const bf16* Wp = W_u + (size_t)col * HDIM;
        f32x4 ee[4] = {{0,0,0,0},{0,0,0,0},{0,0,0,0},{0,0,0,0}};
#pragma unroll 2
        for (int t = 0; t < 4; ++t) {
            bf16x8 b = *(const bf16x8*)(Wp + 32 * t + 8 * q);
#pragma unroll
            for (int fr = 0; fr < 4; ++fr) {
                bf16x8 a = *(const bf16x8*)(s_hn + (fr * 16 + c) * SH + 32 * t + 8 * q);
                ee[fr] = mfma16(a, b, ee[fr]);
            }
        }
        float we = (float)w_e[col];
#pragma unroll
        for (int fr = 0; fr < 4; ++fr) {
            float fv = (fr < 2) ? fvA : fvB;
#pragma unroll
            for (int r = 0; r < 4; ++r) {
                float v = sigmoidf_(ee[fr][r] + fv) * we;
                for (int m = 1; m < 16; m <<= 1) v += __shfl_xor(v, m);
                if (c == 0) atomicAdd(&s_e[fr * 16 + q * 4 + r], v);
            }
        }
    }
    __syncthreads();   // B5 (s_e final)

    // ---------- output (f32): per graph [ct_g (128) | ct_l (128)] -----------
    {
        int part = tid >> 7;        // 0..3
        int co = tid & 127;
        if (part == 0) {
            float s = 0.f;
#pragma unroll 8
            for (int n = 0; n < 32; ++n)
                s += s_e[n] * s_cnt[n] * (float)s_hn[n * SH + co];
            out[(size_t)(2 * g2) * 256 + co] = s;
        } else if (part == 1) {
            out[(size_t)(2 * g2) * 256 + 128 + co] = (float)s_hn[llA * SH + co];
        } else if (part == 2) {
            float s = 0.f;
#pragma unroll 8
            for (int n = 32; n < 64; ++n)
                s += s_e[n] * s_cnt[n] * (float)s_hn[n * SH + co];
            out[(size_t)(2 * g2 + 1) * 256 + co] = s;
        } else {
            out[(size_t)(2 * g2 + 1) * 256 + 128 + co] = (float)s_hn[llB * SH + co];
        }
    }
}

extern "C" void kernel_launch(void* const* d_in, const int* in_sizes, int n_in,
                              void* d_out, int out_size, void* d_ws, size_t ws_size,
                              hipStream_t stream) {
    const int* src  = (const int*)d_in[14];
    const int* dst  = (const int*)d_in[15];
    const int* last = (const int*)d_in[17];
    float* out = (float*)d_out;

    u32*  flag  = (u32*)d_ws;
    bf16* conv  = (bf16*)((char*)d_ws + 4096);
    float* bwin = (float*)((char*)d_ws + 430 * 1024);
    float* bwog = (float*)((char*)d_ws + 434 * 1024);
    bf16* u_t   = (bf16*)((char*)d_ws + 448 * 1024);   // 384x256 bf16 = 192KB
    u32*  adjw  = (u32*)((char*)d_ws + (1u << 20));
    const u8* adj8 = (const u8*)adjw;

    // bf16 weight copies, contiguous in input order 2..13
    const int cnts[12] = {16384, 128, 16384, 128, 98304, 384, 49152, 384,
                          16384, 16384, 128, 128};
    bf16* cp[12];
    {
        bf16* p = conv;
        for (int i = 0; i < 12; ++i) { cp[i] = p; p += cnts[i]; }
    }

    hipMemsetAsync(adjw, 0, 8u << 20, stream);          // zero adj
    k_prep<<<(NCONV + 2047) / 2048, 256, 0, stream>>>(
        (const u32*)d_in[0], conv, flag,
        d_in[2], d_in[3], d_in[4], d_in[5], d_in[6], d_in[7],
        d_in[8], d_in[9], d_in[10], d_in[11], d_in[12], d_in[13]);
    k_fuse<<<96, 256, 0, stream>>>(cp[0], cp[1], cp[2], cp[3], cp[4], cp[5],
                                   u_t, bwin, bwog);
    k_adj<<<NEDGE / 256, 256, 0, stream>>>(src, dst, adjw);
    k_mono<<<NG / 2, 512, 0, stream>>>(d_in[0], d_in[1],
                                       u_t, cp[5], cp[6], cp[7],
                                       cp[8], cp[9], cp[10], cp[11],
                                       bwin, bwog,
                                       last, adj8, flag, out);
}

// Round 11
// 470.991 us; speedup vs baseline: 1.6298x; 1.0043x over previous
//
#include <hip/hip_runtime.h>

// SRGNN — Round 19: de-risk. Launch side reverted to r16's byte-proven
//  structure (memset + k_prep + k_fuse + k_adj + k_mono, plain launches —
//  passed at 473us). r17 (cooperative) and r18 (merged k_pre) both died with
//  "container failed twice"; r18 had no plausible kernel-side killer, so infra
//  flakiness is the leading theory — this round discriminates: if THIS fails,
//  it's conclusively infra (r16 verbatim next).
//  Carried forward (in-kernel only, low risk):
//   (a) GRU loop static split t<4 (U+V) / t>=4 (U-only) — no per-iter dynamic
//       branch, scheduler can batch the 5 weight-frag loads;
//   (b) s_setprio(1) around the GRU MFMA cluster (2 independent blocks/CU =
//       phase-staggered waves, the regime where setprio measured +; free if null).
//  Tripwires: WRITE >> 8.2MB => split raised live-range past 128 regs => revert
//  split; absmax shift => bug; fail => infra.
// ws: [0] flag ; [4K] bf16 conv (~419KB) ; [430K] bw_in/bw_og f32 ;
//     [448K] u_t bf16 384x256 (192KB) ; [1MiB] adj u8 (8MB).

#define NG    8192
#define HDIM  128
#define NEDGE 524288
#define NCONV 214272

typedef __bf16 bf16;
typedef __bf16 bf16x8 __attribute__((ext_vector_type(8)));
typedef float  f32x4  __attribute__((ext_vector_type(4)));
typedef unsigned int u32;
typedef unsigned char u8;

__device__ __forceinline__ f32x4 mfma16(bf16x8 a, bf16x8 b, f32x4 c) {
    // D = A(16x32)*B(32x16)+C ; A[m=lane&15][k=quad*8+j], B[k=quad*8+j][n=lane&15],
    // D[row=quad*4+r][col=lane&15]
    return __builtin_amdgcn_mfma_f32_16x16x32_bf16(a, b, c, 0, 0, 0);
}

__device__ __forceinline__ float sigmoidf_(float x) { return 1.f / (1.f + __expf(-x)); }
__device__ __forceinline__ float tanhf_(float x) { return 1.f - 2.f / (__expf(2.f * x) + 1.f); }

// ---- k_prep: 105 convert blocks (zeroing via hipMemsetAsync) ---------------
__global__ __launch_bounds__(256) void k_prep(
        const u32* __restrict__ featw,
        bf16* __restrict__ conv, u32* __restrict__ flagout,
        const void* t0, const void* t1, const void* t2,  const void* t3,
        const void* t4, const void* t5, const void* t6,  const void* t7,
        const void* t8, const void* t9, const void* t10, const void* t11) {
    const int b = blockIdx.x, tid = threadIdx.x;
    __shared__ int s_isf32;
    if (tid == 0) s_isf32 = 0;
    __syncthreads();
    {
        u32 hit = 0;
#pragma unroll
        for (int k = 0; k < 16; ++k) {
            u32 x = featw[tid * 16 + k];
            hit |= (((x >> 7) & 0xFFu) == 0xFFu) ? 1u : 0u;
        }
        if (hit) s_isf32 = 1;             // benign race
    }
    __syncthreads();
    const bool isf32 = s_isf32 != 0;
    if (b == 0 && tid == 0) *flagout = isf32 ? 1u : 0u;

    int e0 = b * 2048 + tid * 8;
    if (e0 >= NCONV) return;
    const int cnts[12] = {16384, 128, 16384, 128, 98304, 384, 49152, 384,
                          16384, 16384, 128, 128};
    int t = 0, base = 0;
    while (e0 >= base + cnts[t]) { base += cnts[t]; ++t; }
    int off = e0 - base;
    const void* sp;
    switch (t) {
        case 0: sp = t0; break; case 1: sp = t1; break;
        case 2: sp = t2; break; case 3: sp = t3; break;
        case 4: sp = t4; break; case 5: sp = t5; break;
        case 6: sp = t6; break; case 7: sp = t7; break;
        case 8: sp = t8; break; case 9: sp = t9; break;
        case 10: sp = t10; break; default: sp = t11; break;
    }
    if (isf32) {
        const float4* s = (const float4*)sp + (off >> 2);
        float4 a = s[0], bb = s[1];
        bf16x8 v;
        v[0] = (bf16)a.x;  v[1] = (bf16)a.y;  v[2] = (bf16)a.z;  v[3] = (bf16)a.w;
        v[4] = (bf16)bb.x; v[5] = (bf16)bb.y; v[6] = (bf16)bb.z; v[7] = (bf16)bb.w;
        *(bf16x8*)(conv + e0) = v;
    } else {
        *(uint4*)(conv + e0) = ((const uint4*)sp)[off >> 3];
    }
}

// ---- k_fuse: 96 blocks (jt = b>>2, ksel = b&3) -----------------------------
__global__ __launch_bounds__(256) void k_fuse(
        const bf16* __restrict__ W_in, const bf16* __restrict__ b_in,
        const bf16* __restrict__ W_og, const bf16* __restrict__ b_og,
        const bf16* __restrict__ W_ih, const bf16* __restrict__ b_ih,
        bf16* __restrict__ u_t, float* __restrict__ bw_in,
        float* __restrict__ bw_og) {
    const int jt = blockIdx.x >> 2;            // 0..23
    const int ksel = blockIdx.x & 3;
    const int tid = threadIdx.x;
    const int wave = tid >> 6, lane = tid & 63, q = lane >> 4, c = lane & 15;
    {
        int kt = wave * 4 + ksel;              // 0..15 (col tile of 256)
        bool og = kt >= 8;
        const bf16* Wsrc = og ? W_og : W_in;   // [128][128] row-major
        int kcol = (kt & 7) * 16 + c;          // 0..127
        int mo = og ? 128 : 0;
        f32x4 acc = {0, 0, 0, 0};
#pragma unroll 1
        for (int t = 0; t < 4; ++t) {
            bf16x8 a = *(const bf16x8*)(W_ih + (jt * 16 + c) * 256 + mo + 32 * t + 8 * q);
            bf16x8 b;
#pragma unroll
            for (int jj = 0; jj < 8; ++jj)
                b[jj] = Wsrc[(32 * t + 8 * q + jj) * 128 + kcol];
            acc = mfma16(a, b, acc);
        }
#pragma unroll
        for (int r = 0; r < 4; ++r)
            u_t[(size_t)(jt * 16 + q * 4 + r) * 256 + kt * 16 + c] = (bf16)acc[r];
    }
    if (ksel == 0) {   // bias: jj = tid>>4 (16 j's), mm = tid&15, shfl reduce
        int jj = tid >> 4, mm = tid & 15;
        int j = jt * 16 + jj;
        float si = 0.f, so = 0.f;
#pragma unroll
        for (int i = 0; i < 8; ++i) {
            int m = mm * 8 + i;
            si += (float)b_in[m] * (float)W_ih[j * 256 + m];
            so += (float)b_og[m] * (float)W_ih[j * 256 + 128 + m];
        }
        for (int m = 1; m < 16; m <<= 1) {
            si += __shfl_xor(si, m);
            so += __shfl_xor(so, m);
        }
        if (mm == 0) { bw_in[j] = si; bw_og[j] = so; }
    }
}

__global__ __launch_bounds__(256) void k_adj(const int* __restrict__ src,
                                             const int* __restrict__ dst,
                                             u32* __restrict__ adj) {
    int e = blockIdx.x * 256 + threadIdx.x;
    int s = src[e], d = dst[e];
    int g = s >> 5;                          // edges are intra-graph
    u32 bidx = ((u32)g << 10) | ((u32)(d & 31) << 5) | (u32)(s & 31);
    atomicAdd(&adj[bidx >> 2], 1u << (8 * (bidx & 3)));
}

__global__ __launch_bounds__(512, 4) void k_mono(
        const void* __restrict__ featv, const void* __restrict__ cntv,
        const bf16* __restrict__ u_t,  const bf16* __restrict__ b_ih,
        const bf16* __restrict__ W_hh, const bf16* __restrict__ b_hh,
        const bf16* __restrict__ W_u,  const bf16* __restrict__ W_v,
        const bf16* __restrict__ b_v,  const bf16* __restrict__ w_e,
        const float* __restrict__ bw_in, const float* __restrict__ bw_og,
        const int* __restrict__ last_nodes, const u8* __restrict__ adj8,
        const u32* __restrict__ flag, float* __restrict__ out) {
    const int g2   = blockIdx.x;            // graph pair: graphs 2*g2, 2*g2+1
    const int tid  = threadIdx.x;
    const int wave = tid >> 6, lane = tid & 63, q = lane >> 4, c = lane & 15;
    const bool isf32 = (*flag) != 0u;
    const int col  = wave * 16 + c;         // this wave's output column (0..127)

    const int SF = 136;   // bf16 stride, feat tile (pad 8)
    const int SC = 264;   // bf16 stride, P tile (pad 8)
    const int SA = 40;    // bf16 stride, adjacency (pad 8)
    const int SH = 136;   // bf16 stride, hnp/hn tile (16B-aligned rows)
    __shared__ __align__(16) bf16 s_feat[64 * 136];   // 17408 B (feat, stays feat)
    __shared__ __align__(16) bf16 s_fc  [64 * 264];   // 33792 B (P; adjw aliased)
    __shared__ __align__(16) bf16 s_adjb[64 * 40];    // 5120 B  adj[v][u]
    __shared__ __align__(16) bf16 s_adjT[64 * 40];    // 5120 B  adj[u][v]
    __shared__ __align__(16) bf16 s_hnp [64 * 136];   // 17408 B hnp, then hn
    __shared__ float s_invin[64], s_invout[64];
    __shared__ float s_din[64], s_dout[64];
    __shared__ float s_e[64], s_cnt[64];
    u32* s_adjw = (u32*)s_fc;   // alias: read pre-B1 only; s_fc written post-B1

    // ---------- phase 0: stage feat + adj word + adjb/adjT + cnt + e=0 ------
    if (isf32) {
        const float4* fp = (const float4*)((const float*)featv + (size_t)g2 * 8192);
        for (int ch = tid; ch < 2048; ch += 512) {
            float4 v = fp[ch];
            int row = ch >> 5, off = (ch & 31) * 4;
            bf16* dp = s_feat + row * SF + off;
            dp[0] = (bf16)v.x; dp[1] = (bf16)v.y; dp[2] = (bf16)v.z; dp[3] = (bf16)v.w;
        }
    } else {
        const uint4* fp = (const uint4*)((const bf16*)featv + (size_t)g2 * 8192);
        for (int ch = tid; ch < 1024; ch += 512) {
            int row = ch >> 4, off = (ch & 15) * 8;
            *(uint4*)(s_feat + row * SF + off) = fp[ch];
        }
    }
    {
        u32 w = ((const u32*)(adj8 + (size_t)g2 * 2048))[tid];
        s_adjw[tid] = w;
        int vrow = tid >> 3;            // global row 0..63
        int grp  = tid >> 8;            // graph within pair
        int vloc = vrow & 31;
        int u0 = (tid & 7) * 4;
#pragma unroll
        for (int j = 0; j < 4; ++j) {
            float cv = (float)((w >> (8 * j)) & 0xFFu);
            s_adjb[vrow * SA + u0 + j] = (bf16)cv;
            s_adjT[(grp * 32 + u0 + j) * SA + vloc] = (bf16)cv;
        }
    }
    if (tid < 64) {
        s_e[tid] = 0.f;
        s_cnt[tid] = isf32 ? ((const float*)cntv)[(size_t)g2 * 64 + tid]
                           : (float)((const bf16*)cntv)[(size_t)g2 * 64 + tid];
    }
    __syncthreads();   // B0

    // ---------- phase 1: degrees (from s_adjw alias) + hnp GEMM -------------
    if (tid < 64) {                                  // deg_in[row] = row-sum
        u32 s = 0;
#pragma unroll
        for (int i = 0; i < 8; ++i) {
            u32 w = s_adjw[tid * 8 + i];
            s += (w & 0xFF) + ((w >> 8) & 0xFF) + ((w >> 16) & 0xFF) + (w >> 24);
        }
        s_invin[tid] = 1.f / fmaxf((float)s, 1.f);
        s_din[tid] = (s > 0) ? 1.f : 0.f;
    } else if (tid < 128) {                          // deg_out = col-sum
        int uu = tid - 64; int grp = uu >> 5; int ul = uu & 31; u32 s = 0;
#pragma unroll 8
        for (int v = 0; v < 32; ++v)
            s += (s_adjw[grp * 256 + v * 8 + (ul >> 2)] >> (8 * (ul & 3))) & 0xFF;
        s_invout[uu] = 1.f / fmaxf((float)s, 1.f);
        s_dout[uu] = (s > 0) ? 1.f : 0.f;
    }
    // hnp = feat @ W_hh_n^T + b -> s_hnp (wave-private cols)
    {
        f32x4 hp[4] = {{0,0,0,0},{0,0,0,0},{0,0,0,0},{0,0,0,0}};
        const bf16* Vp = W_hh + (256 + col) * HDIM;
#pragma unroll 1
        for (int t = 0; t < 4; ++t) {
            bf16x8 b = *(const bf16x8*)(Vp + 32 * t + 8 * q);
#pragma unroll
            for (int fr = 0; fr < 4; ++fr) {
                bf16x8 a = *(const bf16x8*)(s_feat + (fr * 16 + c) * SF + 32 * t + 8 * q);
                hp[fr] = mfma16(a, b, hp[fr]);
            }
        }
        float bh = (float)b_hh[256 + col];
#pragma unroll
        for (int fr = 0; fr < 4; ++fr)
#pragma unroll
            for (int r = 0; r < 4; ++r)
                s_hnp[(fr * 16 + q * 4 + r) * SH + col] = (bf16)(hp[fr][r] + bh);
    }
    __syncthreads();   // B1 (degrees + hnp ready; s_adjw alias now dead)

    // ---------- phase 2: P = [invin*(adj@feat) | invout*(adjT@feat)] --------
#pragma unroll
    for (int kk = 0; kk < 2; ++kk) {
        int ct = wave * 2 + kk;                // 0..15
        int colb = (ct & 7) * 16;
        const bf16* Ab = (ct < 8) ? s_adjb : s_adjT;
        const float* inv = (ct < 8) ? s_invin : s_invout;
        bf16x8 bA, bB;
        const bf16* Bp0 = s_feat + (q * 8) * SF + colb + c;
        const bf16* Bp1 = s_feat + (32 + q * 8) * SF + colb + c;
#pragma unroll
        for (int jj = 0; jj < 8; ++jj) { bA[jj] = Bp0[jj * SF]; bB[jj] = Bp1[jj * SF]; }
        bf16x8 a0 = *(const bf16x8*)(Ab + c * SA + 8 * q);
        bf16x8 a1 = *(const bf16x8*)(Ab + (16 + c) * SA + 8 * q);
        bf16x8 a2 = *(const bf16x8*)(Ab + (32 + c) * SA + 8 * q);
        bf16x8 a3 = *(const bf16x8*)(Ab + (48 + c) * SA + 8 * q);
        f32x4 z = {0, 0, 0, 0};
        f32x4 p0 = mfma16(a0, bA, z);
        f32x4 p1 = mfma16(a1, bA, z);
        f32x4 p2 = mfma16(a2, bB, z);
        f32x4 p3 = mfma16(a3, bB, z);
#pragma unroll
        for (int r = 0; r < 4; ++r) {
            int r0 = q * 4 + r;
            s_fc[(r0)      * SC + ct * 16 + c] = (bf16)(p0[r] * inv[r0]);
            s_fc[(16 + r0) * SC + ct * 16 + c] = (bf16)(p1[r] * inv[16 + r0]);
            s_fc[(32 + r0) * SC + ct * 16 + c] = (bf16)(p2[r] * inv[32 + r0]);
            s_fc[(48 + r0) * SC + ct * 16 + c] = (bf16)(p3[r] * inv[48 + r0]);
        }
    }
    __syncthreads();   // B2

    // ---------- phase 3: GRU — static split t<4 (U+V) / t>=4 (U), setprio ---
    f32x4 rr[4] = {{0,0,0,0},{0,0,0,0},{0,0,0,0},{0,0,0,0}};
    f32x4 zz[4] = {{0,0,0,0},{0,0,0,0},{0,0,0,0},{0,0,0,0}};
    f32x4 in_[4] = {{0,0,0,0},{0,0,0,0},{0,0,0,0},{0,0,0,0}};
    {
        const bf16* Ur = u_t + (size_t)(col) * 256;
        const bf16* Uz = u_t + (size_t)(128 + col) * 256;
        const bf16* Un = u_t + (size_t)(256 + col) * 256;
        const bf16* Vr = W_hh + (col) * HDIM;
        const bf16* Vz = W_hh + (128 + col) * HDIM;
        __builtin_amdgcn_s_setprio(1);
#pragma unroll 2
        for (int t = 0; t < 4; ++t) {     // U + V half (no dynamic branch)
            bf16x8 br = *(const bf16x8*)(Ur + 32 * t + 8 * q);
            bf16x8 bz = *(const bf16x8*)(Uz + 32 * t + 8 * q);
            bf16x8 bn = *(const bf16x8*)(Un + 32 * t + 8 * q);
            bf16x8 vr = *(const bf16x8*)(Vr + 32 * t + 8 * q);
            bf16x8 vz = *(const bf16x8*)(Vz + 32 * t + 8 * q);
#pragma unroll
            for (int fr = 0; fr < 4; ++fr) {
                bf16x8 a = *(const bf16x8*)(s_fc + (fr * 16 + c) * SC + 32 * t + 8 * q);
                bf16x8 f = *(const bf16x8*)(s_feat + (fr * 16 + c) * SF + 32 * t + 8 * q);
                rr[fr] = mfma16(a, br, rr[fr]);
                zz[fr] = mfma16(a, bz, zz[fr]);
                in_[fr] = mfma16(a, bn, in_[fr]);
                rr[fr] = mfma16(f, vr, rr[fr]);
                zz[fr] = mfma16(f, vz, zz[fr]);
            }
        }
#pragma unroll 2
        for (int t = 4; t < 8; ++t) {     // U-only half
            bf16x8 br = *(const bf16x8*)(Ur + 32 * t + 8 * q);
            bf16x8 bz = *(const bf16x8*)(Uz + 32 * t + 8 * q);
            bf16x8 bn = *(const bf16x8*)(Un + 32 * t + 8 * q);
#pragma unroll
            for (int fr = 0; fr < 4; ++fr) {
                bf16x8 a = *(const bf16x8*)(s_fc + (fr * 16 + c) * SC + 32 * t + 8 * q);
                rr[fr] = mfma16(a, br, rr[fr]);
                zz[fr] = mfma16(a, bz, zz[fr]);
                in_[fr] = mfma16(a, bn, in_[fr]);
            }
        }
        __builtin_amdgcn_s_setprio(0);
    }
    // epilogue: read hnp (own cols) -> hv; then overwrite s_hnp with hn
    f32x4 hv[4];
    {
        float brz  = (float)b_ih[col]       + (float)b_hh[col];
        float bzz  = (float)b_ih[128 + col] + (float)b_hh[128 + col];
        float bin_ = (float)b_ih[256 + col];
        float bwr_i = bw_in[col],       bwr_o = bw_og[col];
        float bwz_i = bw_in[128 + col], bwz_o = bw_og[128 + col];
        float bwn_i = bw_in[256 + col], bwn_o = bw_og[256 + col];
#pragma unroll
        for (int fr = 0; fr < 4; ++fr) {
#pragma unroll
            for (int r = 0; r < 4; ++r) {
                int row = fr * 16 + q * 4 + r;
                float di = s_din[row], dou = s_dout[row];
                float rg = sigmoidf_(rr[fr][r] + brz + di * bwr_i + dou * bwr_o);
                float z_ = sigmoidf_(zz[fr][r] + bzz + di * bwz_i + dou * bwz_o);
                float ng = tanhf_(in_[fr][r] + bin_ + di * bwn_i + dou * bwn_o
                                  + rg * (float)s_hnp[row * SH + col]);
                float fv = (float)s_feat[row * SF + col];
                hv[fr][r] = (1.f - z_) * ng + z_ * fv;
            }
        }
    }
    int llA = last_nodes[2 * g2] & 31;
    int llB = 32 + (last_nodes[2 * g2 + 1] & 31);
#pragma unroll
    for (int fr = 0; fr < 4; ++fr)
#pragma unroll
        for (int r = 0; r < 4; ++r)
            s_hnp[(fr * 16 + q * 4 + r) * SH + col] = (bf16)hv[fr][r];
    __syncthreads();   // B3 (hn visible everywhere)
    const bf16* s_hn = s_hnp;

    // ---------- phase 4+5: fv in regs, then e via MFMA + shfl + s_e atomics -
    float fvA, fvB;
    {
        const bf16* Wp = W_v + (size_t)col * HDIM;
        f32x4 accA = {0, 0, 0, 0}, accB = {0, 0, 0, 0};
#pragma unroll 2
        for (int t = 0; t < 4; ++t) {
            bf16x8 b  = *(const bf16x8*)(Wp + 32 * t + 8 * q);
            bf16x8 aA = *(const bf16x8*)(s_hn + llA * SH + 32 * t + 8 * q);
            bf16x8 aB = *(const bf16x8*)(s_hn + llB * SH + 32 * t + 8 * q);
            accA = mfma16(aA, b, accA);
            accB = mfma16(aB, b, accB);
        }
        // broadcast-A: every lane's acc[0] == fv[col] (A rows identical)
        fvA = accA[0] + (float)b_v[col];
        fvB = accB[0] + (float)b_v[col];
    }
    {
        const bf16* Wp = W_u + (size_t)col * HDIM;
        f32x4 ee[4] = {{0,0,0,0},{0,0,0,0},{0,0,0,0},{0,0,0,0}};
#pragma unroll 2
        for (int t = 0; t < 4; ++t) {
            bf16x8 b = *(const bf16x8*)(Wp + 32 * t + 8 * q);
#pragma unroll
            for (int fr = 0; fr < 4; ++fr) {
                bf16x8 a = *(const bf16x8*)(s_hn + (fr * 16 + c) * SH + 32 * t + 8 * q);
                ee[fr] = mfma16(a, b, ee[fr]);
            }
        }
        float we = (float)w_e[col];
#pragma unroll
        for (int fr = 0; fr < 4; ++fr) {
            float fv = (fr < 2) ? fvA : fvB;
#pragma unroll
            for (int r = 0; r < 4; ++r) {
                float v = sigmoidf_(ee[fr][r] + fv) * we;
                for (int m = 1; m < 16; m <<= 1) v += __shfl_xor(v, m);
                if (c == 0) atomicAdd(&s_e[fr * 16 + q * 4 + r], v);
            }
        }
    }
    __syncthreads();   // B5 (s_e final)

    // ---------- output (f32): per graph [ct_g (128) | ct_l (128)] -----------
    {
        int part = tid >> 7;        // 0..3
        int co = tid & 127;
        if (part == 0) {
            float s = 0.f;
#pragma unroll 8
            for (int n = 0; n < 32; ++n)
                s += s_e[n] * s_cnt[n] * (float)s_hn[n * SH + co];
            out[(size_t)(2 * g2) * 256 + co] = s;
        } else if (part == 1) {
            out[(size_t)(2 * g2) * 256 + 128 + co] = (float)s_hn[llA * SH + co];
        } else if (part == 2) {
            float s = 0.f;
#pragma unroll 8
            for (int n = 32; n < 64; ++n)
                s += s_e[n] * s_cnt[n] * (float)s_hn[n * SH + co];
            out[(size_t)(2 * g2 + 1) * 256 + co] = s;
        } else {
            out[(size_t)(2 * g2 + 1) * 256 + 128 + co] = (float)s_hn[llB * SH + co];
        }
    }
}

extern "C" void kernel_launch(void* const* d_in, const int* in_sizes, int n_in,
                              void* d_out, int out_size, void* d_ws, size_t ws_size,
                              hipStream_t stream) {
    const int* src  = (const int*)d_in[14];
    const int* dst  = (const int*)d_in[15];
    const int* last = (const int*)d_in[17];
    float* out = (float*)d_out;

    u32*  flag  = (u32*)d_ws;
    bf16* conv  = (bf16*)((char*)d_ws + 4096);
    float* bwin = (float*)((char*)d_ws + 430 * 1024);
    float* bwog = (float*)((char*)d_ws + 434 * 1024);
    bf16* u_t   = (bf16*)((char*)d_ws + 448 * 1024);   // 384x256 bf16 = 192KB
    u32*  adjw  = (u32*)((char*)d_ws + (1u << 20));
    const u8* adj8 = (const u8*)adjw;

    // bf16 weight copies, contiguous in input order 2..13
    const int cnts[12] = {16384, 128, 16384, 128, 98304, 384, 49152, 384,
                          16384, 16384, 128, 128};
    bf16* cp[12];
    {
        bf16* p = conv;
        for (int i = 0; i < 12; ++i) { cp[i] = p; p += cnts[i]; }
    }

    hipMemsetAsync(adjw, 0, 8u << 20, stream);          // zero adj
    k_prep<<<(NCONV + 2047) / 2048, 256, 0, stream>>>(
        (const u32*)d_in[0], conv, flag,
        d_in[2], d_in[3], d_in[4], d_in[5], d_in[6], d_in[7],
        d_in[8], d_in[9], d_in[10], d_in[11], d_in[12], d_in[13]);
    k_fuse<<<96, 256, 0, stream>>>(cp[0], cp[1], cp[2], cp[3], cp[4], cp[5],
                                   u_t, bwin, bwog);
    k_adj<<<NEDGE / 256, 256, 0, stream>>>(src, dst, adjw);
    k_mono<<<NG / 2, 512, 0, stream>>>(d_in[0], d_in[1],
                                       u_t, cp[5], cp[6], cp[7],
                                       cp[8], cp[9], cp[10], cp[11],
                                       bwin, bwog,
                                       last, adj8, flag, out);
}